// Round 10
// baseline (611.113 us; speedup 1.0000x reference)
//
#include <hip/hip_runtime.h>

#define DEV __device__ __forceinline__

typedef unsigned short u16;
typedef unsigned int u32;
typedef __attribute__((ext_vector_type(4))) float f32x4;
typedef __attribute__((ext_vector_type(8))) u16 u16x8;
typedef __attribute__((ext_vector_type(4))) u16 u16x4;
typedef __attribute__((ext_vector_type(8))) __bf16 bf16x8;

#define INTER 4096
#define DSTATE 128
#define CONVD 4352
#define NPAD 8704
#define NROWS 4096

DEV float b2f(u16 u){ union{u32 i; float f;} v; v.i = ((u32)u)<<16; return v.f; }
DEV u16 f2b(float f){ union{u32 i; float f;} v; v.f = f; u32 r = v.i + 0x7fffu + ((v.i>>16)&1u); return (u16)(r>>16); }

typedef const __attribute__((address_space(1))) u32 gas_u32;
typedef __attribute__((address_space(3))) u32 las_u32;
DEV void gl_lds16(const u16* g, u16* l){
  __builtin_amdgcn_global_load_lds((gas_u32*)g, (las_u32*)l, 16, 0, 0);
}

// ---------------- fused f32 -> bf16 converts (X, W1 with zero-pad, W2) ----------------
__global__ __launch_bounds__(256) void k_cvt3(
    const float* __restrict__ X, const float* __restrict__ W1, const float* __restrict__ W2,
    u16* __restrict__ Xb, u16* __restrict__ Wb, u16* __restrict__ W2b)
{
  long b = blockIdx.x;
  const float* src; u16* dst; long n, base;
  if (b < 8192)       { src = X;  dst = Xb;  n = 8388608L;  base = b*1024L; }
  else if (b < 25600) { src = W1; dst = Wb;  n = 17432576L; base = (b-8192)*1024L; }
  else                { src = W2; dst = W2b; n = 8388608L;  base = (b-25600)*1024L; }
  long i = base + (long)threadIdx.x*4;
  u16x4 o;
  if (i < n){
    f32x4 v = *(const f32x4*)&src[i];
    o[0]=f2b(v[0]); o[1]=f2b(v[1]); o[2]=f2b(v[2]); o[3]=f2b(v[3]);
  } else {
    o[0]=0; o[1]=0; o[2]=0; o[3]=0;
  }
  *(u16x4*)&dst[i] = o;
}

// ================= 256x256 BT GEMM — m201-faithful 8-phase quadrant schedule =================
// 512 threads (8 waves, 2Mx4N), per-wave 128x64.  LDS 128KB: [buf][kh][A 256x32][B 256x32],
// st_16x32 swizzle via linear LDS dest + pre-swizzled global src.
// Phase = { A-quadrant reads (8 x b128, ch0 phases only; regs live across ch1 phase)
//           + B reads (4 x b128), stage ONE half-tile (2 x gl_lds), s_barrier,
//           lgkmcnt(0) + sched_barrier(0) [rule 18], setprio(1), 16 MFMA (4m x 2n x 2kk),
//           setprio(0), [vmcnt(2) at ph3/ph7], s_barrier }.
// Stage slots (iteration reads tile u @buf0 ph0-3, u+1 @buf1 ph4-7):
//   ph0:A1(u+1)->b1  ph1:B0(u+1)->b1  ph2:B1(u+1)->b1  ph3:A0(u+2)->b0 +vmcnt(2)
//   ph4:A1(u+2)->b0  ph5:B0(u+2)->b0  ph6:B1(u+2)->b0  ph7:A0(u+3)->b1 +vmcnt(2)
// Each stage lands >=1 phase after its region's last read (reads lgkm-retired pre-barrier);
// vmcnt(2) at ph3/ph7 retires exactly the half-tiles the following 4 read-phases need.
template<int EPI>
__global__ __launch_bounds__(512, 2) void k_gemmq(
    const u16* __restrict__ A, const u16* __restrict__ B,
    void* __restrict__ C0, float* __restrict__ C1,
    int lda, int ldb, int ldc, int K, int NTM, long sCz)
{
  __shared__ __align__(16) char smem[131072];
  const int t = threadIdx.x, lane = t & 63, w = t >> 6;
  const int wm = w >> 2, wn = w & 3, w64 = w * 64;
  const int NT = K >> 6;
  const int z = blockIdx.y;

  const int nwg = gridDim.x;
  const int orig = blockIdx.x;
  const int wg = (orig & 7) * (nwg >> 3) + (orig >> 3);
  const int mt = wg % NTM, nt = wg / NTM;     // nt-major: A streams, B panels L2-resident

  const u16* Ab = A + (long)mt * 256 * lda + (long)z * K;
  const u16* Bb = B + (long)nt * 256 * ldb + (long)z * K;

  const int laneoff = (lane & 15) * 64 + (lane >> 4) * 16;
  const int lo = laneoff ^ (((laneoff >> 9) & 1) << 5);

  // one 8KB stage instruction covers 512 threads x 16B; inverse-swizzled source
  const int up = t ^ (((t >> 5) & 1) << 1);
  const int srow = (up >> 6) * 16 + ((up & 63) >> 2);
  const int sc8 = (up & 3) * 8;
  const long aoff = (long)srow * lda + sc8;
  const long boff = (long)srow * ldb + sc8;

  f32x4 acc[8][4];
#pragma unroll
  for (int i=0;i<8;i++)
#pragma unroll
    for (int j=0;j<4;j++) acc[i][j] = (f32x4){0.f,0.f,0.f,0.f};

  bf16x8 a_[4][2], b_[2][2];

// stage half-tile: A rows RH*128..+127 x K64 of tile KT -> buf BUF (2 loads: kh0, kh1)
#define SAH(BUF,RH,KT) do{ \
    gl_lds16(Ab + aoff + (long)(RH)*128*lda + (long)(KT)*64,      (u16*)(smem + (BUF)*65536 +         (RH)*8192 + w64*16)); \
    gl_lds16(Ab + aoff + (long)(RH)*128*lda + (long)(KT)*64 + 32, (u16*)(smem + (BUF)*65536 + 16384 + (RH)*8192 + w64*16)); }while(0)
#define SBH(BUF,RH,KT) do{ \
    gl_lds16(Bb + boff + (long)(RH)*128*ldb + (long)(KT)*64,      (u16*)(smem + (BUF)*65536 + 32768 +         (RH)*8192 + w64*16)); \
    gl_lds16(Bb + boff + (long)(RH)*128*ldb + (long)(KT)*64 + 32, (u16*)(smem + (BUF)*65536 + 32768 + 16384 + (RH)*8192 + w64*16)); }while(0)

// VM: 0=none, 1=vmcnt(2), 2=vmcnt(0)
#define PH(BUF,RH,CH,RA,STMT,VM) do{ \
    const char* pa_ = smem + (BUF)*65536; \
    const char* pb_ = pa_ + 32768; \
    if (RA){ \
      _Pragma("unroll") for (int i_=0;i_<4;i_++) \
        _Pragma("unroll") for (int k_=0;k_<2;k_++) \
          a_[i_][k_] = *(const bf16x8*)(pa_ + k_*16384 + (wm*8+(RH)*4+i_)*1024 + lo); \
    } \
    _Pragma("unroll") for (int j_=0;j_<2;j_++) \
      _Pragma("unroll") for (int k_=0;k_<2;k_++) \
        b_[j_][k_] = *(const bf16x8*)(pb_ + k_*16384 + (wn*4+(CH)*2+j_)*1024 + lo); \
    STMT; \
    asm volatile("s_barrier":::"memory"); \
    asm volatile("s_waitcnt lgkmcnt(0)":::"memory"); \
    __builtin_amdgcn_sched_barrier(0); \
    __builtin_amdgcn_s_setprio(1); \
    _Pragma("unroll") for (int i_=0;i_<4;i_++) \
      _Pragma("unroll") for (int j_=0;j_<2;j_++) \
        _Pragma("unroll") for (int k_=0;k_<2;k_++) \
          acc[(RH)*4+i_][(CH)*2+j_] = __builtin_amdgcn_mfma_f32_16x16x32_bf16(a_[i_][k_], b_[j_][k_], acc[(RH)*4+i_][(CH)*2+j_], 0,0,0); \
    __builtin_amdgcn_s_setprio(0); \
    if ((VM)==1) asm volatile("s_waitcnt vmcnt(2)":::"memory"); \
    if ((VM)==2) asm volatile("s_waitcnt vmcnt(0)":::"memory"); \
    asm volatile("s_barrier":::"memory"); \
  }while(0)

  // prologue: tile0 complete + A0(t1) in flight
  SAH(0,0,0); SAH(0,1,0); SBH(0,0,0); SBH(0,1,0); SAH(1,0,1);
  asm volatile("s_waitcnt vmcnt(2)":::"memory");
  asm volatile("s_barrier":::"memory");

  for (int u = 0; u <= NT-4; u += 2){
    PH(0,0,0,1, SAH(1,1,u+1), 0);
    PH(0,0,1,0, SBH(1,0,u+1), 0);
    PH(0,1,0,1, SBH(1,1,u+1), 0);
    PH(0,1,1,0, SAH(0,0,u+2), 1);
    PH(1,0,0,1, SAH(0,1,u+2), 0);
    PH(1,0,1,0, SBH(0,0,u+2), 0);
    PH(1,1,0,1, SBH(0,1,u+2), 0);
    PH(1,1,1,0, SAH(1,0,u+3), 1);
  }
  { // epilogue: u = NT-2 (stages only tile NT-1's remaining halves)
    PH(0,0,0,1, SAH(1,1,NT-1), 0);
    PH(0,0,1,0, SBH(1,0,NT-1), 0);
    PH(0,1,0,1, SBH(1,1,NT-1), 0);
    PH(0,1,1,0, ((void)0), 2);
    PH(1,0,0,1, ((void)0), 0);
    PH(1,0,1,0, ((void)0), 0);
    PH(1,1,0,1, ((void)0), 0);
    PH(1,1,1,0, ((void)0), 0);
  }
#undef SAH
#undef SBH
#undef PH

#pragma unroll
  for (int i=0;i<8;i++)
#pragma unroll
    for (int j=0;j<4;j++)
#pragma unroll
      for (int r=0;r<4;r++){
        int gm = mt*256 + wm*128 + i*16 + (lane>>4)*4 + r;
        int gn = nt*256 + wn*64 + j*16 + (lane&15);
        float v = acc[i][j][r];
        if (EPI==0){
          ((u16*)C0)[(long)gm*ldc + gn] = f2b(v);
          if (gn >= 8448 && gn < 8512) C1[(long)gm*64 + (gn-8448)] = v;
        } else {
          ((float*)C0)[(long)z*sCz + (long)gm*ldc + gn] = v;
        }
      }
}

// ================= 256x256 BT GEMM, 128KB, SGB-interleaved (R7 proven) — out_proj =================
template<int EPI>
__global__ __launch_bounds__(512, 2) void k_gemm8(
    const u16* __restrict__ A, const u16* __restrict__ B,
    void* __restrict__ C0, float* __restrict__ C1,
    int lda, int ldb, int ldc, int K, int NTM, long sCz)
{
  __shared__ __align__(16) char smem[131072];
  const int t = threadIdx.x, lane = t & 63, w = t >> 6;
  const int wm = w >> 2, wn = w & 3, w64 = w * 64;
  const int NT = K >> 6, NIT = NT >> 1;
  const int z = blockIdx.y;

  const int nwg = gridDim.x;
  const int orig = blockIdx.x;
  const int wg = (orig & 7) * (nwg >> 3) + (orig >> 3);
  const int mt = wg % NTM, nt = wg / NTM;

  const u16* Ab = A + (long)mt * 256 * lda + (long)z * K;
  const u16* Bb = B + (long)nt * 256 * ldb + (long)z * K;

  const int laneoff = (lane & 15) * 64 + (lane >> 4) * 16;
  const int lo = laneoff ^ (((laneoff >> 9) & 1) << 5);

  long aoff[2], boff[2];
#pragma unroll
  for (int q = 0; q < 2; q++) {
    int u = t + q * 512;
    int up = u ^ (((u >> 5) & 1) << 1);
    int row = (up >> 6) * 16 + ((up & 63) >> 2);
    int c8 = (up & 3) * 8;
    aoff[q] = (long)row * lda + c8;
    boff[q] = (long)row * ldb + c8;
  }

  f32x4 acc[8][4];
#pragma unroll
  for (int i=0;i<8;i++)
#pragma unroll
    for (int j=0;j<4;j++) acc[i][j] = (f32x4){0.f,0.f,0.f,0.f};

#define SA(BUF,KH,KT) do{ long kb_ = (long)(KT)*64 + (KH)*32; \
    gl_lds16(Ab + aoff[0] + kb_, (u16*)(smem + (BUF)*65536 + (KH)*16384 + w64*16)); \
    gl_lds16(Ab + aoff[1] + kb_, (u16*)(smem + (BUF)*65536 + (KH)*16384 + 8192 + w64*16)); }while(0)
#define SB(BUF,KH,KT) do{ long kb_ = (long)(KT)*64 + (KH)*32; \
    gl_lds16(Bb + boff[0] + kb_, (u16*)(smem + (BUF)*65536 + 32768 + (KH)*16384 + w64*16)); \
    gl_lds16(Bb + boff[1] + kb_, (u16*)(smem + (BUF)*65536 + 32768 + (KH)*16384 + 8192 + w64*16)); }while(0)

#define SPHASE(BUF,KH,STMT,VM,HASV) do{ \
    const char* pa_ = smem + (BUF)*65536 + (KH)*16384; \
    const char* pb_ = smem + (BUF)*65536 + 32768 + (KH)*16384; \
    STMT; \
    bf16x8 a_[8], b_[4]; \
    _Pragma("unroll") \
    for (int j_=0;j_<4;j_++) b_[j_] = *(const bf16x8*)(pb_ + (wn*4+j_)*1024 + lo); \
    _Pragma("unroll") \
    for (int m_=0;m_<8;m_++) a_[m_] = *(const bf16x8*)(pa_ + (wm*8+m_)*1024 + lo); \
    __builtin_amdgcn_s_setprio(1); \
    _Pragma("unroll") \
    for (int m_=0;m_<8;m_++) \
      _Pragma("unroll") \
      for (int j_=0;j_<4;j_++) \
        acc[m_][j_] = __builtin_amdgcn_mfma_f32_16x16x32_bf16(a_[m_], b_[j_], acc[m_][j_], 0,0,0); \
    __builtin_amdgcn_s_setprio(0); \
    __builtin_amdgcn_sched_group_barrier(0x100, 6, 0); \
    if (HASV) __builtin_amdgcn_sched_group_barrier(0x010, 4, 0); \
    _Pragma("unroll") \
    for (int g_=0; g_<6; ++g_){ \
      __builtin_amdgcn_sched_group_barrier(0x008, 4, 0); \
      __builtin_amdgcn_sched_group_barrier(0x100, 1, 0); \
    } \
    __builtin_amdgcn_sched_group_barrier(0x008, 8, 0); \
    if ((VM)==1) asm volatile("s_waitcnt vmcnt(8)":::"memory"); \
    if ((VM)==2) asm volatile("s_waitcnt vmcnt(4)":::"memory"); \
    if ((VM)==3) asm volatile("s_waitcnt vmcnt(0)":::"memory"); \
    asm volatile("s_barrier":::"memory"); \
  }while(0)

  SA(0,0,0); SB(0,0,0); SA(0,1,0); SB(0,1,0); SA(1,0,1); SB(1,0,1);
  asm volatile("s_waitcnt vmcnt(8)":::"memory");
  asm volatile("s_barrier":::"memory");

  for (int it = 0; it < NIT-1; ++it) {
    int t1 = 2*it+1, t2 = 2*it+2, t3 = 2*it+3;
    SPHASE(0,0, { SA(1,1,t1); SB(1,1,t1); }, 1, 1);
    SPHASE(0,1, { SA(0,0,t2); SB(0,0,t2); }, 1, 1);
    SPHASE(1,0, { SA(0,1,t2); SB(0,1,t2); }, 1, 1);
    SPHASE(1,1, { SA(1,0,t3); SB(1,0,t3); }, 1, 1);
  }
  {
    int tl = NT-1;
    SPHASE(0,0, { SA(1,1,tl); SB(1,1,tl); }, 1, 1);
    SPHASE(0,1, ((void)0), 2, 0);
    SPHASE(1,0, ((void)0), 3, 0);
    SPHASE(1,1, ((void)0), 0, 0);
  }
#undef SA
#undef SB
#undef SPHASE

#pragma unroll
  for (int i=0;i<8;i++)
#pragma unroll
    for (int j=0;j<4;j++)
#pragma unroll
      for (int r=0;r<4;r++){
        int gm = mt*256 + wm*128 + i*16 + (lane>>4)*4 + r;
        int gn = nt*256 + wn*64 + j*16 + (lane&15);
        float v = acc[i][j][r];
        if (EPI==0){
          ((u16*)C0)[(long)gm*ldc + gn] = f2b(v);
          if (gn >= 8448 && gn < 8512) C1[(long)gm*64 + (gn-8448)] = v;
        } else {
          ((float*)C0)[(long)z*sCz + (long)gm*ldc + gn] = v;
        }
      }
}

// ---------------- partial add: out = p0 + p1 ----------------
__global__ __launch_bounds__(256) void k_add(const float* __restrict__ p, float* __restrict__ out, long n){
  long i = ((long)blockIdx.x*256 + threadIdx.x)*8;
  if (i >= n) return;
  f32x4 a0 = *(const f32x4*)&p[i];
  f32x4 a1 = *(const f32x4*)&p[i+4];
  f32x4 b0 = *(const f32x4*)&p[n+i];
  f32x4 b1 = *(const f32x4*)&p[n+i+4];
  a0 += b0; a1 += b1;
  *(f32x4*)&out[i] = a0;
  *(f32x4*)&out[i+4] = a1;
}

// ---------------- 128x128 BT GEMM (kept for the small per-chunk G = C@B^T) ----------------
template<int EPI>
__global__ __launch_bounds__(256) void k_gemm_bt(
    const u16* __restrict__ A, const u16* __restrict__ B,
    void* __restrict__ C0, float* __restrict__ C1,
    int lda, int ldb, int ldc, int K,
    long sAz, long sBz, long sCz, int auxcol)
{
  __shared__ u16 As[128*64];
  __shared__ u16 Bs[128*64];
  const int t = threadIdx.x, w = t>>6, lane = t&63;
  const int mt = blockIdx.y, nt = blockIdx.x, z = blockIdx.z;
  const u16* Ab = A + (long)z*sAz + (long)mt*128*lda;
  const u16* Bb = B + (long)z*sBz + (long)nt*128*ldb;
  const int wm = w>>1, wn = w&1;
  f32x4 acc[4][4];
#pragma unroll
  for (int i=0;i<4;i++)
#pragma unroll
    for (int j=0;j<4;j++) acc[i][j] = (f32x4){0.f,0.f,0.f,0.f};
  const int srow = (lane>>3), scol = (lane&7)*8;
  for (int k0=0; k0<K; k0+=64){
#pragma unroll
    for (int i=0;i<4;i++){
      int ch = w*4+i;
      int row = ch*8 + srow;
      gl_lds16(Ab + (long)row*lda + k0 + scol, As + ch*512);
      gl_lds16(Bb + (long)row*ldb + k0 + scol, Bs + ch*512);
    }
    __syncthreads();
#pragma unroll
    for (int kk=0;kk<2;kk++){
      bf16x8 af[4], bfr[4];
#pragma unroll
      for (int i=0;i<4;i++) af[i]  = *(const bf16x8*)&As[(wm*64+i*16+(lane&15))*64 + kk*32 + (lane>>4)*8];
#pragma unroll
      for (int j=0;j<4;j++) bfr[j] = *(const bf16x8*)&Bs[(wn*64+j*16+(lane&15))*64 + kk*32 + (lane>>4)*8];
#pragma unroll
      for (int i=0;i<4;i++)
#pragma unroll
        for (int j=0;j<4;j++)
          acc[i][j] = __builtin_amdgcn_mfma_f32_16x16x32_bf16(af[i], bfr[j], acc[i][j], 0,0,0);
    }
    __syncthreads();
  }
#pragma unroll
  for (int i=0;i<4;i++)
#pragma unroll
    for (int j=0;j<4;j++)
#pragma unroll
      for (int r=0;r<4;r++){
        int gm = mt*128 + wm*64 + i*16 + (lane>>4)*4 + r;
        int gn = nt*128 + wn*64 + j*16 + (lane&15);
        float v = acc[i][j][r];
        if (EPI==0){
          ((u16*)C0)[(long)gm*ldc + gn] = f2b(v);
          if (gn >= auxcol) C1[(long)gm*128 + (gn-auxcol)] = v;
        } else {
          ((float*)C0)[(long)z*sCz + (long)gm*ldc + gn] = v;
        }
      }
}

// ---------------- depthwise causal conv (K=4) + silu ----------------
__global__ __launch_bounds__(256) void k_conv(
    const u16* __restrict__ Pb, const float* __restrict__ cw, const float* __restrict__ cb,
    u16* __restrict__ XBC)
{
  long tg = (long)blockIdx.x*256 + threadIdx.x;
  int row = (int)(tg/544);
  int ch0 = (int)(tg%544)*8;
  int s = row & 2047;
  float acc[8];
#pragma unroll
  for (int j=0;j<8;j++) acc[j] = cb[ch0+j];
#pragma unroll
  for (int k=0;k<4;k++){
    int sk = s - 3 + k;
    if (sk >= 0){
      u16x8 v = *(const u16x8*)&Pb[(long)(row-3+k)*NPAD + INTER + ch0];
#pragma unroll
      for (int j=0;j<8;j++) acc[j] += b2f(v[j]) * cw[(ch0+j)*4 + k];
    }
  }
  u16x8 o;
#pragma unroll
  for (int j=0;j<8;j++){ float x = acc[j]; o[j] = f2b(x/(1.f+__expf(-x))); }
  *(u16x8*)&XBC[(long)row*CONVD + ch0] = o;
}

// ---------------- dt = softplus(dtraw + bias), a = dt*A, cumsum(a) per (b,h,chunk) ----------------
__global__ __launch_bounds__(256) void k_dtcs(
    const float* __restrict__ DTraw, const float* __restrict__ dt_bias,
    const float* __restrict__ A_log,
    float* __restrict__ dtb, float* __restrict__ csb, float* __restrict__ cdec)
{
  __shared__ float sc[256];
  int bid = blockIdx.x;          // ((b*64+h)*8 + c)
  int bh = bid>>3, c = bid&7;
  int h = bh & 63, b = bh>>6;
  int l = threadIdx.x;
  int row = (b*8+c)*256 + l;
  float x = DTraw[(long)row*64 + h] + dt_bias[h];
  float dt = (x > 20.f) ? x : log1pf(__expf(x));
  float a = dt * (-__expf(A_log[h]));
  dtb[(long)row*64 + h] = dt;
  sc[l] = a; __syncthreads();
  for (int off=1; off<256; off<<=1){
    float v = (l>=off) ? sc[l-off] : 0.f;
    __syncthreads();
    sc[l] += v;
    __syncthreads();
  }
  float cs = sc[l];
  csb[(long)bid*256 + l] = cs;
  if (l==255) cdec[bid] = __expf(cs);
}

// ---------------- chunk states via MFMA: states[p][n] = sum_l xdt[l][p]*decay[l]*B[l][n] ----------------
__global__ __launch_bounds__(256) void k_states(
    const u16* __restrict__ XBC, const float* __restrict__ dtb, const float* __restrict__ csb,
    float* __restrict__ states)
{
  __shared__ u16 xsT[64*136];
  __shared__ u16 bsT[128*136];
  __shared__ float dtl[128], del[128];
  int bid = blockIdx.x;            // (b*8+c)*64 + h
  int h = bid & 63, bc = bid >> 6;
  int b = bc>>3, c = bc&7;
  int rowb = bc*256;
  int t = threadIdx.x, w = t>>6, lane = t&63;
  int csbase = ((b*64+h)*8 + c)*256;
  float clast = csb[csbase + 255];
  f32x4 acc[8];
#pragma unroll
  for (int j=0;j<8;j++) acc[j] = (f32x4){0.f,0.f,0.f,0.f};
  for (int half=0; half<2; half++){
    int lbase = half*128;
    if (t < 128){
      dtl[t] = dtb[(long)(rowb+lbase+t)*64 + h];
      del[t] = __expf(clast - csb[csbase + lbase + t]);
    }
    __syncthreads();
#pragma unroll
    for (int it=0; it<4; it++){
      int id = it*256+t;
      int p8 = id&7, l = id>>3;
      u16x8 v = *(const u16x8*)&XBC[(long)(rowb+lbase+l)*CONVD + h*64 + p8*8];
      float d = dtl[l];
#pragma unroll
      for (int j=0;j<8;j++) xsT[(p8*8+j)*136 + l] = f2b(b2f(v[j])*d);
    }
#pragma unroll
    for (int it=0; it<8; it++){
      int id = it*256+t;
      int n8 = id&15, l = id>>4;
      u16x8 v = *(const u16x8*)&XBC[(long)(rowb+lbase+l)*CONVD + INTER + n8*8];
      float d = del[l];
#pragma unroll
      for (int j=0;j<8;j++) bsT[(n8*8+j)*136 + l] = f2b(b2f(v[j])*d);
    }
    __syncthreads();
#pragma unroll
    for (int ks=0; ks<4; ks++){
      bf16x8 af = *(const bf16x8*)&xsT[(w*16 + (lane&15))*136 + ks*32 + (lane>>4)*8];
#pragma unroll
      for (int j=0;j<8;j++){
        bf16x8 bf = *(const bf16x8*)&bsT[(j*16 + (lane&15))*136 + ks*32 + (lane>>4)*8];
        acc[j] = __builtin_amdgcn_mfma_f32_16x16x32_bf16(af, bf, acc[j], 0,0,0);
      }
    }
    __syncthreads();
  }
  float* outp = states + (long)bid*8192;
#pragma unroll
  for (int j=0;j<8;j++)
#pragma unroll
    for (int r=0;r<4;r++){
      int gm = w*16 + (lane>>4)*4 + r;
      int gn = j*16 + (lane&15);
      outp[gm*128 + gn] = acc[j][r];
    }
}

// ---------------- inter-chunk scan (vectorized x4) ----------------
__global__ __launch_bounds__(256) void k_scan(
    const float* __restrict__ states, const float* __restrict__ cdec,
    u16* __restrict__ prevb)
{
  int bid = blockIdx.x;            // (b*64+h)*8 + sub
  int bh = bid>>3, sub = bid&7;
  int b = bh>>6, h = bh&63;
  int e = (sub*256 + threadIdx.x)*4;
  f32x4 carry = (f32x4){0.f,0.f,0.f,0.f};
#pragma unroll
  for (int c=0;c<8;c++){
    long idx = ((long)((b*8+c)*64 + h))*8192 + e;
    u16x4 o;
    o[0]=f2b(carry[0]); o[1]=f2b(carry[1]); o[2]=f2b(carry[2]); o[3]=f2b(carry[3]);
    *(u16x4*)&prevb[idx] = o;
    f32x4 s = *(const f32x4*)&states[idx];
    float d = cdec[bh*8 + c];
    carry = carry*d + s;
  }
}

// ---------------- fused Y_diag + Y_off + D*x per (b,c,h) ----------------
__global__ __launch_bounds__(256) void k_ydiag(
    const u16* __restrict__ XBC, const float* __restrict__ G,
    const u16* __restrict__ prevb, const float* __restrict__ dtb,
    const float* __restrict__ csb, const float* __restrict__ Dp,
    float* __restrict__ Y)
{
  __shared__ u16 PA[256*72];
  __shared__ u16 PB[64*72];
  __shared__ float csl[256];
  int bid = blockIdx.x;
  int h = bid&63, bc = bid>>6;
  int b = bc>>3, c = bc&7;
  int rowb = bc*256;
  int t = threadIdx.x, w = t>>6, lane = t&63;
  int csbase = ((b*64+h)*8 + c)*256;
  csl[t] = csb[csbase + t];
  const float* Gz = G + (long)bc*65536;
  f32x4 ad[4][4], ao[4][4];
#pragma unroll
  for (int i=0;i<4;i++)
#pragma unroll
    for (int j=0;j<4;j++){ ad[i][j]=(f32x4){0.f,0.f,0.f,0.f}; ao[i][j]=(f32x4){0.f,0.f,0.f,0.f}; }
  __syncthreads();
  for (int sl6=0; sl6<6; sl6++){
    if (sl6 < 4){
      int s0 = sl6*64;
#pragma unroll
      for (int r=0;r<8;r++){
        int id = r*256+t;
        int l = id>>3, sc8 = (id&7)*8;
        f32x4 g0 = *(const f32x4*)&Gz[l*256 + s0+sc8];
        f32x4 g1 = *(const f32x4*)&Gz[l*256 + s0+sc8+4];
        float cl = csl[l];
        u16x8 o;
#pragma unroll
        for (int jj=0;jj<4;jj++){
          int s = s0+sc8+jj;
          o[jj] = (s<=l) ? f2b(g0[jj]*__expf(cl - csl[s])) : (u16)0;
        }
#pragma unroll
        for (int jj=4;jj<8;jj++){
          int s = s0+sc8+jj;
          o[jj] = (s<=l) ? f2b(g1[jj-4]*__expf(cl - csl[s])) : (u16)0;
        }
        *(u16x8*)&PA[l*72 + sc8] = o;
      }
#pragma unroll
      for (int r=0;r<16;r++){
        int id = r*256+t;
        int p = id&63, ks = id>>6;
        float xv = b2f(XBC[(long)(rowb+s0+ks)*CONVD + h*64 + p]);
        float d = dtb[(long)(rowb+s0+ks)*64 + h];
        PB[p*72 + ks] = f2b(xv*d);
      }
    } else {
      int n0 = (sl6-4)*64;
#pragma unroll
      for (int r=0;r<8;r++){
        int id = r*256+t;
        int l = id>>3, kc = (id&7)*8;
        u16x8 v = *(const u16x8*)&XBC[(long)(rowb+l)*CONVD + INTER + DSTATE + n0 + kc];
        *(u16x8*)&PA[l*72 + kc] = v;
      }
#pragma unroll
      for (int r=0;r<2;r++){
        int id = r*256+t;
        int p = id>>3, kc = (id&7)*8;
        u16x8 v = *(const u16x8*)&prevb[((long)bid*64 + p)*128 + n0 + kc];
        *(u16x8*)&PB[p*72 + kc] = v;
      }
    }
    __syncthreads();
#pragma unroll
    for (int kk=0;kk<2;kk++){
      bf16x8 af[4], bfr[4];
#pragma unroll
      for (int i=0;i<4;i++) af[i]  = *(const bf16x8*)&PA[(w*64+i*16+(lane&15))*72 + kk*32 + (lane>>4)*8];
#pragma unroll
      for (int j=0;j<4;j++) bfr[j] = *(const bf16x8*)&PB[(j*16+(lane&15))*72 + kk*32 + (lane>>4)*8];
      if (sl6 < 4){
#pragma unroll
        for (int i=0;i<4;i++)
#pragma unroll
          for (int j=0;j<4;j++)
            ad[i][j] = __builtin_amdgcn_mfma_f32_16x16x32_bf16(af[i], bfr[j], ad[i][j], 0,0,0);
      } else {
#pragma unroll
        for (int i=0;i<4;i++)
#pragma unroll
          for (int j=0;j<4;j++)
            ao[i][j] = __builtin_amdgcn_mfma_f32_16x16x32_bf16(af[i], bfr[j], ao[i][j], 0,0,0);
      }
    }
    __syncthreads();
  }
  float Dh = Dp[h];
#pragma unroll
  for (int i=0;i<4;i++)
#pragma unroll
    for (int j=0;j<4;j++)
#pragma unroll
      for (int r=0;r<4;r++){
        int l = w*64 + i*16 + (lane>>4)*4 + r;
        int p = j*16 + (lane&15);
        float e = __expf(csl[l]);
        float xv = b2f(XBC[(long)(rowb+l)*CONVD + h*64 + p]);
        float v = ad[i][j][r] + e*ao[i][j][r] + Dh*xv;
        Y[(long)(rowb+l)*INTER + h*64 + p] = v;
      }
}

// ---------------- gated RMSNorm -> bf16 ----------------
__global__ __launch_bounds__(256) void k_norm(
    const float* __restrict__ Y, const u16* __restrict__ Pb,
    const float* __restrict__ nw, u16* __restrict__ hb)
{
  int row = blockIdx.x, t = threadIdx.x;
  int w = t>>6, lane = t&63;
  float hv[16];
  float ss = 0.f;
#pragma unroll
  for (int r=0;r<4;r++){
    int idx = (r*256+t)*4;
    f32x4 yv = *(const f32x4*)&Y[(long)row*INTER + idx];
    u16x4 gv = *(const u16x4*)&Pb[(long)row*NPAD + idx];
#pragma unroll
    for (int jj=0;jj<4;jj++){
      float g = b2f(gv[jj]);
      float hh = yv[jj] * g / (1.f+__expf(-g));
      hv[r*4+jj] = hh;
      ss += hh*hh;
    }
  }
  for (int off=32; off; off>>=1) ss += __shfl_down(ss, off);
  __shared__ float sm[4];
  if (lane==0) sm[w]=ss;
  __syncthreads();
  float tot = sm[0]+sm[1]+sm[2]+sm[3];
  float sc = rsqrtf(tot/4096.f + 1e-6f);
#pragma unroll
  for (int r=0;r<4;r++){
    int idx = (r*256+t)*4;
    f32x4 nv = *(const f32x4*)&nw[idx];
    u16x4 o;
#pragma unroll
    for (int jj=0;jj<4;jj++) o[jj] = f2b(hv[r*4+jj]*nv[jj]*sc);
    *(u16x4*)&hb[(long)row*INTER + idx] = o;
  }
}

// ---------------- launch ----------------
extern "C" void kernel_launch(void* const* d_in, const int* in_sizes, int n_in,
                              void* d_out, int out_size, void* d_ws, size_t ws_size,
                              hipStream_t stream)
{
  (void)in_sizes; (void)n_in;
  const float* X    = (const float*)d_in[0];
  const float* W1   = (const float*)d_in[1];
  const float* CW   = (const float*)d_in[2];
  const float* CB   = (const float*)d_in[3];
  const float* DTB  = (const float*)d_in[4];
  const float* ALOG = (const float*)d_in[5];
  const float* DD   = (const float*)d_in[6];
  const float* NW   = (const float*)d_in[7];
  const float* W2   = (const float*)d_in[8];
  float* out = (float*)d_out;
  char* ws = (char*)d_ws;

  constexpr long OFF_XB    = 0L;
  constexpr long OFF_WB    = 16777216L;
  constexpr long OFF_Y     = 0L;
  constexpr long OFF_P01   = 0L;           // 2 x 4096x2048 fp32 = 67,108,864
  constexpr long OFF_ST    = 67108864L;
  constexpr long OFF_HB    = 67108864L;
  constexpr long OFF_W2B   = 100663296L;
  constexpr long OFF_PB    = 117440512L;   // 4096 x 8704 bf16 = 71,303,168
  constexpr long OFF_DTRAW = 188743680L;   // 4096 x 64 fp32 = 1,048,576
  constexpr long OFF_XBC   = 189792256L;
  constexpr long OFF_DT    = 225443840L;
  constexpr long OFF_CS    = 226492416L;
  constexpr long OFF_CDEC  = 227540992L;
  constexpr long OFF_G     = 227545088L;
  constexpr long OFF_PREV  = 231739392L;
  constexpr long WS_NEEDED = 248516608L;

  if ((long)ws_size < WS_NEEDED){
    hipMemsetAsync(d_out, 0, (size_t)out_size*4, stream);
    return;
  }

  u16*   Xb    = (u16*)(ws + OFF_XB);
  u16*   Wb    = (u16*)(ws + OFF_WB);
  u16*   W2b   = (u16*)(ws + OFF_W2B);
  u16*   Pb    = (u16*)(ws + OFF_PB);
  float* DTraw = (float*)(ws + OFF_DTRAW);
  u16*   XBCb  = (u16*)(ws + OFF_XBC);
  float* dtb   = (float*)(ws + OFF_DT);
  float* csb   = (float*)(ws + OFF_CS);
  float* cdec  = (float*)(ws + OFF_CDEC);
  float* G     = (float*)(ws + OFF_G);
  float* st    = (float*)(ws + OFF_ST);
  u16*   prevb = (u16*)(ws + OFF_PREV);
  float* Y     = (float*)(ws + OFF_Y);
  float* P01   = (float*)(ws + OFF_P01);
  u16*   hb    = (u16*)(ws + OFF_HB);

  // fused converts: X (8192 blocks) | W1 + pad (17408) | W2 (8192)
  k_cvt3<<<33792, 256, 0, stream>>>(X, W1, W2, Xb, Wb, W2b);

  // in_proj: (4096x2048) @ (8704x2048)^T -> Pb bf16 (ld 8704) + DTraw fp32 side-store
  // NEW: m201-faithful quadrant schedule
  k_gemmq<0><<<dim3(544,1), 512, 0, stream>>>(Xb, Wb, Pb, DTraw, 2048, 2048, NPAD, 2048, 16, 0L);

  // conv + silu
  k_conv<<<8704, 256, 0, stream>>>(Pb, CW, CB, XBCb);

  // dt / a / cumsum
  k_dtcs<<<1024, 256, 0, stream>>>(DTraw, DTB, ALOG, dtb, csb, cdec);

  // G[bc] = C @ B^T  (256x256x128 per (b,c))
  k_gemm_bt<1><<<dim3(2,2,16), 256, 0, stream>>>(XBCb + INTER + DSTATE, XBCb + INTER, G, nullptr,
      CONVD, CONVD, 256, 128, 256L*CONVD, 256L*CONVD, 65536L, 0);

  // chunk states (MFMA)
  k_states<<<1024, 256, 0, stream>>>(XBCb, dtb, csb, st);

  // inter-chunk scan (x4 vectorized)
  k_scan<<<1024, 256, 0, stream>>>(st, cdec, prevb);

  // Y = Y_diag + Y_off + D*x
  k_ydiag<<<1024, 256, 0, stream>>>(XBCb, G, prevb, dtb, csb, DD, Y);

  // gated RMSNorm -> bf16
  k_norm<<<4096, 256, 0, stream>>>(Y, Pb, NW, hb);

  // out_proj split-K=2: (4096x4096) @ (2048x4096)^T -> partials P0,P1 -> add
  k_gemm8<1><<<dim3(128,2), 512, 0, stream>>>(hb, W2b, P01, nullptr, 4096, 4096, 2048, 2048, 16, 8388608L);
  k_add<<<8192, 256, 0, stream>>>(P01, out, 8388608L);
}

// Round 11
// 595.439 us; speedup vs baseline: 1.0263x; 1.0263x over previous
//
#include <hip/hip_runtime.h>

#define DEV __device__ __forceinline__

typedef unsigned short u16;
typedef unsigned int u32;
typedef __attribute__((ext_vector_type(4))) float f32x4;
typedef __attribute__((ext_vector_type(8))) u16 u16x8;
typedef __attribute__((ext_vector_type(4))) u16 u16x4;
typedef __attribute__((ext_vector_type(8))) __bf16 bf16x8;

#define INTER 4096
#define DSTATE 128
#define CONVD 4352
#define NPAD 8704
#define NROWS 4096

DEV float b2f(u16 u){ union{u32 i; float f;} v; v.i = ((u32)u)<<16; return v.f; }
DEV u16 f2b(float f){ union{u32 i; float f;} v; v.f = f; u32 r = v.i + 0x7fffu + ((v.i>>16)&1u); return (u16)(r>>16); }

typedef const __attribute__((address_space(1))) u32 gas_u32;
typedef __attribute__((address_space(3))) u32 las_u32;
DEV void gl_lds16(const u16* g, u16* l){
  __builtin_amdgcn_global_load_lds((gas_u32*)g, (las_u32*)l, 16, 0, 0);
}

// ---------------- fused f32 -> bf16 converts (X, W1 with zero-pad, W2) ----------------
__global__ __launch_bounds__(256) void k_cvt3(
    const float* __restrict__ X, const float* __restrict__ W1, const float* __restrict__ W2,
    u16* __restrict__ Xb, u16* __restrict__ Wb, u16* __restrict__ W2b)
{
  long b = blockIdx.x;
  const float* src; u16* dst; long n, base;
  if (b < 8192)       { src = X;  dst = Xb;  n = 8388608L;  base = b*1024L; }
  else if (b < 25600) { src = W1; dst = Wb;  n = 17432576L; base = (b-8192)*1024L; }
  else                { src = W2; dst = W2b; n = 8388608L;  base = (b-25600)*1024L; }
  long i = base + (long)threadIdx.x*4;
  u16x4 o;
  if (i < n){
    f32x4 v = *(const f32x4*)&src[i];
    o[0]=f2b(v[0]); o[1]=f2b(v[1]); o[2]=f2b(v[2]); o[3]=f2b(v[3]);
  } else {
    o[0]=0; o[1]=0; o[2]=0; o[3]=0;
  }
  *(u16x4*)&dst[i] = o;
}

// ================= 256x256 BT GEMM, 128KB, SGB-interleaved (R7 proven) — in_proj =================
// NOTE (R8 lesson): acc[8][4]=128 regs requires <=2 waves/SIMD; do NOT raise occupancy arg.
template<int EPI>
__global__ __launch_bounds__(512, 2) void k_gemm8(
    const u16* __restrict__ A, const u16* __restrict__ B,
    void* __restrict__ C0, float* __restrict__ C1,
    int lda, int ldb, int ldc, int K, int NTM, long sCz)
{
  __shared__ __align__(16) char smem[131072];
  const int t = threadIdx.x, lane = t & 63, w = t >> 6;
  const int wm = w >> 2, wn = w & 3, w64 = w * 64;
  const int NT = K >> 6, NIT = NT >> 1;
  const int z = blockIdx.y;

  const int nwg = gridDim.x;
  const int orig = blockIdx.x;
  const int wg = (orig & 7) * (nwg >> 3) + (orig >> 3);
  const int mt = wg % NTM, nt = wg / NTM;     // nt-major: A streams, B panels L2-resident

  const u16* Ab = A + (long)mt * 256 * lda + (long)z * K;
  const u16* Bb = B + (long)nt * 256 * ldb + (long)z * K;

  const int laneoff = (lane & 15) * 64 + (lane >> 4) * 16;
  const int lo = laneoff ^ (((laneoff >> 9) & 1) << 5);

  long aoff[2], boff[2];
#pragma unroll
  for (int q = 0; q < 2; q++) {
    int u = t + q * 512;
    int up = u ^ (((u >> 5) & 1) << 1);          // inverse st_16x32 swizzle on 16B chunks
    int row = (up >> 6) * 16 + ((up & 63) >> 2);
    int c8 = (up & 3) * 8;
    aoff[q] = (long)row * lda + c8;
    boff[q] = (long)row * ldb + c8;
  }

  f32x4 acc[8][4];
#pragma unroll
  for (int i=0;i<8;i++)
#pragma unroll
    for (int j=0;j<4;j++) acc[i][j] = (f32x4){0.f,0.f,0.f,0.f};

#define SA(BUF,KH,KT) do{ long kb_ = (long)(KT)*64 + (KH)*32; \
    gl_lds16(Ab + aoff[0] + kb_, (u16*)(smem + (BUF)*65536 + (KH)*16384 + w64*16)); \
    gl_lds16(Ab + aoff[1] + kb_, (u16*)(smem + (BUF)*65536 + (KH)*16384 + 8192 + w64*16)); }while(0)
#define SB(BUF,KH,KT) do{ long kb_ = (long)(KT)*64 + (KH)*32; \
    gl_lds16(Bb + boff[0] + kb_, (u16*)(smem + (BUF)*65536 + 32768 + (KH)*16384 + w64*16)); \
    gl_lds16(Bb + boff[1] + kb_, (u16*)(smem + (BUF)*65536 + 32768 + (KH)*16384 + 8192 + w64*16)); }while(0)

// VM: 0=none, 1=vmcnt(8), 2=vmcnt(4), 3=vmcnt(0).  HASV: stage present (pin VMEM group).
#define SPHASE(BUF,KH,STMT,VM,HASV) do{ \
    const char* pa_ = smem + (BUF)*65536 + (KH)*16384; \
    const char* pb_ = smem + (BUF)*65536 + 32768 + (KH)*16384; \
    STMT; \
    bf16x8 a_[8], b_[4]; \
    _Pragma("unroll") \
    for (int j_=0;j_<4;j_++) b_[j_] = *(const bf16x8*)(pb_ + (wn*4+j_)*1024 + lo); \
    _Pragma("unroll") \
    for (int m_=0;m_<8;m_++) a_[m_] = *(const bf16x8*)(pa_ + (wm*8+m_)*1024 + lo); \
    __builtin_amdgcn_s_setprio(1); \
    _Pragma("unroll") \
    for (int m_=0;m_<8;m_++) \
      _Pragma("unroll") \
      for (int j_=0;j_<4;j_++) \
        acc[m_][j_] = __builtin_amdgcn_mfma_f32_16x16x32_bf16(a_[m_], b_[j_], acc[m_][j_], 0,0,0); \
    __builtin_amdgcn_s_setprio(0); \
    /* pinned schedule: DSx6 (B0-3,A0,A1) | VMEMx4 stage | 6x{MFMAx4, DSx1} | MFMAx8 */ \
    __builtin_amdgcn_sched_group_barrier(0x100, 6, 0); \
    if (HASV) __builtin_amdgcn_sched_group_barrier(0x010, 4, 0); \
    _Pragma("unroll") \
    for (int g_=0; g_<6; ++g_){ \
      __builtin_amdgcn_sched_group_barrier(0x008, 4, 0); \
      __builtin_amdgcn_sched_group_barrier(0x100, 1, 0); \
    } \
    __builtin_amdgcn_sched_group_barrier(0x008, 8, 0); \
    if ((VM)==1) asm volatile("s_waitcnt vmcnt(8)":::"memory"); \
    if ((VM)==2) asm volatile("s_waitcnt vmcnt(4)":::"memory"); \
    if ((VM)==3) asm volatile("s_waitcnt vmcnt(0)":::"memory"); \
    asm volatile("s_barrier":::"memory"); \
  }while(0)

  // prologue: tile0 (both halves) + tile1 kh0  -> 12 loads/wave
  SA(0,0,0); SB(0,0,0); SA(0,1,0); SB(0,1,0); SA(1,0,1); SB(1,0,1);
  asm volatile("s_waitcnt vmcnt(8)":::"memory");
  asm volatile("s_barrier":::"memory");

  for (int it = 0; it < NIT-1; ++it) {
    int t1 = 2*it+1, t2 = 2*it+2, t3 = 2*it+3;
    SPHASE(0,0, { SA(1,1,t1); SB(1,1,t1); }, 1, 1);
    SPHASE(0,1, { SA(0,0,t2); SB(0,0,t2); }, 1, 1);
    SPHASE(1,0, { SA(0,1,t2); SB(0,1,t2); }, 1, 1);
    SPHASE(1,1, { SA(1,0,t3); SB(1,0,t3); }, 1, 1);
  }
  { // final iteration (tiles NT-2, NT-1)
    int tl = NT-1;
    SPHASE(0,0, { SA(1,1,tl); SB(1,1,tl); }, 1, 1);
    SPHASE(0,1, ((void)0), 2, 0);
    SPHASE(1,0, ((void)0), 3, 0);
    SPHASE(1,1, ((void)0), 0, 0);
  }
#undef SA
#undef SB
#undef SPHASE

#pragma unroll
  for (int i=0;i<8;i++)
#pragma unroll
    for (int j=0;j<4;j++)
#pragma unroll
      for (int r=0;r<4;r++){
        int gm = mt*256 + wm*128 + i*16 + (lane>>4)*4 + r;
        int gn = nt*256 + wn*64 + j*16 + (lane&15);
        float v = acc[i][j][r];
        if (EPI==0){
          ((u16*)C0)[(long)gm*ldc + gn] = f2b(v);
          if (gn >= 8448 && gn < 8512) C1[(long)gm*64 + (gn-8448)] = v;
        } else {
          ((float*)C0)[(long)z*sCz + (long)gm*ldc + gn] = v;
        }
      }
}

// ================= 256x128 BT GEMM — out_proj (no split-K, fp32 direct store) =================
// 512 threads, 8 waves 2Mx4N, wave-tile 128x32, acc[8][2].  LDS 96KB:
// per buf 48KB = A(kh0 16K | kh1 16K) + B(kh0 8K | kh1 8K); same st_16x32 swizzle.
// Half-tile = 3 gl_lds/wave (2 A + 1 B); proven gemm8 ledger rescaled:
// steady vmcnt(6) (=2 half-tiles), epilogue vmcnt(3) -> vmcnt(0).
__global__ __launch_bounds__(512, 2) void k_gemmN(
    const u16* __restrict__ A, const u16* __restrict__ B, float* __restrict__ C0,
    int lda, int ldb, int ldc, int K, int NTM)
{
  __shared__ __align__(16) char smem[98304];
  const int t = threadIdx.x, lane = t & 63, w = t >> 6;
  const int wm = w >> 2, wn = w & 3, w64 = w * 64;
  const int NT = K >> 6, NIT = NT >> 1;

  const int nwg = gridDim.x;
  const int orig = blockIdx.x;
  const int wg = (orig & 7) * (nwg >> 3) + (orig >> 3);
  const int mt = wg % NTM, nt = wg / NTM;

  const u16* Ab = A + (long)mt * 256 * lda;
  const u16* Bb = B + (long)nt * 128 * ldb;

  const int laneoff = (lane & 15) * 64 + (lane >> 4) * 16;
  const int lo = laneoff ^ (((laneoff >> 9) & 1) << 5);

  long aoff[2];
#pragma unroll
  for (int q = 0; q < 2; q++) {
    int u = t + q * 512;
    int up = u ^ (((u >> 5) & 1) << 1);
    int row = (up >> 6) * 16 + ((up & 63) >> 2);
    int c8 = (up & 3) * 8;
    aoff[q] = (long)row * lda + c8;
  }
  long boff;
  {
    int up = t ^ (((t >> 5) & 1) << 1);
    int row = (up >> 6) * 16 + ((up & 63) >> 2);   // 0..127
    int c8 = (up & 3) * 8;
    boff = (long)row * ldb + c8;
  }

  f32x4 acc[8][2];
#pragma unroll
  for (int i=0;i<8;i++)
#pragma unroll
    for (int j=0;j<2;j++) acc[i][j] = (f32x4){0.f,0.f,0.f,0.f};

#define SAN(BUF,KH,KT) do{ long kb_ = (long)(KT)*64 + (KH)*32; \
    gl_lds16(Ab + aoff[0] + kb_, (u16*)(smem + (BUF)*49152 + (KH)*16384 + w64*16)); \
    gl_lds16(Ab + aoff[1] + kb_, (u16*)(smem + (BUF)*49152 + (KH)*16384 + 8192 + w64*16)); }while(0)
#define SBN(BUF,KH,KT) do{ long kb_ = (long)(KT)*64 + (KH)*32; \
    gl_lds16(Bb + boff + kb_, (u16*)(smem + (BUF)*49152 + 32768 + (KH)*8192 + w64*16)); }while(0)

// VM: 0=none, 1=vmcnt(6), 2=vmcnt(3), 3=vmcnt(0)
#define NPHASE(BUF,KH,STMT,VM) do{ \
    const char* pa_ = smem + (BUF)*49152 + (KH)*16384; \
    const char* pb_ = smem + (BUF)*49152 + 32768 + (KH)*8192; \
    STMT; \
    bf16x8 a_[8], b_[2]; \
    _Pragma("unroll") \
    for (int j_=0;j_<2;j_++) b_[j_] = *(const bf16x8*)(pb_ + (wn*2+j_)*1024 + lo); \
    _Pragma("unroll") \
    for (int m_=0;m_<8;m_++) a_[m_] = *(const bf16x8*)(pa_ + (wm*8+m_)*1024 + lo); \
    __builtin_amdgcn_s_setprio(1); \
    _Pragma("unroll") \
    for (int m_=0;m_<8;m_++) \
      _Pragma("unroll") \
      for (int j_=0;j_<2;j_++) \
        acc[m_][j_] = __builtin_amdgcn_mfma_f32_16x16x32_bf16(a_[m_], b_[j_], acc[m_][j_], 0,0,0); \
    __builtin_amdgcn_s_setprio(0); \
    if ((VM)==1) asm volatile("s_waitcnt vmcnt(6)":::"memory"); \
    if ((VM)==2) asm volatile("s_waitcnt vmcnt(3)":::"memory"); \
    if ((VM)==3) asm volatile("s_waitcnt vmcnt(0)":::"memory"); \
    asm volatile("s_barrier":::"memory"); \
  }while(0)

  // prologue: tile0 (both halves) + tile1 kh0 -> 9 loads/wave
  SAN(0,0,0); SBN(0,0,0); SAN(0,1,0); SBN(0,1,0); SAN(1,0,1); SBN(1,0,1);
  asm volatile("s_waitcnt vmcnt(6)":::"memory");
  asm volatile("s_barrier":::"memory");

  for (int it = 0; it < NIT-1; ++it) {
    int t1 = 2*it+1, t2 = 2*it+2, t3 = 2*it+3;
    NPHASE(0,0, { SAN(1,1,t1); SBN(1,1,t1); }, 1);
    NPHASE(0,1, { SAN(0,0,t2); SBN(0,0,t2); }, 1);
    NPHASE(1,0, { SAN(0,1,t2); SBN(0,1,t2); }, 1);
    NPHASE(1,1, { SAN(1,0,t3); SBN(1,0,t3); }, 1);
  }
  { // final iteration (tiles NT-2, NT-1)
    int tl = NT-1;
    NPHASE(0,0, { SAN(1,1,tl); SBN(1,1,tl); }, 1);
    NPHASE(0,1, ((void)0), 2);
    NPHASE(1,0, ((void)0), 3);
    NPHASE(1,1, ((void)0), 0);
  }
#undef SAN
#undef SBN
#undef NPHASE

#pragma unroll
  for (int i=0;i<8;i++)
#pragma unroll
    for (int j=0;j<2;j++)
#pragma unroll
      for (int r=0;r<4;r++){
        int gm = mt*256 + wm*128 + i*16 + (lane>>4)*4 + r;
        int gn = nt*128 + wn*32 + j*16 + (lane&15);
        C0[(long)gm*ldc + gn] = acc[i][j][r];
      }
}

// ---------------- 128x128 BT GEMM (kept for the small per-chunk G = C@B^T) ----------------
template<int EPI>
__global__ __launch_bounds__(256) void k_gemm_bt(
    const u16* __restrict__ A, const u16* __restrict__ B,
    void* __restrict__ C0, float* __restrict__ C1,
    int lda, int ldb, int ldc, int K,
    long sAz, long sBz, long sCz, int auxcol)
{
  __shared__ u16 As[128*64];
  __shared__ u16 Bs[128*64];
  const int t = threadIdx.x, w = t>>6, lane = t&63;
  const int mt = blockIdx.y, nt = blockIdx.x, z = blockIdx.z;
  const u16* Ab = A + (long)z*sAz + (long)mt*128*lda;
  const u16* Bb = B + (long)z*sBz + (long)nt*128*ldb;
  const int wm = w>>1, wn = w&1;
  f32x4 acc[4][4];
#pragma unroll
  for (int i=0;i<4;i++)
#pragma unroll
    for (int j=0;j<4;j++) acc[i][j] = (f32x4){0.f,0.f,0.f,0.f};
  const int srow = (lane>>3), scol = (lane&7)*8;
  for (int k0=0; k0<K; k0+=64){
#pragma unroll
    for (int i=0;i<4;i++){
      int ch = w*4+i;
      int row = ch*8 + srow;
      gl_lds16(Ab + (long)row*lda + k0 + scol, As + ch*512);
      gl_lds16(Bb + (long)row*ldb + k0 + scol, Bs + ch*512);
    }
    __syncthreads();
#pragma unroll
    for (int kk=0;kk<2;kk++){
      bf16x8 af[4], bfr[4];
#pragma unroll
      for (int i=0;i<4;i++) af[i]  = *(const bf16x8*)&As[(wm*64+i*16+(lane&15))*64 + kk*32 + (lane>>4)*8];
#pragma unroll
      for (int j=0;j<4;j++) bfr[j] = *(const bf16x8*)&Bs[(wn*64+j*16+(lane&15))*64 + kk*32 + (lane>>4)*8];
#pragma unroll
      for (int i=0;i<4;i++)
#pragma unroll
        for (int j=0;j<4;j++)
          acc[i][j] = __builtin_amdgcn_mfma_f32_16x16x32_bf16(af[i], bfr[j], acc[i][j], 0,0,0);
    }
    __syncthreads();
  }
#pragma unroll
  for (int i=0;i<4;i++)
#pragma unroll
    for (int j=0;j<4;j++)
#pragma unroll
      for (int r=0;r<4;r++){
        int gm = mt*128 + wm*64 + i*16 + (lane>>4)*4 + r;
        int gn = nt*128 + wn*64 + j*16 + (lane&15);
        float v = acc[i][j][r];
        if (EPI==0){
          ((u16*)C0)[(long)gm*ldc + gn] = f2b(v);
          if (gn >= auxcol) C1[(long)gm*128 + (gn-auxcol)] = v;
        } else {
          ((float*)C0)[(long)z*sCz + (long)gm*ldc + gn] = v;
        }
      }
}

// ---------------- depthwise causal conv (K=4) + silu ----------------
__global__ __launch_bounds__(256) void k_conv(
    const u16* __restrict__ Pb, const float* __restrict__ cw, const float* __restrict__ cb,
    u16* __restrict__ XBC)
{
  long tg = (long)blockIdx.x*256 + threadIdx.x;
  int row = (int)(tg/544);
  int ch0 = (int)(tg%544)*8;
  int s = row & 2047;
  float acc[8];
#pragma unroll
  for (int j=0;j<8;j++) acc[j] = cb[ch0+j];
#pragma unroll
  for (int k=0;k<4;k++){
    int sk = s - 3 + k;
    if (sk >= 0){
      u16x8 v = *(const u16x8*)&Pb[(long)(row-3+k)*NPAD + INTER + ch0];
#pragma unroll
      for (int j=0;j<8;j++) acc[j] += b2f(v[j]) * cw[(ch0+j)*4 + k];
    }
  }
  u16x8 o;
#pragma unroll
  for (int j=0;j<8;j++){ float x = acc[j]; o[j] = f2b(x/(1.f+__expf(-x))); }
  *(u16x8*)&XBC[(long)row*CONVD + ch0] = o;
}

// ---------------- dt = softplus(dtraw + bias), a = dt*A, cumsum(a) per (b,h,chunk) ----------------
__global__ __launch_bounds__(256) void k_dtcs(
    const float* __restrict__ DTraw, const float* __restrict__ dt_bias,
    const float* __restrict__ A_log,
    float* __restrict__ dtb, float* __restrict__ csb, float* __restrict__ cdec)
{
  __shared__ float sc[256];
  int bid = blockIdx.x;          // ((b*64+h)*8 + c)
  int bh = bid>>3, c = bid&7;
  int h = bh & 63, b = bh>>6;
  int l = threadIdx.x;
  int row = (b*8+c)*256 + l;
  float x = DTraw[(long)row*64 + h] + dt_bias[h];
  float dt = (x > 20.f) ? x : log1pf(__expf(x));
  float a = dt * (-__expf(A_log[h]));
  dtb[(long)row*64 + h] = dt;
  sc[l] = a; __syncthreads();
  for (int off=1; off<256; off<<=1){
    float v = (l>=off) ? sc[l-off] : 0.f;
    __syncthreads();
    sc[l] += v;
    __syncthreads();
  }
  float cs = sc[l];
  csb[(long)bid*256 + l] = cs;
  if (l==255) cdec[bid] = __expf(cs);
}

// ---------------- chunk states via MFMA: states[p][n] = sum_l xdt[l][p]*decay[l]*B[l][n] ----------------
__global__ __launch_bounds__(256) void k_states(
    const u16* __restrict__ XBC, const float* __restrict__ dtb, const float* __restrict__ csb,
    float* __restrict__ states)
{
  __shared__ u16 xsT[64*136];
  __shared__ u16 bsT[128*136];
  __shared__ float dtl[128], del[128];
  int bid = blockIdx.x;            // (b*8+c)*64 + h
  int h = bid & 63, bc = bid >> 6;
  int b = bc>>3, c = bc&7;
  int rowb = bc*256;
  int t = threadIdx.x, w = t>>6, lane = t&63;
  int csbase = ((b*64+h)*8 + c)*256;
  float clast = csb[csbase + 255];
  f32x4 acc[8];
#pragma unroll
  for (int j=0;j<8;j++) acc[j] = (f32x4){0.f,0.f,0.f,0.f};
  for (int half=0; half<2; half++){
    int lbase = half*128;
    if (t < 128){
      dtl[t] = dtb[(long)(rowb+lbase+t)*64 + h];
      del[t] = __expf(clast - csb[csbase + lbase + t]);
    }
    __syncthreads();
#pragma unroll
    for (int it=0; it<4; it++){
      int id = it*256+t;
      int p8 = id&7, l = id>>3;
      u16x8 v = *(const u16x8*)&XBC[(long)(rowb+lbase+l)*CONVD + h*64 + p8*8];
      float d = dtl[l];
#pragma unroll
      for (int j=0;j<8;j++) xsT[(p8*8+j)*136 + l] = f2b(b2f(v[j])*d);
    }
#pragma unroll
    for (int it=0; it<8; it++){
      int id = it*256+t;
      int n8 = id&15, l = id>>4;
      u16x8 v = *(const u16x8*)&XBC[(long)(rowb+lbase+l)*CONVD + INTER + n8*8];
      float d = del[l];
#pragma unroll
      for (int j=0;j<8;j++) bsT[(n8*8+j)*136 + l] = f2b(b2f(v[j])*d);
    }
    __syncthreads();
#pragma unroll
    for (int ks=0; ks<4; ks++){
      bf16x8 af = *(const bf16x8*)&xsT[(w*16 + (lane&15))*136 + ks*32 + (lane>>4)*8];
#pragma unroll
      for (int j=0;j<8;j++){
        bf16x8 bf = *(const bf16x8*)&bsT[(j*16 + (lane&15))*136 + ks*32 + (lane>>4)*8];
        acc[j] = __builtin_amdgcn_mfma_f32_16x16x32_bf16(af, bf, acc[j], 0,0,0);
      }
    }
    __syncthreads();
  }
  float* outp = states + (long)bid*8192;
#pragma unroll
  for (int j=0;j<8;j++)
#pragma unroll
    for (int r=0;r<4;r++){
      int gm = w*16 + (lane>>4)*4 + r;
      int gn = j*16 + (lane&15);
      outp[gm*128 + gn] = acc[j][r];
    }
}

// ---------------- inter-chunk scan (vectorized x4) ----------------
__global__ __launch_bounds__(256) void k_scan(
    const float* __restrict__ states, const float* __restrict__ cdec,
    u16* __restrict__ prevb)
{
  int bid = blockIdx.x;            // (b*64+h)*8 + sub
  int bh = bid>>3, sub = bid&7;
  int b = bh>>6, h = bh&63;
  int e = (sub*256 + threadIdx.x)*4;
  f32x4 carry = (f32x4){0.f,0.f,0.f,0.f};
#pragma unroll
  for (int c=0;c<8;c++){
    long idx = ((long)((b*8+c)*64 + h))*8192 + e;
    u16x4 o;
    o[0]=f2b(carry[0]); o[1]=f2b(carry[1]); o[2]=f2b(carry[2]); o[3]=f2b(carry[3]);
    *(u16x4*)&prevb[idx] = o;
    f32x4 s = *(const f32x4*)&states[idx];
    float d = cdec[bh*8 + c];
    carry = carry*d + s;
  }
}

// ---------------- fused Y_diag + Y_off + D*x per (b,c,h) ----------------
__global__ __launch_bounds__(256) void k_ydiag(
    const u16* __restrict__ XBC, const float* __restrict__ G,
    const u16* __restrict__ prevb, const float* __restrict__ dtb,
    const float* __restrict__ csb, const float* __restrict__ Dp,
    float* __restrict__ Y)
{
  __shared__ u16 PA[256*72];
  __shared__ u16 PB[64*72];
  __shared__ float csl[256];
  int bid = blockIdx.x;
  int h = bid&63, bc = bid>>6;
  int b = bc>>3, c = bc&7;
  int rowb = bc*256;
  int t = threadIdx.x, w = t>>6, lane = t&63;
  int csbase = ((b*64+h)*8 + c)*256;
  csl[t] = csb[csbase + t];
  const float* Gz = G + (long)bc*65536;
  f32x4 ad[4][4], ao[4][4];
#pragma unroll
  for (int i=0;i<4;i++)
#pragma unroll
    for (int j=0;j<4;j++){ ad[i][j]=(f32x4){0.f,0.f,0.f,0.f}; ao[i][j]=(f32x4){0.f,0.f,0.f,0.f}; }
  __syncthreads();
  for (int sl6=0; sl6<6; sl6++){
    if (sl6 < 4){
      int s0 = sl6*64;
#pragma unroll
      for (int r=0;r<8;r++){
        int id = r*256+t;
        int l = id>>3, sc8 = (id&7)*8;
        f32x4 g0 = *(const f32x4*)&Gz[l*256 + s0+sc8];
        f32x4 g1 = *(const f32x4*)&Gz[l*256 + s0+sc8+4];
        float cl = csl[l];
        u16x8 o;
#pragma unroll
        for (int jj=0;jj<4;jj++){
          int s = s0+sc8+jj;
          o[jj] = (s<=l) ? f2b(g0[jj]*__expf(cl - csl[s])) : (u16)0;
        }
#pragma unroll
        for (int jj=4;jj<8;jj++){
          int s = s0+sc8+jj;
          o[jj] = (s<=l) ? f2b(g1[jj-4]*__expf(cl - csl[s])) : (u16)0;
        }
        *(u16x8*)&PA[l*72 + sc8] = o;
      }
#pragma unroll
      for (int r=0;r<16;r++){
        int id = r*256+t;
        int p = id&63, ks = id>>6;
        float xv = b2f(XBC[(long)(rowb+s0+ks)*CONVD + h*64 + p]);
        float d = dtb[(long)(rowb+s0+ks)*64 + h];
        PB[p*72 + ks] = f2b(xv*d);
      }
    } else {
      int n0 = (sl6-4)*64;
#pragma unroll
      for (int r=0;r<8;r++){
        int id = r*256+t;
        int l = id>>3, kc = (id&7)*8;
        u16x8 v = *(const u16x8*)&XBC[(long)(rowb+l)*CONVD + INTER + DSTATE + n0 + kc];
        *(u16x8*)&PA[l*72 + kc] = v;
      }
#pragma unroll
      for (int r=0;r<2;r++){
        int id = r*256+t;
        int p = id>>3, kc = (id&7)*8;
        u16x8 v = *(const u16x8*)&prevb[((long)bid*64 + p)*128 + n0 + kc];
        *(u16x8*)&PB[p*72 + kc] = v;
      }
    }
    __syncthreads();
#pragma unroll
    for (int kk=0;kk<2;kk++){
      bf16x8 af[4], bfr[4];
#pragma unroll
      for (int i=0;i<4;i++) af[i]  = *(const bf16x8*)&PA[(w*64+i*16+(lane&15))*72 + kk*32 + (lane>>4)*8];
#pragma unroll
      for (int j=0;j<4;j++) bfr[j] = *(const bf16x8*)&PB[(j*16+(lane&15))*72 + kk*32 + (lane>>4)*8];
      if (sl6 < 4){
#pragma unroll
        for (int i=0;i<4;i++)
#pragma unroll
          for (int j=0;j<4;j++)
            ad[i][j] = __builtin_amdgcn_mfma_f32_16x16x32_bf16(af[i], bfr[j], ad[i][j], 0,0,0);
      } else {
#pragma unroll
        for (int i=0;i<4;i++)
#pragma unroll
          for (int j=0;j<4;j++)
            ao[i][j] = __builtin_amdgcn_mfma_f32_16x16x32_bf16(af[i], bfr[j], ao[i][j], 0,0,0);
      }
    }
    __syncthreads();
  }
  float Dh = Dp[h];
#pragma unroll
  for (int i=0;i<4;i++)
#pragma unroll
    for (int j=0;j<4;j++)
#pragma unroll
      for (int r=0;r<4;r++){
        int l = w*64 + i*16 + (lane>>4)*4 + r;
        int p = j*16 + (lane&15);
        float e = __expf(csl[l]);
        float xv = b2f(XBC[(long)(rowb+l)*CONVD + h*64 + p]);
        float v = ad[i][j][r] + e*ao[i][j][r] + Dh*xv;
        Y[(long)(rowb+l)*INTER + h*64 + p] = v;
      }
}

// ---------------- gated RMSNorm -> bf16 ----------------
__global__ __launch_bounds__(256) void k_norm(
    const float* __restrict__ Y, const u16* __restrict__ Pb,
    const float* __restrict__ nw, u16* __restrict__ hb)
{
  int row = blockIdx.x, t = threadIdx.x;
  int w = t>>6, lane = t&63;
  float hv[16];
  float ss = 0.f;
#pragma unroll
  for (int r=0;r<4;r++){
    int idx = (r*256+t)*4;
    f32x4 yv = *(const f32x4*)&Y[(long)row*INTER + idx];
    u16x4 gv = *(const u16x4*)&Pb[(long)row*NPAD + idx];
#pragma unroll
    for (int jj=0;jj<4;jj++){
      float g = b2f(gv[jj]);
      float hh = yv[jj] * g / (1.f+__expf(-g));
      hv[r*4+jj] = hh;
      ss += hh*hh;
    }
  }
  for (int off=32; off; off>>=1) ss += __shfl_down(ss, off);
  __shared__ float sm[4];
  if (lane==0) sm[w]=ss;
  __syncthreads();
  float tot = sm[0]+sm[1]+sm[2]+sm[3];
  float sc = rsqrtf(tot/4096.f + 1e-6f);
#pragma unroll
  for (int r=0;r<4;r++){
    int idx = (r*256+t)*4;
    f32x4 nv = *(const f32x4*)&nw[idx];
    u16x4 o;
#pragma unroll
    for (int jj=0;jj<4;jj++) o[jj] = f2b(hv[r*4+jj]*nv[jj]*sc);
    *(u16x4*)&hb[(long)row*INTER + idx] = o;
  }
}

// ---------------- launch ----------------
extern "C" void kernel_launch(void* const* d_in, const int* in_sizes, int n_in,
                              void* d_out, int out_size, void* d_ws, size_t ws_size,
                              hipStream_t stream)
{
  (void)in_sizes; (void)n_in;
  const float* X    = (const float*)d_in[0];
  const float* W1   = (const float*)d_in[1];
  const float* CW   = (const float*)d_in[2];
  const float* CB   = (const float*)d_in[3];
  const float* DTB  = (const float*)d_in[4];
  const float* ALOG = (const float*)d_in[5];
  const float* DD   = (const float*)d_in[6];
  const float* NW   = (const float*)d_in[7];
  const float* W2   = (const float*)d_in[8];
  float* out = (float*)d_out;
  char* ws = (char*)d_ws;

  constexpr long OFF_XB    = 0L;
  constexpr long OFF_WB    = 16777216L;
  constexpr long OFF_Y     = 0L;
  constexpr long OFF_ST    = 67108864L;
  constexpr long OFF_HB    = 67108864L;
  constexpr long OFF_W2B   = 100663296L;
  constexpr long OFF_PB    = 117440512L;   // 4096 x 8704 bf16 = 71,303,168
  constexpr long OFF_DTRAW = 188743680L;   // 4096 x 64 fp32 = 1,048,576
  constexpr long OFF_XBC   = 189792256L;
  constexpr long OFF_DT    = 225443840L;
  constexpr long OFF_CS    = 226492416L;
  constexpr long OFF_CDEC  = 227540992L;
  constexpr long OFF_G     = 227545088L;
  constexpr long OFF_PREV  = 231739392L;
  constexpr long WS_NEEDED = 248516608L;

  if ((long)ws_size < WS_NEEDED){
    hipMemsetAsync(d_out, 0, (size_t)out_size*4, stream);
    return;
  }

  u16*   Xb    = (u16*)(ws + OFF_XB);
  u16*   Wb    = (u16*)(ws + OFF_WB);
  u16*   W2b   = (u16*)(ws + OFF_W2B);
  u16*   Pb    = (u16*)(ws + OFF_PB);
  float* DTraw = (float*)(ws + OFF_DTRAW);
  u16*   XBCb  = (u16*)(ws + OFF_XBC);
  float* dtb   = (float*)(ws + OFF_DT);
  float* csb   = (float*)(ws + OFF_CS);
  float* cdec  = (float*)(ws + OFF_CDEC);
  float* G     = (float*)(ws + OFF_G);
  float* st    = (float*)(ws + OFF_ST);
  u16*   prevb = (u16*)(ws + OFF_PREV);
  float* Y     = (float*)(ws + OFF_Y);
  u16*   hb    = (u16*)(ws + OFF_HB);

  // fused converts: X (8192 blocks) | W1 + pad (17408) | W2 (8192)
  k_cvt3<<<33792, 256, 0, stream>>>(X, W1, W2, Xb, Wb, W2b);

  // in_proj: (4096x2048) @ (8704x2048)^T -> Pb bf16 (ld 8704) + DTraw fp32 side-store
  k_gemm8<0><<<dim3(544,1), 512, 0, stream>>>(Xb, Wb, Pb, DTraw, 2048, 2048, NPAD, 2048, 16, 0L);

  // conv + silu
  k_conv<<<8704, 256, 0, stream>>>(Pb, CW, CB, XBCb);

  // dt / a / cumsum
  k_dtcs<<<1024, 256, 0, stream>>>(DTraw, DTB, ALOG, dtb, csb, cdec);

  // G[bc] = C @ B^T  (256x256x128 per (b,c))
  k_gemm_bt<1><<<dim3(2,2,16), 256, 0, stream>>>(XBCb + INTER + DSTATE, XBCb + INTER, G, nullptr,
      CONVD, CONVD, 256, 128, 256L*CONVD, 256L*CONVD, 65536L, 0);

  // chunk states (MFMA)
  k_states<<<1024, 256, 0, stream>>>(XBCb, dtb, csb, st);

  // inter-chunk scan (x4 vectorized)
  k_scan<<<1024, 256, 0, stream>>>(st, cdec, prevb);

  // Y = Y_diag + Y_off + D*x
  k_ydiag<<<1024, 256, 0, stream>>>(XBCb, G, prevb, dtb, csb, DD, Y);

  // gated RMSNorm -> bf16
  k_norm<<<4096, 256, 0, stream>>>(Y, Pb, NW, hb);

  // out_proj: (4096x4096) @ (2048x4096)^T -> d_out fp32, 256x128 tiles, 256 blocks, no split-K
  k_gemmN<<<256, 512, 0, stream>>>(hb, W2b, out, 4096, 4096, 2048, 4096, 16);
}

// Round 12
// 572.975 us; speedup vs baseline: 1.0666x; 1.0392x over previous
//
#include <hip/hip_runtime.h>

#define DEV __device__ __forceinline__

typedef unsigned short u16;
typedef unsigned int u32;
typedef __attribute__((ext_vector_type(4))) float f32x4;
typedef __attribute__((ext_vector_type(8))) u16 u16x8;
typedef __attribute__((ext_vector_type(4))) u16 u16x4;
typedef __attribute__((ext_vector_type(8))) __bf16 bf16x8;

#define INTER 4096
#define DSTATE 128
#define CONVD 4352
#define NPAD 8704
#define NROWS 4096

DEV float b2f(u16 u){ union{u32 i; float f;} v; v.i = ((u32)u)<<16; return v.f; }
DEV u16 f2b(float f){ union{u32 i; float f;} v; v.f = f; u32 r = v.i + 0x7fffu + ((v.i>>16)&1u); return (u16)(r>>16); }

typedef const __attribute__((address_space(1))) u32 gas_u32;
typedef __attribute__((address_space(3))) u32 las_u32;
DEV void gl_lds16(const u16* g, u16* l){
  __builtin_amdgcn_global_load_lds((gas_u32*)g, (las_u32*)l, 16, 0, 0);
}

// ---------------- fused f32 -> bf16 converts (X, W1 with zero-pad, W2) ----------------
__global__ __launch_bounds__(256) void k_cvt3(
    const float* __restrict__ X, const float* __restrict__ W1, const float* __restrict__ W2,
    u16* __restrict__ Xb, u16* __restrict__ Wb, u16* __restrict__ W2b)
{
  long b = blockIdx.x;
  const float* src; u16* dst; long n, base;
  if (b < 8192)       { src = X;  dst = Xb;  n = 8388608L;  base = b*1024L; }
  else if (b < 25600) { src = W1; dst = Wb;  n = 17432576L; base = (b-8192)*1024L; }
  else                { src = W2; dst = W2b; n = 8388608L;  base = (b-25600)*1024L; }
  long i = base + (long)threadIdx.x*4;
  u16x4 o;
  if (i < n){
    f32x4 v = *(const f32x4*)&src[i];
    o[0]=f2b(v[0]); o[1]=f2b(v[1]); o[2]=f2b(v[2]); o[3]=f2b(v[3]);
  } else {
    o[0]=0; o[1]=0; o[2]=0; o[3]=0;
  }
  *(u16x4*)&dst[i] = o;
}

// ================= 256x256 BT GEMM, 128KB, SGB-interleaved (R7 proven) — in_proj =================
// NOTE (R8 lesson): acc[8][4]=128 regs requires <=2 waves/SIMD; do NOT raise occupancy arg.
template<int EPI>
__global__ __launch_bounds__(512, 2) void k_gemm8(
    const u16* __restrict__ A, const u16* __restrict__ B,
    void* __restrict__ C0, float* __restrict__ C1,
    int lda, int ldb, int ldc, int K, int NTM, long sCz)
{
  __shared__ __align__(16) char smem[131072];
  const int t = threadIdx.x, lane = t & 63, w = t >> 6;
  const int wm = w >> 2, wn = w & 3, w64 = w * 64;
  const int NT = K >> 6, NIT = NT >> 1;
  const int z = blockIdx.y;

  const int nwg = gridDim.x;
  const int orig = blockIdx.x;
  const int wg = (orig & 7) * (nwg >> 3) + (orig >> 3);
  const int mt = wg % NTM, nt = wg / NTM;     // nt-major: A streams, B panels L2-resident

  const u16* Ab = A + (long)mt * 256 * lda + (long)z * K;
  const u16* Bb = B + (long)nt * 256 * ldb + (long)z * K;

  const int laneoff = (lane & 15) * 64 + (lane >> 4) * 16;
  const int lo = laneoff ^ (((laneoff >> 9) & 1) << 5);

  long aoff[2], boff[2];
#pragma unroll
  for (int q = 0; q < 2; q++) {
    int u = t + q * 512;
    int up = u ^ (((u >> 5) & 1) << 1);          // inverse st_16x32 swizzle on 16B chunks
    int row = (up >> 6) * 16 + ((up & 63) >> 2);
    int c8 = (up & 3) * 8;
    aoff[q] = (long)row * lda + c8;
    boff[q] = (long)row * ldb + c8;
  }

  f32x4 acc[8][4];
#pragma unroll
  for (int i=0;i<8;i++)
#pragma unroll
    for (int j=0;j<4;j++) acc[i][j] = (f32x4){0.f,0.f,0.f,0.f};

#define SA(BUF,KH,KT) do{ long kb_ = (long)(KT)*64 + (KH)*32; \
    gl_lds16(Ab + aoff[0] + kb_, (u16*)(smem + (BUF)*65536 + (KH)*16384 + w64*16)); \
    gl_lds16(Ab + aoff[1] + kb_, (u16*)(smem + (BUF)*65536 + (KH)*16384 + 8192 + w64*16)); }while(0)
#define SB(BUF,KH,KT) do{ long kb_ = (long)(KT)*64 + (KH)*32; \
    gl_lds16(Bb + boff[0] + kb_, (u16*)(smem + (BUF)*65536 + 32768 + (KH)*16384 + w64*16)); \
    gl_lds16(Bb + boff[1] + kb_, (u16*)(smem + (BUF)*65536 + 32768 + (KH)*16384 + 8192 + w64*16)); }while(0)

// VM: 0=none, 1=vmcnt(8), 2=vmcnt(4), 3=vmcnt(0).  HASV: stage present (pin VMEM group).
#define SPHASE(BUF,KH,STMT,VM,HASV) do{ \
    const char* pa_ = smem + (BUF)*65536 + (KH)*16384; \
    const char* pb_ = smem + (BUF)*65536 + 32768 + (KH)*16384; \
    STMT; \
    bf16x8 a_[8], b_[4]; \
    _Pragma("unroll") \
    for (int j_=0;j_<4;j_++) b_[j_] = *(const bf16x8*)(pb_ + (wn*4+j_)*1024 + lo); \
    _Pragma("unroll") \
    for (int m_=0;m_<8;m_++) a_[m_] = *(const bf16x8*)(pa_ + (wm*8+m_)*1024 + lo); \
    __builtin_amdgcn_s_setprio(1); \
    _Pragma("unroll") \
    for (int m_=0;m_<8;m_++) \
      _Pragma("unroll") \
      for (int j_=0;j_<4;j_++) \
        acc[m_][j_] = __builtin_amdgcn_mfma_f32_16x16x32_bf16(a_[m_], b_[j_], acc[m_][j_], 0,0,0); \
    __builtin_amdgcn_s_setprio(0); \
    /* pinned schedule: DSx6 (B0-3,A0,A1) | VMEMx4 stage | 6x{MFMAx4, DSx1} | MFMAx8 */ \
    __builtin_amdgcn_sched_group_barrier(0x100, 6, 0); \
    if (HASV) __builtin_amdgcn_sched_group_barrier(0x010, 4, 0); \
    _Pragma("unroll") \
    for (int g_=0; g_<6; ++g_){ \
      __builtin_amdgcn_sched_group_barrier(0x008, 4, 0); \
      __builtin_amdgcn_sched_group_barrier(0x100, 1, 0); \
    } \
    __builtin_amdgcn_sched_group_barrier(0x008, 8, 0); \
    if ((VM)==1) asm volatile("s_waitcnt vmcnt(8)":::"memory"); \
    if ((VM)==2) asm volatile("s_waitcnt vmcnt(4)":::"memory"); \
    if ((VM)==3) asm volatile("s_waitcnt vmcnt(0)":::"memory"); \
    asm volatile("s_barrier":::"memory"); \
  }while(0)

  // prologue: tile0 (both halves) + tile1 kh0  -> 12 loads/wave
  SA(0,0,0); SB(0,0,0); SA(0,1,0); SB(0,1,0); SA(1,0,1); SB(1,0,1);
  asm volatile("s_waitcnt vmcnt(8)":::"memory");
  asm volatile("s_barrier":::"memory");

  for (int it = 0; it < NIT-1; ++it) {
    int t1 = 2*it+1, t2 = 2*it+2, t3 = 2*it+3;
    SPHASE(0,0, { SA(1,1,t1); SB(1,1,t1); }, 1, 1);
    SPHASE(0,1, { SA(0,0,t2); SB(0,0,t2); }, 1, 1);
    SPHASE(1,0, { SA(0,1,t2); SB(0,1,t2); }, 1, 1);
    SPHASE(1,1, { SA(1,0,t3); SB(1,0,t3); }, 1, 1);
  }
  { // final iteration (tiles NT-2, NT-1)
    int tl = NT-1;
    SPHASE(0,0, { SA(1,1,tl); SB(1,1,tl); }, 1, 1);
    SPHASE(0,1, ((void)0), 2, 0);
    SPHASE(1,0, ((void)0), 3, 0);
    SPHASE(1,1, ((void)0), 0, 0);
  }
#undef SA
#undef SB
#undef SPHASE

#pragma unroll
  for (int i=0;i<8;i++)
#pragma unroll
    for (int j=0;j<4;j++)
#pragma unroll
      for (int r=0;r<4;r++){
        int gm = mt*256 + wm*128 + i*16 + (lane>>4)*4 + r;
        int gn = nt*256 + wn*64 + j*16 + (lane&15);
        float v = acc[i][j][r];
        if (EPI==0){
          ((u16*)C0)[(long)gm*ldc + gn] = f2b(v);
          if (gn >= 8448 && gn < 8512) C1[(long)gm*64 + (gn-8448)] = v;
        } else {
          ((float*)C0)[(long)z*sCz + (long)gm*ldc + gn] = v;
        }
      }
}

// ================= 256x128 BT GEMM — out_proj (no split-K, fp32 direct store) =================
__global__ __launch_bounds__(512, 2) void k_gemmN(
    const u16* __restrict__ A, const u16* __restrict__ B, float* __restrict__ C0,
    int lda, int ldb, int ldc, int K, int NTM)
{
  __shared__ __align__(16) char smem[98304];
  const int t = threadIdx.x, lane = t & 63, w = t >> 6;
  const int wm = w >> 2, wn = w & 3, w64 = w * 64;
  const int NT = K >> 6, NIT = NT >> 1;

  const int nwg = gridDim.x;
  const int orig = blockIdx.x;
  const int wg = (orig & 7) * (nwg >> 3) + (orig >> 3);
  const int mt = wg % NTM, nt = wg / NTM;

  const u16* Ab = A + (long)mt * 256 * lda;
  const u16* Bb = B + (long)nt * 128 * ldb;

  const int laneoff = (lane & 15) * 64 + (lane >> 4) * 16;
  const int lo = laneoff ^ (((laneoff >> 9) & 1) << 5);

  long aoff[2];
#pragma unroll
  for (int q = 0; q < 2; q++) {
    int u = t + q * 512;
    int up = u ^ (((u >> 5) & 1) << 1);
    int row = (up >> 6) * 16 + ((up & 63) >> 2);
    int c8 = (up & 3) * 8;
    aoff[q] = (long)row * lda + c8;
  }
  long boff;
  {
    int up = t ^ (((t >> 5) & 1) << 1);
    int row = (up >> 6) * 16 + ((up & 63) >> 2);   // 0..127
    int c8 = (up & 3) * 8;
    boff = (long)row * ldb + c8;
  }

  f32x4 acc[8][2];
#pragma unroll
  for (int i=0;i<8;i++)
#pragma unroll
    for (int j=0;j<2;j++) acc[i][j] = (f32x4){0.f,0.f,0.f,0.f};

#define SAN(BUF,KH,KT) do{ long kb_ = (long)(KT)*64 + (KH)*32; \
    gl_lds16(Ab + aoff[0] + kb_, (u16*)(smem + (BUF)*49152 + (KH)*16384 + w64*16)); \
    gl_lds16(Ab + aoff[1] + kb_, (u16*)(smem + (BUF)*49152 + (KH)*16384 + 8192 + w64*16)); }while(0)
#define SBN(BUF,KH,KT) do{ long kb_ = (long)(KT)*64 + (KH)*32; \
    gl_lds16(Bb + boff + kb_, (u16*)(smem + (BUF)*49152 + 32768 + (KH)*8192 + w64*16)); }while(0)

// VM: 0=none, 1=vmcnt(6), 2=vmcnt(3), 3=vmcnt(0)
#define NPHASE(BUF,KH,STMT,VM) do{ \
    const char* pa_ = smem + (BUF)*49152 + (KH)*16384; \
    const char* pb_ = smem + (BUF)*49152 + 32768 + (KH)*8192; \
    STMT; \
    bf16x8 a_[8], b_[2]; \
    _Pragma("unroll") \
    for (int j_=0;j_<2;j_++) b_[j_] = *(const bf16x8*)(pb_ + (wn*2+j_)*1024 + lo); \
    _Pragma("unroll") \
    for (int m_=0;m_<8;m_++) a_[m_] = *(const bf16x8*)(pa_ + (wm*8+m_)*1024 + lo); \
    __builtin_amdgcn_s_setprio(1); \
    _Pragma("unroll") \
    for (int m_=0;m_<8;m_++) \
      _Pragma("unroll") \
      for (int j_=0;j_<2;j_++) \
        acc[m_][j_] = __builtin_amdgcn_mfma_f32_16x16x32_bf16(a_[m_], b_[j_], acc[m_][j_], 0,0,0); \
    __builtin_amdgcn_s_setprio(0); \
    if ((VM)==1) asm volatile("s_waitcnt vmcnt(6)":::"memory"); \
    if ((VM)==2) asm volatile("s_waitcnt vmcnt(3)":::"memory"); \
    if ((VM)==3) asm volatile("s_waitcnt vmcnt(0)":::"memory"); \
    asm volatile("s_barrier":::"memory"); \
  }while(0)

  // prologue: tile0 (both halves) + tile1 kh0 -> 9 loads/wave
  SAN(0,0,0); SBN(0,0,0); SAN(0,1,0); SBN(0,1,0); SAN(1,0,1); SBN(1,0,1);
  asm volatile("s_waitcnt vmcnt(6)":::"memory");
  asm volatile("s_barrier":::"memory");

  for (int it = 0; it < NIT-1; ++it) {
    int t1 = 2*it+1, t2 = 2*it+2, t3 = 2*it+3;
    NPHASE(0,0, { SAN(1,1,t1); SBN(1,1,t1); }, 1);
    NPHASE(0,1, { SAN(0,0,t2); SBN(0,0,t2); }, 1);
    NPHASE(1,0, { SAN(0,1,t2); SBN(0,1,t2); }, 1);
    NPHASE(1,1, { SAN(1,0,t3); SBN(1,0,t3); }, 1);
  }
  { // final iteration (tiles NT-2, NT-1)
    int tl = NT-1;
    NPHASE(0,0, { SAN(1,1,tl); SBN(1,1,tl); }, 1);
    NPHASE(0,1, ((void)0), 2);
    NPHASE(1,0, ((void)0), 3);
    NPHASE(1,1, ((void)0), 0);
  }
#undef SAN
#undef SBN
#undef NPHASE

#pragma unroll
  for (int i=0;i<8;i++)
#pragma unroll
    for (int j=0;j<2;j++)
#pragma unroll
      for (int r=0;r<4;r++){
        int gm = mt*256 + wm*128 + i*16 + (lane>>4)*4 + r;
        int gn = nt*128 + wn*32 + j*16 + (lane&15);
        C0[(long)gm*ldc + gn] = acc[i][j][r];
      }
}

// ---------------- 128x128 BT GEMM (kept for the small per-chunk G = C@B^T) ----------------
template<int EPI>
__global__ __launch_bounds__(256) void k_gemm_bt(
    const u16* __restrict__ A, const u16* __restrict__ B,
    void* __restrict__ C0, float* __restrict__ C1,
    int lda, int ldb, int ldc, int K,
    long sAz, long sBz, long sCz, int auxcol)
{
  __shared__ u16 As[128*64];
  __shared__ u16 Bs[128*64];
  const int t = threadIdx.x, w = t>>6, lane = t&63;
  const int mt = blockIdx.y, nt = blockIdx.x, z = blockIdx.z;
  const u16* Ab = A + (long)z*sAz + (long)mt*128*lda;
  const u16* Bb = B + (long)z*sBz + (long)nt*128*ldb;
  const int wm = w>>1, wn = w&1;
  f32x4 acc[4][4];
#pragma unroll
  for (int i=0;i<4;i++)
#pragma unroll
    for (int j=0;j<4;j++) acc[i][j] = (f32x4){0.f,0.f,0.f,0.f};
  const int srow = (lane>>3), scol = (lane&7)*8;
  for (int k0=0; k0<K; k0+=64){
#pragma unroll
    for (int i=0;i<4;i++){
      int ch = w*4+i;
      int row = ch*8 + srow;
      gl_lds16(Ab + (long)row*lda + k0 + scol, As + ch*512);
      gl_lds16(Bb + (long)row*ldb + k0 + scol, Bs + ch*512);
    }
    __syncthreads();
#pragma unroll
    for (int kk=0;kk<2;kk++){
      bf16x8 af[4], bfr[4];
#pragma unroll
      for (int i=0;i<4;i++) af[i]  = *(const bf16x8*)&As[(wm*64+i*16+(lane&15))*64 + kk*32 + (lane>>4)*8];
#pragma unroll
      for (int j=0;j<4;j++) bfr[j] = *(const bf16x8*)&Bs[(wn*64+j*16+(lane&15))*64 + kk*32 + (lane>>4)*8];
#pragma unroll
      for (int i=0;i<4;i++)
#pragma unroll
        for (int j=0;j<4;j++)
          acc[i][j] = __builtin_amdgcn_mfma_f32_16x16x32_bf16(af[i], bfr[j], acc[i][j], 0,0,0);
    }
    __syncthreads();
  }
#pragma unroll
  for (int i=0;i<4;i++)
#pragma unroll
    for (int j=0;j<4;j++)
#pragma unroll
      for (int r=0;r<4;r++){
        int gm = mt*128 + wm*64 + i*16 + (lane>>4)*4 + r;
        int gn = nt*128 + wn*64 + j*16 + (lane&15);
        float v = acc[i][j][r];
        if (EPI==0){
          ((u16*)C0)[(long)gm*ldc + gn] = f2b(v);
          if (gn >= auxcol) C1[(long)gm*128 + (gn-auxcol)] = v;
        } else {
          ((float*)C0)[(long)z*sCz + (long)gm*ldc + gn] = v;
        }
      }
}

// ---------------- depthwise causal conv (K=4) + silu ----------------
__global__ __launch_bounds__(256) void k_conv(
    const u16* __restrict__ Pb, const float* __restrict__ cw, const float* __restrict__ cb,
    u16* __restrict__ XBC)
{
  long tg = (long)blockIdx.x*256 + threadIdx.x;
  int row = (int)(tg/544);
  int ch0 = (int)(tg%544)*8;
  int s = row & 2047;
  float acc[8];
#pragma unroll
  for (int j=0;j<8;j++) acc[j] = cb[ch0+j];
#pragma unroll
  for (int k=0;k<4;k++){
    int sk = s - 3 + k;
    if (sk >= 0){
      u16x8 v = *(const u16x8*)&Pb[(long)(row-3+k)*NPAD + INTER + ch0];
#pragma unroll
      for (int j=0;j<8;j++) acc[j] += b2f(v[j]) * cw[(ch0+j)*4 + k];
    }
  }
  u16x8 o;
#pragma unroll
  for (int j=0;j<8;j++){ float x = acc[j]; o[j] = f2b(x/(1.f+__expf(-x))); }
  *(u16x8*)&XBC[(long)row*CONVD + ch0] = o;
}

// ---------------- dt = softplus(dtraw + bias), a = dt*A, cumsum(a) per (b,h,chunk) ----------------
__global__ __launch_bounds__(256) void k_dtcs(
    const float* __restrict__ DTraw, const float* __restrict__ dt_bias,
    const float* __restrict__ A_log,
    float* __restrict__ dtb, float* __restrict__ csb, float* __restrict__ cdec)
{
  __shared__ float sc[256];
  int bid = blockIdx.x;          // ((b*64+h)*8 + c)
  int bh = bid>>3, c = bid&7;
  int h = bh & 63, b = bh>>6;
  int l = threadIdx.x;
  int row = (b*8+c)*256 + l;
  float x = DTraw[(long)row*64 + h] + dt_bias[h];
  float dt = (x > 20.f) ? x : log1pf(__expf(x));
  float a = dt * (-__expf(A_log[h]));
  dtb[(long)row*64 + h] = dt;
  sc[l] = a; __syncthreads();
  for (int off=1; off<256; off<<=1){
    float v = (l>=off) ? sc[l-off] : 0.f;
    __syncthreads();
    sc[l] += v;
    __syncthreads();
  }
  float cs = sc[l];
  csb[(long)bid*256 + l] = cs;
  if (l==255) cdec[bid] = __expf(cs);
}

// ---------------- chunk states via MFMA, XOR-swizzled transposed staging ----------------
// states[p][n] = sum_l xdt[l][p]*decay[l]*B[l][n]
// xsT[p][l] (64x128, row stride 136 u16), bsT[n][l] (128x136): transposed scalar writes
// had bank step (8*136*2/4)%32 == 0 -> 8..32-way conflicts.  Fix (G4/T2): XOR swizzle
// byte ^= ((row>>3)&7)<<4 (bijective within the 272B row span, preserves 16B alignment
// of b128 fragment reads) + pack 2 l per dword write.  Writes now <=2-way, reads ~2-way.
__global__ __launch_bounds__(256) void k_states(
    const u16* __restrict__ XBC, const float* __restrict__ dtb, const float* __restrict__ csb,
    float* __restrict__ states)
{
  __shared__ u16 xsT[64*136];
  __shared__ u16 bsT[128*136];
  __shared__ float dtl[128], del[128];
  int bid = blockIdx.x;            // (b*8+c)*64 + h
  int h = bid & 63, bc = bid >> 6;
  int b = bc>>3, c = bc&7;
  int rowb = bc*256;
  int t = threadIdx.x, w = t>>6, lane = t&63;
  int csbase = ((b*64+h)*8 + c)*256;
  float clast = csb[csbase + 255];
  f32x4 acc[8];
#pragma unroll
  for (int j=0;j<8;j++) acc[j] = (f32x4){0.f,0.f,0.f,0.f};
  for (int half=0; half<2; half++){
    int lbase = half*128;
    if (t < 128){
      dtl[t] = dtb[(long)(rowb+lbase+t)*64 + h];
      del[t] = __expf(clast - csb[csbase + lbase + t]);
    }
    __syncthreads();
    // xsT[p][l] = x[l][p]*dt[l] ; 8 p-groups x 64 l-pairs = 512 ids -> 2 iters
#pragma unroll
    for (int it=0; it<2; it++){
      int id = it*256+t;
      int p8 = id&7, l = (id>>3)*2;
      u16x8 v0 = *(const u16x8*)&XBC[(long)(rowb+lbase+l  )*CONVD + h*64 + p8*8];
      u16x8 v1 = *(const u16x8*)&XBC[(long)(rowb+lbase+l+1)*CONVD + h*64 + p8*8];
      float d0 = dtl[l], d1 = dtl[l+1];
#pragma unroll
      for (int j=0;j<8;j++){
        int row = p8*8+j;
        u32 dv = (u32)f2b(b2f(v0[j])*d0) | ((u32)f2b(b2f(v1[j])*d1)<<16);
        u32 byte = (u32)(2*(row*136 + l)) ^ (((u32)(row>>3)&7u)<<4);
        *(u32*)((char*)xsT + byte) = dv;
      }
    }
    // bsT[n][l] = B[l][n]*del[l] ; 16 n-groups x 64 l-pairs = 1024 ids -> 4 iters
#pragma unroll
    for (int it=0; it<4; it++){
      int id = it*256+t;
      int n8 = id&15, l = (id>>4)*2;
      u16x8 v0 = *(const u16x8*)&XBC[(long)(rowb+lbase+l  )*CONVD + INTER + n8*8];
      u16x8 v1 = *(const u16x8*)&XBC[(long)(rowb+lbase+l+1)*CONVD + INTER + n8*8];
      float d0 = del[l], d1 = del[l+1];
#pragma unroll
      for (int j=0;j<8;j++){
        int row = n8*8+j;
        u32 dv = (u32)f2b(b2f(v0[j])*d0) | ((u32)f2b(b2f(v1[j])*d1)<<16);
        u32 byte = (u32)(2*(row*136 + l)) ^ (((u32)(row>>3)&7u)<<4);
        *(u32*)((char*)bsT + byte) = dv;
      }
    }
    __syncthreads();
#pragma unroll
    for (int ks=0; ks<4; ks++){
      int rowA = w*16 + (lane&15);
      u32 abyte = (u32)(2*(rowA*136 + ks*32 + (lane>>4)*8)) ^ (((u32)(rowA>>3)&7u)<<4);
      bf16x8 af = *(const bf16x8*)((char*)xsT + abyte);
#pragma unroll
      for (int j=0;j<8;j++){
        int rowB = j*16 + (lane&15);
        u32 bbyte = (u32)(2*(rowB*136 + ks*32 + (lane>>4)*8)) ^ (((u32)(rowB>>3)&7u)<<4);
        bf16x8 bf = *(const bf16x8*)((char*)bsT + bbyte);
        acc[j] = __builtin_amdgcn_mfma_f32_16x16x32_bf16(af, bf, acc[j], 0,0,0);
      }
    }
    __syncthreads();
  }
  float* outp = states + (long)bid*8192;
#pragma unroll
  for (int j=0;j<8;j++)
#pragma unroll
    for (int r=0;r<4;r++){
      int gm = w*16 + (lane>>4)*4 + r;
      int gn = j*16 + (lane&15);
      outp[gm*128 + gn] = acc[j][r];
    }
}

// ---------------- inter-chunk scan (vectorized x4) ----------------
__global__ __launch_bounds__(256) void k_scan(
    const float* __restrict__ states, const float* __restrict__ cdec,
    u16* __restrict__ prevb)
{
  int bid = blockIdx.x;            // (b*64+h)*8 + sub
  int bh = bid>>3, sub = bid&7;
  int b = bh>>6, h = bh&63;
  int e = (sub*256 + threadIdx.x)*4;
  f32x4 carry = (f32x4){0.f,0.f,0.f,0.f};
#pragma unroll
  for (int c=0;c<8;c++){
    long idx = ((long)((b*8+c)*64 + h))*8192 + e;
    u16x4 o;
    o[0]=f2b(carry[0]); o[1]=f2b(carry[1]); o[2]=f2b(carry[2]); o[3]=f2b(carry[3]);
    *(u16x4*)&prevb[idx] = o;
    f32x4 s = *(const f32x4*)&states[idx];
    float d = cdec[bh*8 + c];
    carry = carry*d + s;
  }
}

// ---------------- fused Y_diag + Y_off + D*x per (b,c,h) ----------------
__global__ __launch_bounds__(256) void k_ydiag(
    const u16* __restrict__ XBC, const float* __restrict__ G,
    const u16* __restrict__ prevb, const float* __restrict__ dtb,
    const float* __restrict__ csb, const float* __restrict__ Dp,
    float* __restrict__ Y)
{
  __shared__ u16 PA[256*72];
  __shared__ u16 PB[64*72];
  __shared__ float csl[256];
  int bid = blockIdx.x;
  int h = bid&63, bc = bid>>6;
  int b = bc>>3, c = bc&7;
  int rowb = bc*256;
  int t = threadIdx.x, w = t>>6, lane = t&63;
  int csbase = ((b*64+h)*8 + c)*256;
  csl[t] = csb[csbase + t];
  const float* Gz = G + (long)bc*65536;
  f32x4 ad[4][4], ao[4][4];
#pragma unroll
  for (int i=0;i<4;i++)
#pragma unroll
    for (int j=0;j<4;j++){ ad[i][j]=(f32x4){0.f,0.f,0.f,0.f}; ao[i][j]=(f32x4){0.f,0.f,0.f,0.f}; }
  __syncthreads();
  for (int sl6=0; sl6<6; sl6++){
    if (sl6 < 4){
      int s0 = sl6*64;
#pragma unroll
      for (int r=0;r<8;r++){
        int id = r*256+t;
        int l = id>>3, sc8 = (id&7)*8;
        f32x4 g0 = *(const f32x4*)&Gz[l*256 + s0+sc8];
        f32x4 g1 = *(const f32x4*)&Gz[l*256 + s0+sc8+4];
        float cl = csl[l];
        u16x8 o;
#pragma unroll
        for (int jj=0;jj<4;jj++){
          int s = s0+sc8+jj;
          o[jj] = (s<=l) ? f2b(g0[jj]*__expf(cl - csl[s])) : (u16)0;
        }
#pragma unroll
        for (int jj=4;jj<8;jj++){
          int s = s0+sc8+jj;
          o[jj] = (s<=l) ? f2b(g1[jj-4]*__expf(cl - csl[s])) : (u16)0;
        }
        *(u16x8*)&PA[l*72 + sc8] = o;
      }
#pragma unroll
      for (int r=0;r<16;r++){
        int id = r*256+t;
        int p = id&63, ks = id>>6;
        float xv = b2f(XBC[(long)(rowb+s0+ks)*CONVD + h*64 + p]);
        float d = dtb[(long)(rowb+s0+ks)*64 + h];
        PB[p*72 + ks] = f2b(xv*d);
      }
    } else {
      int n0 = (sl6-4)*64;
#pragma unroll
      for (int r=0;r<8;r++){
        int id = r*256+t;
        int l = id>>3, kc = (id&7)*8;
        u16x8 v = *(const u16x8*)&XBC[(long)(rowb+l)*CONVD + INTER + DSTATE + n0 + kc];
        *(u16x8*)&PA[l*72 + kc] = v;
      }
#pragma unroll
      for (int r=0;r<2;r++){
        int id = r*256+t;
        int p = id>>3, kc = (id&7)*8;
        u16x8 v = *(const u16x8*)&prevb[((long)bid*64 + p)*128 + n0 + kc];
        *(u16x8*)&PB[p*72 + kc] = v;
      }
    }
    __syncthreads();
#pragma unroll
    for (int kk=0;kk<2;kk++){
      bf16x8 af[4], bfr[4];
#pragma unroll
      for (int i=0;i<4;i++) af[i]  = *(const bf16x8*)&PA[(w*64+i*16+(lane&15))*72 + kk*32 + (lane>>4)*8];
#pragma unroll
      for (int j=0;j<4;j++) bfr[j] = *(const bf16x8*)&PB[(j*16+(lane&15))*72 + kk*32 + (lane>>4)*8];
      if (sl6 < 4){
#pragma unroll
        for (int i=0;i<4;i++)
#pragma unroll
          for (int j=0;j<4;j++)
            ad[i][j] = __builtin_amdgcn_mfma_f32_16x16x32_bf16(af[i], bfr[j], ad[i][j], 0,0,0);
      } else {
#pragma unroll
        for (int i=0;i<4;i++)
#pragma unroll
          for (int j=0;j<4;j++)
            ao[i][j] = __builtin_amdgcn_mfma_f32_16x16x32_bf16(af[i], bfr[j], ao[i][j], 0,0,0);
      }
    }
    __syncthreads();
  }
  float Dh = Dp[h];
#pragma unroll
  for (int i=0;i<4;i++)
#pragma unroll
    for (int j=0;j<4;j++)
#pragma unroll
      for (int r=0;r<4;r++){
        int l = w*64 + i*16 + (lane>>4)*4 + r;
        int p = j*16 + (lane&15);
        float e = __expf(csl[l]);
        float xv = b2f(XBC[(long)(rowb+l)*CONVD + h*64 + p]);
        float v = ad[i][j][r] + e*ao[i][j][r] + Dh*xv;
        Y[(long)(rowb+l)*INTER + h*64 + p] = v;
      }
}

// ---------------- gated RMSNorm -> bf16 ----------------
__global__ __launch_bounds__(256) void k_norm(
    const float* __restrict__ Y, const u16* __restrict__ Pb,
    const float* __restrict__ nw, u16* __restrict__ hb)
{
  int row = blockIdx.x, t = threadIdx.x;
  int w = t>>6, lane = t&63;
  float hv[16];
  float ss = 0.f;
#pragma unroll
  for (int r=0;r<4;r++){
    int idx = (r*256+t)*4;
    f32x4 yv = *(const f32x4*)&Y[(long)row*INTER + idx];
    u16x4 gv = *(const u16x4*)&Pb[(long)row*NPAD + idx];
#pragma unroll
    for (int jj=0;jj<4;jj++){
      float g = b2f(gv[jj]);
      float hh = yv[jj] * g / (1.f+__expf(-g));
      hv[r*4+jj] = hh;
      ss += hh*hh;
    }
  }
  for (int off=32; off; off>>=1) ss += __shfl_down(ss, off);
  __shared__ float sm[4];
  if (lane==0) sm[w]=ss;
  __syncthreads();
  float tot = sm[0]+sm[1]+sm[2]+sm[3];
  float sc = rsqrtf(tot/4096.f + 1e-6f);
#pragma unroll
  for (int r=0;r<4;r++){
    int idx = (r*256+t)*4;
    f32x4 nv = *(const f32x4*)&nw[idx];
    u16x4 o;
#pragma unroll
    for (int jj=0;jj<4;jj++) o[jj] = f2b(hv[r*4+jj]*nv[jj]*sc);
    *(u16x4*)&hb[(long)row*INTER + idx] = o;
  }
}

// ---------------- launch ----------------
extern "C" void kernel_launch(void* const* d_in, const int* in_sizes, int n_in,
                              void* d_out, int out_size, void* d_ws, size_t ws_size,
                              hipStream_t stream)
{
  (void)in_sizes; (void)n_in;
  const float* X    = (const float*)d_in[0];
  const float* W1   = (const float*)d_in[1];
  const float* CW   = (const float*)d_in[2];
  const float* CB   = (const float*)d_in[3];
  const float* DTB  = (const float*)d_in[4];
  const float* ALOG = (const float*)d_in[5];
  const float* DD   = (const float*)d_in[6];
  const float* NW   = (const float*)d_in[7];
  const float* W2   = (const float*)d_in[8];
  float* out = (float*)d_out;
  char* ws = (char*)d_ws;

  constexpr long OFF_XB    = 0L;
  constexpr long OFF_WB    = 16777216L;
  constexpr long OFF_Y     = 0L;
  constexpr long OFF_ST    = 67108864L;
  constexpr long OFF_HB    = 67108864L;
  constexpr long OFF_W2B   = 100663296L;
  constexpr long OFF_PB    = 117440512L;   // 4096 x 8704 bf16 = 71,303,168
  constexpr long OFF_DTRAW = 188743680L;   // 4096 x 64 fp32 = 1,048,576
  constexpr long OFF_XBC   = 189792256L;
  constexpr long OFF_DT    = 225443840L;
  constexpr long OFF_CS    = 226492416L;
  constexpr long OFF_CDEC  = 227540992L;
  constexpr long OFF_G     = 227545088L;
  constexpr long OFF_PREV  = 231739392L;
  constexpr long WS_NEEDED = 248516608L;

  if ((long)ws_size < WS_NEEDED){
    hipMemsetAsync(d_out, 0, (size_t)out_size*4, stream);
    return;
  }

  u16*   Xb    = (u16*)(ws + OFF_XB);
  u16*   Wb    = (u16*)(ws + OFF_WB);
  u16*   W2b   = (u16*)(ws + OFF_W2B);
  u16*   Pb    = (u16*)(ws + OFF_PB);
  float* DTraw = (float*)(ws + OFF_DTRAW);
  u16*   XBCb  = (u16*)(ws + OFF_XBC);
  float* dtb   = (float*)(ws + OFF_DT);
  float* csb   = (float*)(ws + OFF_CS);
  float* cdec  = (float*)(ws + OFF_CDEC);
  float* G     = (float*)(ws + OFF_G);
  float* st    = (float*)(ws + OFF_ST);
  u16*   prevb = (u16*)(ws + OFF_PREV);
  float* Y     = (float*)(ws + OFF_Y);
  u16*   hb    = (u16*)(ws + OFF_HB);

  // fused converts: X (8192 blocks) | W1 + pad (17408) | W2 (8192)
  k_cvt3<<<33792, 256, 0, stream>>>(X, W1, W2, Xb, Wb, W2b);

  // in_proj: (4096x2048) @ (8704x2048)^T -> Pb bf16 (ld 8704) + DTraw fp32 side-store
  k_gemm8<0><<<dim3(544,1), 512, 0, stream>>>(Xb, Wb, Pb, DTraw, 2048, 2048, NPAD, 2048, 16, 0L);

  // conv + silu
  k_conv<<<8704, 256, 0, stream>>>(Pb, CW, CB, XBCb);

  // dt / a / cumsum
  k_dtcs<<<1024, 256, 0, stream>>>(DTraw, DTB, ALOG, dtb, csb, cdec);

  // G[bc] = C @ B^T  (256x256x128 per (b,c))
  k_gemm_bt<1><<<dim3(2,2,16), 256, 0, stream>>>(XBCb + INTER + DSTATE, XBCb + INTER, G, nullptr,
      CONVD, CONVD, 256, 128, 256L*CONVD, 256L*CONVD, 65536L, 0);

  // chunk states (MFMA, swizzled staging)
  k_states<<<1024, 256, 0, stream>>>(XBCb, dtb, csb, st);

  // inter-chunk scan (x4 vectorized)
  k_scan<<<1024, 256, 0, stream>>>(st, cdec, prevb);

  // Y = Y_diag + Y_off + D*x
  k_ydiag<<<1024, 256, 0, stream>>>(XBCb, G, prevb, dtb, csb, DD, Y);

  // gated RMSNorm -> bf16
  k_norm<<<4096, 256, 0, stream>>>(Y, Pb, NW, hb);

  // out_proj: (4096x4096) @ (2048x4096)^T -> d_out fp32, 256x128 tiles, 256 blocks, no split-K
  k_gemmN<<<256, 512, 0, stream>>>(hb, W2b, out, 4096, 4096, 2048, 4096, 16);
}

// Round 13
// 555.263 us; speedup vs baseline: 1.1006x; 1.0319x over previous
//
#include <hip/hip_runtime.h>

#define DEV __device__ __forceinline__

typedef unsigned short u16;
typedef unsigned int u32;
typedef __attribute__((ext_vector_type(4))) float f32x4;
typedef __attribute__((ext_vector_type(8))) u16 u16x8;
typedef __attribute__((ext_vector_type(4))) u16 u16x4;
typedef __attribute__((ext_vector_type(8))) __bf16 bf16x8;

#define INTER 4096
#define DSTATE 128
#define CONVD 4352
#define NPAD 8704
#define NROWS 4096

DEV float b2f(u16 u){ union{u32 i; float f;} v; v.i = ((u32)u)<<16; return v.f; }
DEV u16 f2b(float f){ union{u32 i; float f;} v; v.f = f; u32 r = v.i + 0x7fffu + ((v.i>>16)&1u); return (u16)(r>>16); }

typedef const __attribute__((address_space(1))) u32 gas_u32;
typedef __attribute__((address_space(3))) u32 las_u32;
DEV void gl_lds16(const u16* g, u16* l){
  __builtin_amdgcn_global_load_lds((gas_u32*)g, (las_u32*)l, 16, 0, 0);
}

// ---------------- fused f32 -> bf16 converts (X, W1 with zero-pad, W2) ----------------
__global__ __launch_bounds__(256) void k_cvt3(
    const float* __restrict__ X, const float* __restrict__ W1, const float* __restrict__ W2,
    u16* __restrict__ Xb, u16* __restrict__ Wb, u16* __restrict__ W2b)
{
  long b = blockIdx.x;
  const float* src; u16* dst; long n, base;
  if (b < 8192)       { src = X;  dst = Xb;  n = 8388608L;  base = b*1024L; }
  else if (b < 25600) { src = W1; dst = Wb;  n = 17432576L; base = (b-8192)*1024L; }
  else                { src = W2; dst = W2b; n = 8388608L;  base = (b-25600)*1024L; }
  long i = base + (long)threadIdx.x*4;
  u16x4 o;
  if (i < n){
    f32x4 v = *(const f32x4*)&src[i];
    o[0]=f2b(v[0]); o[1]=f2b(v[1]); o[2]=f2b(v[2]); o[3]=f2b(v[3]);
  } else {
    o[0]=0; o[1]=0; o[2]=0; o[3]=0;
  }
  *(u16x4*)&dst[i] = o;
}

// ================= 256x256 BT GEMM, 128KB, SGB-interleaved (R7 proven) — in_proj =================
// NOTE (R8 lesson): acc[8][4]=128 regs requires <=2 waves/SIMD; do NOT raise occupancy arg.
template<int EPI>
__global__ __launch_bounds__(512, 2) void k_gemm8(
    const u16* __restrict__ A, const u16* __restrict__ B,
    void* __restrict__ C0, float* __restrict__ C1,
    int lda, int ldb, int ldc, int K, int NTM, long sCz)
{
  __shared__ __align__(16) char smem[131072];
  const int t = threadIdx.x, lane = t & 63, w = t >> 6;
  const int wm = w >> 2, wn = w & 3, w64 = w * 64;
  const int NT = K >> 6, NIT = NT >> 1;
  const int z = blockIdx.y;

  const int nwg = gridDim.x;
  const int orig = blockIdx.x;
  const int wg = (orig & 7) * (nwg >> 3) + (orig >> 3);
  const int mt = wg % NTM, nt = wg / NTM;     // nt-major: A streams, B panels L2-resident

  const u16* Ab = A + (long)mt * 256 * lda + (long)z * K;
  const u16* Bb = B + (long)nt * 256 * ldb + (long)z * K;

  const int laneoff = (lane & 15) * 64 + (lane >> 4) * 16;
  const int lo = laneoff ^ (((laneoff >> 9) & 1) << 5);

  long aoff[2], boff[2];
#pragma unroll
  for (int q = 0; q < 2; q++) {
    int u = t + q * 512;
    int up = u ^ (((u >> 5) & 1) << 1);          // inverse st_16x32 swizzle on 16B chunks
    int row = (up >> 6) * 16 + ((up & 63) >> 2);
    int c8 = (up & 3) * 8;
    aoff[q] = (long)row * lda + c8;
    boff[q] = (long)row * ldb + c8;
  }

  f32x4 acc[8][4];
#pragma unroll
  for (int i=0;i<8;i++)
#pragma unroll
    for (int j=0;j<4;j++) acc[i][j] = (f32x4){0.f,0.f,0.f,0.f};

#define SA(BUF,KH,KT) do{ long kb_ = (long)(KT)*64 + (KH)*32; \
    gl_lds16(Ab + aoff[0] + kb_, (u16*)(smem + (BUF)*65536 + (KH)*16384 + w64*16)); \
    gl_lds16(Ab + aoff[1] + kb_, (u16*)(smem + (BUF)*65536 + (KH)*16384 + 8192 + w64*16)); }while(0)
#define SB(BUF,KH,KT) do{ long kb_ = (long)(KT)*64 + (KH)*32; \
    gl_lds16(Bb + boff[0] + kb_, (u16*)(smem + (BUF)*65536 + 32768 + (KH)*16384 + w64*16)); \
    gl_lds16(Bb + boff[1] + kb_, (u16*)(smem + (BUF)*65536 + 32768 + (KH)*16384 + 8192 + w64*16)); }while(0)

// VM: 0=none, 1=vmcnt(8), 2=vmcnt(4), 3=vmcnt(0).  HASV: stage present (pin VMEM group).
#define SPHASE(BUF,KH,STMT,VM,HASV) do{ \
    const char* pa_ = smem + (BUF)*65536 + (KH)*16384; \
    const char* pb_ = smem + (BUF)*65536 + 32768 + (KH)*16384; \
    STMT; \
    bf16x8 a_[8], b_[4]; \
    _Pragma("unroll") \
    for (int j_=0;j_<4;j_++) b_[j_] = *(const bf16x8*)(pb_ + (wn*4+j_)*1024 + lo); \
    _Pragma("unroll") \
    for (int m_=0;m_<8;m_++) a_[m_] = *(const bf16x8*)(pa_ + (wm*8+m_)*1024 + lo); \
    __builtin_amdgcn_s_setprio(1); \
    _Pragma("unroll") \
    for (int m_=0;m_<8;m_++) \
      _Pragma("unroll") \
      for (int j_=0;j_<4;j_++) \
        acc[m_][j_] = __builtin_amdgcn_mfma_f32_16x16x32_bf16(a_[m_], b_[j_], acc[m_][j_], 0,0,0); \
    __builtin_amdgcn_s_setprio(0); \
    /* pinned schedule: DSx6 (B0-3,A0,A1) | VMEMx4 stage | 6x{MFMAx4, DSx1} | MFMAx8 */ \
    __builtin_amdgcn_sched_group_barrier(0x100, 6, 0); \
    if (HASV) __builtin_amdgcn_sched_group_barrier(0x010, 4, 0); \
    _Pragma("unroll") \
    for (int g_=0; g_<6; ++g_){ \
      __builtin_amdgcn_sched_group_barrier(0x008, 4, 0); \
      __builtin_amdgcn_sched_group_barrier(0x100, 1, 0); \
    } \
    __builtin_amdgcn_sched_group_barrier(0x008, 8, 0); \
    if ((VM)==1) asm volatile("s_waitcnt vmcnt(8)":::"memory"); \
    if ((VM)==2) asm volatile("s_waitcnt vmcnt(4)":::"memory"); \
    if ((VM)==3) asm volatile("s_waitcnt vmcnt(0)":::"memory"); \
    asm volatile("s_barrier":::"memory"); \
  }while(0)

  // prologue: tile0 (both halves) + tile1 kh0  -> 12 loads/wave
  SA(0,0,0); SB(0,0,0); SA(0,1,0); SB(0,1,0); SA(1,0,1); SB(1,0,1);
  asm volatile("s_waitcnt vmcnt(8)":::"memory");
  asm volatile("s_barrier":::"memory");

  for (int it = 0; it < NIT-1; ++it) {
    int t1 = 2*it+1, t2 = 2*it+2, t3 = 2*it+3;
    SPHASE(0,0, { SA(1,1,t1); SB(1,1,t1); }, 1, 1);
    SPHASE(0,1, { SA(0,0,t2); SB(0,0,t2); }, 1, 1);
    SPHASE(1,0, { SA(0,1,t2); SB(0,1,t2); }, 1, 1);
    SPHASE(1,1, { SA(1,0,t3); SB(1,0,t3); }, 1, 1);
  }
  { // final iteration (tiles NT-2, NT-1)
    int tl = NT-1;
    SPHASE(0,0, { SA(1,1,tl); SB(1,1,tl); }, 1, 1);
    SPHASE(0,1, ((void)0), 2, 0);
    SPHASE(1,0, ((void)0), 3, 0);
    SPHASE(1,1, ((void)0), 0, 0);
  }
#undef SA
#undef SB
#undef SPHASE

#pragma unroll
  for (int i=0;i<8;i++)
#pragma unroll
    for (int j=0;j<4;j++)
#pragma unroll
      for (int r=0;r<4;r++){
        int gm = mt*256 + wm*128 + i*16 + (lane>>4)*4 + r;
        int gn = nt*256 + wn*64 + j*16 + (lane&15);
        float v = acc[i][j][r];
        if (EPI==0){
          ((u16*)C0)[(long)gm*ldc + gn] = f2b(v);
          if (gn >= 8448 && gn < 8512) C1[(long)gm*64 + (gn-8448)] = v;
        } else {
          ((float*)C0)[(long)z*sCz + (long)gm*ldc + gn] = v;
        }
      }
}

// ================= 256x128 BT GEMM — out_proj (no split-K, fp32 direct store) =================
__global__ __launch_bounds__(512, 2) void k_gemmN(
    const u16* __restrict__ A, const u16* __restrict__ B, float* __restrict__ C0,
    int lda, int ldb, int ldc, int K, int NTM)
{
  __shared__ __align__(16) char smem[98304];
  const int t = threadIdx.x, lane = t & 63, w = t >> 6;
  const int wm = w >> 2, wn = w & 3, w64 = w * 64;
  const int NT = K >> 6, NIT = NT >> 1;

  const int nwg = gridDim.x;
  const int orig = blockIdx.x;
  const int wg = (orig & 7) * (nwg >> 3) + (orig >> 3);
  const int mt = wg % NTM, nt = wg / NTM;

  const u16* Ab = A + (long)mt * 256 * lda;
  const u16* Bb = B + (long)nt * 128 * ldb;

  const int laneoff = (lane & 15) * 64 + (lane >> 4) * 16;
  const int lo = laneoff ^ (((laneoff >> 9) & 1) << 5);

  long aoff[2];
#pragma unroll
  for (int q = 0; q < 2; q++) {
    int u = t + q * 512;
    int up = u ^ (((u >> 5) & 1) << 1);
    int row = (up >> 6) * 16 + ((up & 63) >> 2);
    int c8 = (up & 3) * 8;
    aoff[q] = (long)row * lda + c8;
  }
  long boff;
  {
    int up = t ^ (((t >> 5) & 1) << 1);
    int row = (up >> 6) * 16 + ((up & 63) >> 2);   // 0..127
    int c8 = (up & 3) * 8;
    boff = (long)row * ldb + c8;
  }

  f32x4 acc[8][2];
#pragma unroll
  for (int i=0;i<8;i++)
#pragma unroll
    for (int j=0;j<2;j++) acc[i][j] = (f32x4){0.f,0.f,0.f,0.f};

#define SAN(BUF,KH,KT) do{ long kb_ = (long)(KT)*64 + (KH)*32; \
    gl_lds16(Ab + aoff[0] + kb_, (u16*)(smem + (BUF)*49152 + (KH)*16384 + w64*16)); \
    gl_lds16(Ab + aoff[1] + kb_, (u16*)(smem + (BUF)*49152 + (KH)*16384 + 8192 + w64*16)); }while(0)
#define SBN(BUF,KH,KT) do{ long kb_ = (long)(KT)*64 + (KH)*32; \
    gl_lds16(Bb + boff + kb_, (u16*)(smem + (BUF)*49152 + 32768 + (KH)*8192 + w64*16)); }while(0)

// VM: 0=none, 1=vmcnt(6), 2=vmcnt(3), 3=vmcnt(0)
#define NPHASE(BUF,KH,STMT,VM) do{ \
    const char* pa_ = smem + (BUF)*49152 + (KH)*16384; \
    const char* pb_ = smem + (BUF)*49152 + 32768 + (KH)*8192; \
    STMT; \
    bf16x8 a_[8], b_[2]; \
    _Pragma("unroll") \
    for (int j_=0;j_<2;j_++) b_[j_] = *(const bf16x8*)(pb_ + (wn*2+j_)*1024 + lo); \
    _Pragma("unroll") \
    for (int m_=0;m_<8;m_++) a_[m_] = *(const bf16x8*)(pa_ + (wm*8+m_)*1024 + lo); \
    __builtin_amdgcn_s_setprio(1); \
    _Pragma("unroll") \
    for (int m_=0;m_<8;m_++) \
      _Pragma("unroll") \
      for (int j_=0;j_<2;j_++) \
        acc[m_][j_] = __builtin_amdgcn_mfma_f32_16x16x32_bf16(a_[m_], b_[j_], acc[m_][j_], 0,0,0); \
    __builtin_amdgcn_s_setprio(0); \
    if ((VM)==1) asm volatile("s_waitcnt vmcnt(6)":::"memory"); \
    if ((VM)==2) asm volatile("s_waitcnt vmcnt(3)":::"memory"); \
    if ((VM)==3) asm volatile("s_waitcnt vmcnt(0)":::"memory"); \
    asm volatile("s_barrier":::"memory"); \
  }while(0)

  // prologue: tile0 (both halves) + tile1 kh0 -> 9 loads/wave
  SAN(0,0,0); SBN(0,0,0); SAN(0,1,0); SBN(0,1,0); SAN(1,0,1); SBN(1,0,1);
  asm volatile("s_waitcnt vmcnt(6)":::"memory");
  asm volatile("s_barrier":::"memory");

  for (int it = 0; it < NIT-1; ++it) {
    int t1 = 2*it+1, t2 = 2*it+2, t3 = 2*it+3;
    NPHASE(0,0, { SAN(1,1,t1); SBN(1,1,t1); }, 1);
    NPHASE(0,1, { SAN(0,0,t2); SBN(0,0,t2); }, 1);
    NPHASE(1,0, { SAN(0,1,t2); SBN(0,1,t2); }, 1);
    NPHASE(1,1, { SAN(1,0,t3); SBN(1,0,t3); }, 1);
  }
  { // final iteration (tiles NT-2, NT-1)
    int tl = NT-1;
    NPHASE(0,0, { SAN(1,1,tl); SBN(1,1,tl); }, 1);
    NPHASE(0,1, ((void)0), 2);
    NPHASE(1,0, ((void)0), 3);
    NPHASE(1,1, ((void)0), 0);
  }
#undef SAN
#undef SBN
#undef NPHASE

#pragma unroll
  for (int i=0;i<8;i++)
#pragma unroll
    for (int j=0;j<2;j++)
#pragma unroll
      for (int r=0;r<4;r++){
        int gm = mt*256 + wm*128 + i*16 + (lane>>4)*4 + r;
        int gn = nt*128 + wn*32 + j*16 + (lane&15);
        C0[(long)gm*ldc + gn] = acc[i][j][r];
      }
}

// ---------------- 128x128 BT GEMM (kept for the small per-chunk G = C@B^T) ----------------
template<int EPI>
__global__ __launch_bounds__(256) void k_gemm_bt(
    const u16* __restrict__ A, const u16* __restrict__ B,
    void* __restrict__ C0, float* __restrict__ C1,
    int lda, int ldb, int ldc, int K,
    long sAz, long sBz, long sCz, int auxcol)
{
  __shared__ u16 As[128*64];
  __shared__ u16 Bs[128*64];
  const int t = threadIdx.x, w = t>>6, lane = t&63;
  const int mt = blockIdx.y, nt = blockIdx.x, z = blockIdx.z;
  const u16* Ab = A + (long)z*sAz + (long)mt*128*lda;
  const u16* Bb = B + (long)z*sBz + (long)nt*128*ldb;
  const int wm = w>>1, wn = w&1;
  f32x4 acc[4][4];
#pragma unroll
  for (int i=0;i<4;i++)
#pragma unroll
    for (int j=0;j<4;j++) acc[i][j] = (f32x4){0.f,0.f,0.f,0.f};
  const int srow = (lane>>3), scol = (lane&7)*8;
  for (int k0=0; k0<K; k0+=64){
#pragma unroll
    for (int i=0;i<4;i++){
      int ch = w*4+i;
      int row = ch*8 + srow;
      gl_lds16(Ab + (long)row*lda + k0 + scol, As + ch*512);
      gl_lds16(Bb + (long)row*ldb + k0 + scol, Bs + ch*512);
    }
    __syncthreads();
#pragma unroll
    for (int kk=0;kk<2;kk++){
      bf16x8 af[4], bfr[4];
#pragma unroll
      for (int i=0;i<4;i++) af[i]  = *(const bf16x8*)&As[(wm*64+i*16+(lane&15))*64 + kk*32 + (lane>>4)*8];
#pragma unroll
      for (int j=0;j<4;j++) bfr[j] = *(const bf16x8*)&Bs[(wn*64+j*16+(lane&15))*64 + kk*32 + (lane>>4)*8];
#pragma unroll
      for (int i=0;i<4;i++)
#pragma unroll
        for (int j=0;j<4;j++)
          acc[i][j] = __builtin_amdgcn_mfma_f32_16x16x32_bf16(af[i], bfr[j], acc[i][j], 0,0,0);
    }
    __syncthreads();
  }
#pragma unroll
  for (int i=0;i<4;i++)
#pragma unroll
    for (int j=0;j<4;j++)
#pragma unroll
      for (int r=0;r<4;r++){
        int gm = mt*128 + wm*64 + i*16 + (lane>>4)*4 + r;
        int gn = nt*128 + wn*64 + j*16 + (lane&15);
        float v = acc[i][j][r];
        if (EPI==0){
          ((u16*)C0)[(long)gm*ldc + gn] = f2b(v);
          if (gn >= auxcol) C1[(long)gm*128 + (gn-auxcol)] = v;
        } else {
          ((float*)C0)[(long)z*sCz + (long)gm*ldc + gn] = v;
        }
      }
}

// ---------------- fused: depthwise causal conv (K=4) + silu  |  dt/a/cumsum ----------------
__global__ __launch_bounds__(256) void k_convdt(
    const u16* __restrict__ Pb, const float* __restrict__ cw, const float* __restrict__ cb,
    u16* __restrict__ XBC,
    const float* __restrict__ DTraw, const float* __restrict__ dt_bias,
    const float* __restrict__ A_log,
    float* __restrict__ dtb, float* __restrict__ csb, float* __restrict__ cdec)
{
  __shared__ float sc[256];
  if (blockIdx.x < 8704){
    // ---- conv + silu ----
    long tg = (long)blockIdx.x*256 + threadIdx.x;
    int row = (int)(tg/544);
    int ch0 = (int)(tg%544)*8;
    int s = row & 2047;
    float acc[8];
#pragma unroll
    for (int j=0;j<8;j++) acc[j] = cb[ch0+j];
#pragma unroll
    for (int k=0;k<4;k++){
      int sk = s - 3 + k;
      if (sk >= 0){
        u16x8 v = *(const u16x8*)&Pb[(long)(row-3+k)*NPAD + INTER + ch0];
#pragma unroll
        for (int j=0;j<8;j++) acc[j] += b2f(v[j]) * cw[(ch0+j)*4 + k];
      }
    }
    u16x8 o;
#pragma unroll
    for (int j=0;j<8;j++){ float x = acc[j]; o[j] = f2b(x/(1.f+__expf(-x))); }
    *(u16x8*)&XBC[(long)row*CONVD + ch0] = o;
  } else {
    // ---- dt = softplus(dtraw + bias), a = dt*A, cumsum per (b,h,chunk) ----
    int bid = blockIdx.x - 8704;   // ((b*64+h)*8 + c)
    int bh = bid>>3, c = bid&7;
    int h = bh & 63, b = bh>>6;
    int l = threadIdx.x;
    int row = (b*8+c)*256 + l;
    float x = DTraw[(long)row*64 + h] + dt_bias[h];
    float dt = (x > 20.f) ? x : log1pf(__expf(x));
    float a = dt * (-__expf(A_log[h]));
    dtb[(long)row*64 + h] = dt;
    sc[l] = a; __syncthreads();
    for (int off=1; off<256; off<<=1){
      float v = (l>=off) ? sc[l-off] : 0.f;
      __syncthreads();
      sc[l] += v;
      __syncthreads();
    }
    float cs = sc[l];
    csb[(long)bid*256 + l] = cs;
    if (l==255) cdec[bid] = __expf(cs);
  }
}

// ---------------- chunk states via MFMA, XOR-swizzled transposed staging ----------------
__global__ __launch_bounds__(256) void k_states(
    const u16* __restrict__ XBC, const float* __restrict__ dtb, const float* __restrict__ csb,
    float* __restrict__ states)
{
  __shared__ u16 xsT[64*136];
  __shared__ u16 bsT[128*136];
  __shared__ float dtl[128], del[128];
  int bid = blockIdx.x;            // (b*8+c)*64 + h
  int h = bid & 63, bc = bid >> 6;
  int b = bc>>3, c = bc&7;
  int rowb = bc*256;
  int t = threadIdx.x, w = t>>6, lane = t&63;
  int csbase = ((b*64+h)*8 + c)*256;
  float clast = csb[csbase + 255];
  f32x4 acc[8];
#pragma unroll
  for (int j=0;j<8;j++) acc[j] = (f32x4){0.f,0.f,0.f,0.f};
  for (int half=0; half<2; half++){
    int lbase = half*128;
    if (t < 128){
      dtl[t] = dtb[(long)(rowb+lbase+t)*64 + h];
      del[t] = __expf(clast - csb[csbase + lbase + t]);
    }
    __syncthreads();
#pragma unroll
    for (int it=0; it<2; it++){
      int id = it*256+t;
      int p8 = id&7, l = (id>>3)*2;
      u16x8 v0 = *(const u16x8*)&XBC[(long)(rowb+lbase+l  )*CONVD + h*64 + p8*8];
      u16x8 v1 = *(const u16x8*)&XBC[(long)(rowb+lbase+l+1)*CONVD + h*64 + p8*8];
      float d0 = dtl[l], d1 = dtl[l+1];
#pragma unroll
      for (int j=0;j<8;j++){
        int row = p8*8+j;
        u32 dv = (u32)f2b(b2f(v0[j])*d0) | ((u32)f2b(b2f(v1[j])*d1)<<16);
        u32 byte = (u32)(2*(row*136 + l)) ^ (((u32)(row>>3)&7u)<<4);
        *(u32*)((char*)xsT + byte) = dv;
      }
    }
#pragma unroll
    for (int it=0; it<4; it++){
      int id = it*256+t;
      int n8 = id&15, l = (id>>4)*2;
      u16x8 v0 = *(const u16x8*)&XBC[(long)(rowb+lbase+l  )*CONVD + INTER + n8*8];
      u16x8 v1 = *(const u16x8*)&XBC[(long)(rowb+lbase+l+1)*CONVD + INTER + n8*8];
      float d0 = del[l], d1 = del[l+1];
#pragma unroll
      for (int j=0;j<8;j++){
        int row = n8*8+j;
        u32 dv = (u32)f2b(b2f(v0[j])*d0) | ((u32)f2b(b2f(v1[j])*d1)<<16);
        u32 byte = (u32)(2*(row*136 + l)) ^ (((u32)(row>>3)&7u)<<4);
        *(u32*)((char*)bsT + byte) = dv;
      }
    }
    __syncthreads();
#pragma unroll
    for (int ks=0; ks<4; ks++){
      int rowA = w*16 + (lane&15);
      u32 abyte = (u32)(2*(rowA*136 + ks*32 + (lane>>4)*8)) ^ (((u32)(rowA>>3)&7u)<<4);
      bf16x8 af = *(const bf16x8*)((char*)xsT + abyte);
#pragma unroll
      for (int j=0;j<8;j++){
        int rowB = j*16 + (lane&15);
        u32 bbyte = (u32)(2*(rowB*136 + ks*32 + (lane>>4)*8)) ^ (((u32)(rowB>>3)&7u)<<4);
        bf16x8 bf = *(const bf16x8*)((char*)bsT + bbyte);
        acc[j] = __builtin_amdgcn_mfma_f32_16x16x32_bf16(af, bf, acc[j], 0,0,0);
      }
    }
    __syncthreads();
  }
  float* outp = states + (long)bid*8192;
#pragma unroll
  for (int j=0;j<8;j++)
#pragma unroll
    for (int r=0;r<4;r++){
      int gm = w*16 + (lane>>4)*4 + r;
      int gn = j*16 + (lane&15);
      outp[gm*128 + gn] = acc[j][r];
    }
}

// ---------------- inter-chunk scan (vectorized x4) ----------------
__global__ __launch_bounds__(256) void k_scan(
    const float* __restrict__ states, const float* __restrict__ cdec,
    u16* __restrict__ prevb)
{
  int bid = blockIdx.x;            // (b*64+h)*8 + sub
  int bh = bid>>3, sub = bid&7;
  int b = bh>>6, h = bh&63;
  int e = (sub*256 + threadIdx.x)*4;
  f32x4 carry = (f32x4){0.f,0.f,0.f,0.f};
#pragma unroll
  for (int c=0;c<8;c++){
    long idx = ((long)((b*8+c)*64 + h))*8192 + e;
    u16x4 o;
    o[0]=f2b(carry[0]); o[1]=f2b(carry[1]); o[2]=f2b(carry[2]); o[3]=f2b(carry[3]);
    *(u16x4*)&prevb[idx] = o;
    f32x4 s = *(const f32x4*)&states[idx];
    float d = cdec[bh*8 + c];
    carry = carry*d + s;
  }
}

// ---------------- fused Y_diag + Y_off + D*x per (b,c,h), triangular-skip ----------------
// Causal mask: slice sl6 (s in [s0,s0+64)) has zero contribution for rows l < s0.
// (a) PA staging skips row-spans entirely below s0; (b) waves w < sl6 skip the diag
// fragment reads + MFMAs (their PA rows are all < s0; stale LDS rows are never read).
__global__ __launch_bounds__(256) void k_ydiag(
    const u16* __restrict__ XBC, const float* __restrict__ G,
    const u16* __restrict__ prevb, const float* __restrict__ dtb,
    const float* __restrict__ csb, const float* __restrict__ Dp,
    float* __restrict__ Y)
{
  __shared__ u16 PA[256*72];
  __shared__ u16 PB[64*72];
  __shared__ float csl[256];
  int bid = blockIdx.x;
  int h = bid&63, bc = bid>>6;
  int b = bc>>3, c = bc&7;
  int rowb = bc*256;
  int t = threadIdx.x, w = t>>6, lane = t&63;
  int csbase = ((b*64+h)*8 + c)*256;
  csl[t] = csb[csbase + t];
  const float* Gz = G + (long)bc*65536;
  f32x4 ad[4][4], ao[4][4];
#pragma unroll
  for (int i=0;i<4;i++)
#pragma unroll
    for (int j=0;j<4;j++){ ad[i][j]=(f32x4){0.f,0.f,0.f,0.f}; ao[i][j]=(f32x4){0.f,0.f,0.f,0.f}; }
  __syncthreads();
  for (int sl6=0; sl6<6; sl6++){
    if (sl6 < 4){
      int s0 = sl6*64;
#pragma unroll
      for (int r=0;r<8;r++){
        if ((r+1)*32 > s0){          // rows r*32..r*32+31 contain some l >= s0
          int id = r*256+t;
          int l = id>>3, sc8 = (id&7)*8;
          f32x4 g0 = *(const f32x4*)&Gz[l*256 + s0+sc8];
          f32x4 g1 = *(const f32x4*)&Gz[l*256 + s0+sc8+4];
          float cl = csl[l];
          u16x8 o;
#pragma unroll
          for (int jj=0;jj<4;jj++){
            int s = s0+sc8+jj;
            o[jj] = (s<=l) ? f2b(g0[jj]*__expf(cl - csl[s])) : (u16)0;
          }
#pragma unroll
          for (int jj=4;jj<8;jj++){
            int s = s0+sc8+jj;
            o[jj] = (s<=l) ? f2b(g1[jj-4]*__expf(cl - csl[s])) : (u16)0;
          }
          *(u16x8*)&PA[l*72 + sc8] = o;
        }
      }
#pragma unroll
      for (int r=0;r<16;r++){
        int id = r*256+t;
        int p = id&63, ks = id>>6;
        float xv = b2f(XBC[(long)(rowb+s0+ks)*CONVD + h*64 + p]);
        float d = dtb[(long)(rowb+s0+ks)*64 + h];
        PB[p*72 + ks] = f2b(xv*d);
      }
    } else {
      int n0 = (sl6-4)*64;
#pragma unroll
      for (int r=0;r<8;r++){
        int id = r*256+t;
        int l = id>>3, kc = (id&7)*8;
        u16x8 v = *(const u16x8*)&XBC[(long)(rowb+l)*CONVD + INTER + DSTATE + n0 + kc];
        *(u16x8*)&PA[l*72 + kc] = v;
      }
#pragma unroll
      for (int r=0;r<2;r++){
        int id = r*256+t;
        int p = id>>3, kc = (id&7)*8;
        u16x8 v = *(const u16x8*)&prevb[((long)bid*64 + p)*128 + n0 + kc];
        *(u16x8*)&PB[p*72 + kc] = v;
      }
    }
    __syncthreads();
    if (sl6 < 4){
      if (w >= sl6){
#pragma unroll
        for (int kk=0;kk<2;kk++){
          bf16x8 af[4], bfr[4];
#pragma unroll
          for (int i=0;i<4;i++) af[i]  = *(const bf16x8*)&PA[(w*64+i*16+(lane&15))*72 + kk*32 + (lane>>4)*8];
#pragma unroll
          for (int j=0;j<4;j++) bfr[j] = *(const bf16x8*)&PB[(j*16+(lane&15))*72 + kk*32 + (lane>>4)*8];
#pragma unroll
          for (int i=0;i<4;i++)
#pragma unroll
            for (int j=0;j<4;j++)
              ad[i][j] = __builtin_amdgcn_mfma_f32_16x16x32_bf16(af[i], bfr[j], ad[i][j], 0,0,0);
        }
      }
    } else {
#pragma unroll
      for (int kk=0;kk<2;kk++){
        bf16x8 af[4], bfr[4];
#pragma unroll
        for (int i=0;i<4;i++) af[i]  = *(const bf16x8*)&PA[(w*64+i*16+(lane&15))*72 + kk*32 + (lane>>4)*8];
#pragma unroll
        for (int j=0;j<4;j++) bfr[j] = *(const bf16x8*)&PB[(j*16+(lane&15))*72 + kk*32 + (lane>>4)*8];
#pragma unroll
        for (int i=0;i<4;i++)
#pragma unroll
          for (int j=0;j<4;j++)
            ao[i][j] = __builtin_amdgcn_mfma_f32_16x16x32_bf16(af[i], bfr[j], ao[i][j], 0,0,0);
      }
    }
    __syncthreads();
  }
  float Dh = Dp[h];
#pragma unroll
  for (int i=0;i<4;i++)
#pragma unroll
    for (int j=0;j<4;j++)
#pragma unroll
      for (int r=0;r<4;r++){
        int l = w*64 + i*16 + (lane>>4)*4 + r;
        int p = j*16 + (lane&15);
        float e = __expf(csl[l]);
        float xv = b2f(XBC[(long)(rowb+l)*CONVD + h*64 + p]);
        float v = ad[i][j][r] + e*ao[i][j][r] + Dh*xv;
        Y[(long)(rowb+l)*INTER + h*64 + p] = v;
      }
}

// ---------------- gated RMSNorm -> bf16 ----------------
__global__ __launch_bounds__(256) void k_norm(
    const float* __restrict__ Y, const u16* __restrict__ Pb,
    const float* __restrict__ nw, u16* __restrict__ hb)
{
  int row = blockIdx.x, t = threadIdx.x;
  int w = t>>6, lane = t&63;
  float hv[16];
  float ss = 0.f;
#pragma unroll
  for (int r=0;r<4;r++){
    int idx = (r*256+t)*4;
    f32x4 yv = *(const f32x4*)&Y[(long)row*INTER + idx];
    u16x4 gv = *(const u16x4*)&Pb[(long)row*NPAD + idx];
#pragma unroll
    for (int jj=0;jj<4;jj++){
      float g = b2f(gv[jj]);
      float hh = yv[jj] * g / (1.f+__expf(-g));
      hv[r*4+jj] = hh;
      ss += hh*hh;
    }
  }
  for (int off=32; off; off>>=1) ss += __shfl_down(ss, off);
  __shared__ float sm[4];
  if (lane==0) sm[w]=ss;
  __syncthreads();
  float tot = sm[0]+sm[1]+sm[2]+sm[3];
  float sc = rsqrtf(tot/4096.f + 1e-6f);
#pragma unroll
  for (int r=0;r<4;r++){
    int idx = (r*256+t)*4;
    f32x4 nv = *(const f32x4*)&nw[idx];
    u16x4 o;
#pragma unroll
    for (int jj=0;jj<4;jj++) o[jj] = f2b(hv[r*4+jj]*nv[jj]*sc);
    *(u16x4*)&hb[(long)row*INTER + idx] = o;
  }
}

// ---------------- launch ----------------
extern "C" void kernel_launch(void* const* d_in, const int* in_sizes, int n_in,
                              void* d_out, int out_size, void* d_ws, size_t ws_size,
                              hipStream_t stream)
{
  (void)in_sizes; (void)n_in;
  const float* X    = (const float*)d_in[0];
  const float* W1   = (const float*)d_in[1];
  const float* CW   = (const float*)d_in[2];
  const float* CB   = (const float*)d_in[3];
  const float* DTB  = (const float*)d_in[4];
  const float* ALOG = (const float*)d_in[5];
  const float* DD   = (const float*)d_in[6];
  const float* NW   = (const float*)d_in[7];
  const float* W2   = (const float*)d_in[8];
  float* out = (float*)d_out;
  char* ws = (char*)d_ws;

  constexpr long OFF_XB    = 0L;
  constexpr long OFF_WB    = 16777216L;
  constexpr long OFF_Y     = 0L;
  constexpr long OFF_ST    = 67108864L;
  constexpr long OFF_HB    = 67108864L;
  constexpr long OFF_W2B   = 100663296L;
  constexpr long OFF_PB    = 117440512L;   // 4096 x 8704 bf16 = 71,303,168
  constexpr long OFF_DTRAW = 188743680L;   // 4096 x 64 fp32 = 1,048,576
  constexpr long OFF_XBC   = 189792256L;
  constexpr long OFF_DT    = 225443840L;
  constexpr long OFF_CS    = 226492416L;
  constexpr long OFF_CDEC  = 227540992L;
  constexpr long OFF_G     = 227545088L;
  constexpr long OFF_PREV  = 231739392L;
  constexpr long WS_NEEDED = 248516608L;

  if ((long)ws_size < WS_NEEDED){
    hipMemsetAsync(d_out, 0, (size_t)out_size*4, stream);
    return;
  }

  u16*   Xb    = (u16*)(ws + OFF_XB);
  u16*   Wb    = (u16*)(ws + OFF_WB);
  u16*   W2b   = (u16*)(ws + OFF_W2B);
  u16*   Pb    = (u16*)(ws + OFF_PB);
  float* DTraw = (float*)(ws + OFF_DTRAW);
  u16*   XBCb  = (u16*)(ws + OFF_XBC);
  float* dtb   = (float*)(ws + OFF_DT);
  float* csb   = (float*)(ws + OFF_CS);
  float* cdec  = (float*)(ws + OFF_CDEC);
  float* G     = (float*)(ws + OFF_G);
  float* st    = (float*)(ws + OFF_ST);
  u16*   prevb = (u16*)(ws + OFF_PREV);
  float* Y     = (float*)(ws + OFF_Y);
  u16*   hb    = (u16*)(ws + OFF_HB);

  // fused converts: X (8192 blocks) | W1 + pad (17408) | W2 (8192)
  k_cvt3<<<33792, 256, 0, stream>>>(X, W1, W2, Xb, Wb, W2b);

  // in_proj: (4096x2048) @ (8704x2048)^T -> Pb bf16 (ld 8704) + DTraw fp32 side-store
  k_gemm8<0><<<dim3(544,1), 512, 0, stream>>>(Xb, Wb, Pb, DTraw, 2048, 2048, NPAD, 2048, 16, 0L);

  // fused conv+silu (blocks 0..8703) | dt/a/cumsum (blocks 8704..9727)
  k_convdt<<<9728, 256, 0, stream>>>(Pb, CW, CB, XBCb, DTraw, DTB, ALOG, dtb, csb, cdec);

  // G[bc] = C @ B^T  (256x256x128 per (b,c))
  k_gemm_bt<1><<<dim3(2,2,16), 256, 0, stream>>>(XBCb + INTER + DSTATE, XBCb + INTER, G, nullptr,
      CONVD, CONVD, 256, 128, 256L*CONVD, 256L*CONVD, 65536L, 0);

  // chunk states (MFMA, swizzled staging)
  k_states<<<1024, 256, 0, stream>>>(XBCb, dtb, csb, st);

  // inter-chunk scan (x4 vectorized)
  k_scan<<<1024, 256, 0, stream>>>(st, cdec, prevb);

  // Y = Y_diag + Y_off + D*x  (triangular skip)
  k_ydiag<<<1024, 256, 0, stream>>>(XBCb, G, prevb, dtb, csb, DD, Y);

  // gated RMSNorm -> bf16
  k_norm<<<4096, 256, 0, stream>>>(Y, Pb, NW, hb);

  // out_proj: (4096x4096) @ (2048x4096)^T -> d_out fp32, 256x128 tiles, 256 blocks, no split-K
  k_gemmN<<<256, 512, 0, stream>>>(hb, W2b, out, 4096, 4096, 2048, 4096, 16);
}

// Round 14
// 550.136 us; speedup vs baseline: 1.1108x; 1.0093x over previous
//
#include <hip/hip_runtime.h>

#define DEV __device__ __forceinline__

typedef unsigned short u16;
typedef unsigned int u32;
typedef __attribute__((ext_vector_type(4))) float f32x4;
typedef __attribute__((ext_vector_type(8))) u16 u16x8;
typedef __attribute__((ext_vector_type(4))) u16 u16x4;
typedef __attribute__((ext_vector_type(8))) __bf16 bf16x8;

#define INTER 4096
#define DSTATE 128
#define CONVD 4352
#define NPAD 8704
#define NROWS 4096

DEV float b2f(u16 u){ union{u32 i; float f;} v; v.i = ((u32)u)<<16; return v.f; }
DEV u16 f2b(float f){ union{u32 i; float f;} v; v.f = f; u32 r = v.i + 0x7fffu + ((v.i>>16)&1u); return (u16)(r>>16); }

typedef const __attribute__((address_space(1))) u32 gas_u32;
typedef __attribute__((address_space(3))) u32 las_u32;
DEV void gl_lds16(const u16* g, u16* l){
  __builtin_amdgcn_global_load_lds((gas_u32*)g, (las_u32*)l, 16, 0, 0);
}

// ---------------- fused f32 -> bf16 converts, x8 vectorized (X, W1 with zero-pad, W2) ----------------
__global__ __launch_bounds__(256) void k_cvt3(
    const float* __restrict__ X, const float* __restrict__ W1, const float* __restrict__ W2,
    u16* __restrict__ Xb, u16* __restrict__ Wb, u16* __restrict__ W2b)
{
  long b = blockIdx.x;
  const float* src; u16* dst; long n, base;
  if (b < 4096)       { src = X;  dst = Xb;  n = 8388608L;  base = b*2048L; }
  else if (b < 12800) { src = W1; dst = Wb;  n = 17432576L; base = (b-4096)*2048L; }
  else                { src = W2; dst = W2b; n = 8388608L;  base = (b-12800)*2048L; }
  long i = base + (long)threadIdx.x*8;
  u16x8 o;
  if (i < n){
    f32x4 v0 = *(const f32x4*)&src[i];
    f32x4 v1 = *(const f32x4*)&src[i+4];
    o[0]=f2b(v0[0]); o[1]=f2b(v0[1]); o[2]=f2b(v0[2]); o[3]=f2b(v0[3]);
    o[4]=f2b(v1[0]); o[5]=f2b(v1[1]); o[6]=f2b(v1[2]); o[7]=f2b(v1[3]);
  } else {
    o[0]=0;o[1]=0;o[2]=0;o[3]=0;o[4]=0;o[5]=0;o[6]=0;o[7]=0;
  }
  *(u16x8*)&dst[i] = o;
}

// ================= 256x256 BT GEMM, 128KB, SGB-interleaved (R7 proven) — in_proj =================
// NOTE (R8 lesson): acc[8][4]=128 regs requires <=2 waves/SIMD; do NOT raise occupancy arg.
template<int EPI>
__global__ __launch_bounds__(512, 2) void k_gemm8(
    const u16* __restrict__ A, const u16* __restrict__ B,
    void* __restrict__ C0, float* __restrict__ C1,
    int lda, int ldb, int ldc, int K, int NTM, long sCz)
{
  __shared__ __align__(16) char smem[131072];
  const int t = threadIdx.x, lane = t & 63, w = t >> 6;
  const int wm = w >> 2, wn = w & 3, w64 = w * 64;
  const int NT = K >> 6, NIT = NT >> 1;
  const int z = blockIdx.y;

  const int nwg = gridDim.x;
  const int orig = blockIdx.x;
  const int wg = (orig & 7) * (nwg >> 3) + (orig >> 3);
  const int mt = wg % NTM, nt = wg / NTM;     // nt-major: A streams, B panels L2-resident

  const u16* Ab = A + (long)mt * 256 * lda + (long)z * K;
  const u16* Bb = B + (long)nt * 256 * ldb + (long)z * K;

  const int laneoff = (lane & 15) * 64 + (lane >> 4) * 16;
  const int lo = laneoff ^ (((laneoff >> 9) & 1) << 5);

  long aoff[2], boff[2];
#pragma unroll
  for (int q = 0; q < 2; q++) {
    int u = t + q * 512;
    int up = u ^ (((u >> 5) & 1) << 1);          // inverse st_16x32 swizzle on 16B chunks
    int row = (up >> 6) * 16 + ((up & 63) >> 2);
    int c8 = (up & 3) * 8;
    aoff[q] = (long)row * lda + c8;
    boff[q] = (long)row * ldb + c8;
  }

  f32x4 acc[8][4];
#pragma unroll
  for (int i=0;i<8;i++)
#pragma unroll
    for (int j=0;j<4;j++) acc[i][j] = (f32x4){0.f,0.f,0.f,0.f};

#define SA(BUF,KH,KT) do{ long kb_ = (long)(KT)*64 + (KH)*32; \
    gl_lds16(Ab + aoff[0] + kb_, (u16*)(smem + (BUF)*65536 + (KH)*16384 + w64*16)); \
    gl_lds16(Ab + aoff[1] + kb_, (u16*)(smem + (BUF)*65536 + (KH)*16384 + 8192 + w64*16)); }while(0)
#define SB(BUF,KH,KT) do{ long kb_ = (long)(KT)*64 + (KH)*32; \
    gl_lds16(Bb + boff[0] + kb_, (u16*)(smem + (BUF)*65536 + 32768 + (KH)*16384 + w64*16)); \
    gl_lds16(Bb + boff[1] + kb_, (u16*)(smem + (BUF)*65536 + 32768 + (KH)*16384 + 8192 + w64*16)); }while(0)

// VM: 0=none, 1=vmcnt(8), 2=vmcnt(4), 3=vmcnt(0).  HASV: stage present (pin VMEM group).
#define SPHASE(BUF,KH,STMT,VM,HASV) do{ \
    const char* pa_ = smem + (BUF)*65536 + (KH)*16384; \
    const char* pb_ = smem + (BUF)*65536 + 32768 + (KH)*16384; \
    STMT; \
    bf16x8 a_[8], b_[4]; \
    _Pragma("unroll") \
    for (int j_=0;j_<4;j_++) b_[j_] = *(const bf16x8*)(pb_ + (wn*4+j_)*1024 + lo); \
    _Pragma("unroll") \
    for (int m_=0;m_<8;m_++) a_[m_] = *(const bf16x8*)(pa_ + (wm*8+m_)*1024 + lo); \
    __builtin_amdgcn_s_setprio(1); \
    _Pragma("unroll") \
    for (int m_=0;m_<8;m_++) \
      _Pragma("unroll") \
      for (int j_=0;j_<4;j_++) \
        acc[m_][j_] = __builtin_amdgcn_mfma_f32_16x16x32_bf16(a_[m_], b_[j_], acc[m_][j_], 0,0,0); \
    __builtin_amdgcn_s_setprio(0); \
    /* pinned schedule: DSx6 (B0-3,A0,A1) | VMEMx4 stage | 6x{MFMAx4, DSx1} | MFMAx8 */ \
    __builtin_amdgcn_sched_group_barrier(0x100, 6, 0); \
    if (HASV) __builtin_amdgcn_sched_group_barrier(0x010, 4, 0); \
    _Pragma("unroll") \
    for (int g_=0; g_<6; ++g_){ \
      __builtin_amdgcn_sched_group_barrier(0x008, 4, 0); \
      __builtin_amdgcn_sched_group_barrier(0x100, 1, 0); \
    } \
    __builtin_amdgcn_sched_group_barrier(0x008, 8, 0); \
    if ((VM)==1) asm volatile("s_waitcnt vmcnt(8)":::"memory"); \
    if ((VM)==2) asm volatile("s_waitcnt vmcnt(4)":::"memory"); \
    if ((VM)==3) asm volatile("s_waitcnt vmcnt(0)":::"memory"); \
    asm volatile("s_barrier":::"memory"); \
  }while(0)

  // prologue: tile0 (both halves) + tile1 kh0  -> 12 loads/wave
  SA(0,0,0); SB(0,0,0); SA(0,1,0); SB(0,1,0); SA(1,0,1); SB(1,0,1);
  asm volatile("s_waitcnt vmcnt(8)":::"memory");
  asm volatile("s_barrier":::"memory");

  for (int it = 0; it < NIT-1; ++it) {
    int t1 = 2*it+1, t2 = 2*it+2, t3 = 2*it+3;
    SPHASE(0,0, { SA(1,1,t1); SB(1,1,t1); }, 1, 1);
    SPHASE(0,1, { SA(0,0,t2); SB(0,0,t2); }, 1, 1);
    SPHASE(1,0, { SA(0,1,t2); SB(0,1,t2); }, 1, 1);
    SPHASE(1,1, { SA(1,0,t3); SB(1,0,t3); }, 1, 1);
  }
  { // final iteration (tiles NT-2, NT-1)
    int tl = NT-1;
    SPHASE(0,0, { SA(1,1,tl); SB(1,1,tl); }, 1, 1);
    SPHASE(0,1, ((void)0), 2, 0);
    SPHASE(1,0, ((void)0), 3, 0);
    SPHASE(1,1, ((void)0), 0, 0);
  }
#undef SA
#undef SB
#undef SPHASE

#pragma unroll
  for (int i=0;i<8;i++)
#pragma unroll
    for (int j=0;j<4;j++)
#pragma unroll
      for (int r=0;r<4;r++){
        int gm = mt*256 + wm*128 + i*16 + (lane>>4)*4 + r;
        int gn = nt*256 + wn*64 + j*16 + (lane&15);
        float v = acc[i][j][r];
        if (EPI==0){
          ((u16*)C0)[(long)gm*ldc + gn] = f2b(v);
          if (gn >= 8448 && gn < 8512) C1[(long)gm*64 + (gn-8448)] = v;
        } else {
          ((float*)C0)[(long)z*sCz + (long)gm*ldc + gn] = v;
        }
      }
}

// ================= 256x128 BT GEMM — out_proj (no split-K, fp32 direct store) =================
__global__ __launch_bounds__(512, 2) void k_gemmN(
    const u16* __restrict__ A, const u16* __restrict__ B, float* __restrict__ C0,
    int lda, int ldb, int ldc, int K, int NTM)
{
  __shared__ __align__(16) char smem[98304];
  const int t = threadIdx.x, lane = t & 63, w = t >> 6;
  const int wm = w >> 2, wn = w & 3, w64 = w * 64;
  const int NT = K >> 6, NIT = NT >> 1;

  const int nwg = gridDim.x;
  const int orig = blockIdx.x;
  const int wg = (orig & 7) * (nwg >> 3) + (orig >> 3);
  const int mt = wg % NTM, nt = wg / NTM;

  const u16* Ab = A + (long)mt * 256 * lda;
  const u16* Bb = B + (long)nt * 128 * ldb;

  const int laneoff = (lane & 15) * 64 + (lane >> 4) * 16;
  const int lo = laneoff ^ (((laneoff >> 9) & 1) << 5);

  long aoff[2];
#pragma unroll
  for (int q = 0; q < 2; q++) {
    int u = t + q * 512;
    int up = u ^ (((u >> 5) & 1) << 1);
    int row = (up >> 6) * 16 + ((up & 63) >> 2);
    int c8 = (up & 3) * 8;
    aoff[q] = (long)row * lda + c8;
  }
  long boff;
  {
    int up = t ^ (((t >> 5) & 1) << 1);
    int row = (up >> 6) * 16 + ((up & 63) >> 2);   // 0..127
    int c8 = (up & 3) * 8;
    boff = (long)row * ldb + c8;
  }

  f32x4 acc[8][2];
#pragma unroll
  for (int i=0;i<8;i++)
#pragma unroll
    for (int j=0;j<2;j++) acc[i][j] = (f32x4){0.f,0.f,0.f,0.f};

#define SAN(BUF,KH,KT) do{ long kb_ = (long)(KT)*64 + (KH)*32; \
    gl_lds16(Ab + aoff[0] + kb_, (u16*)(smem + (BUF)*49152 + (KH)*16384 + w64*16)); \
    gl_lds16(Ab + aoff[1] + kb_, (u16*)(smem + (BUF)*49152 + (KH)*16384 + 8192 + w64*16)); }while(0)
#define SBN(BUF,KH,KT) do{ long kb_ = (long)(KT)*64 + (KH)*32; \
    gl_lds16(Bb + boff + kb_, (u16*)(smem + (BUF)*49152 + 32768 + (KH)*8192 + w64*16)); }while(0)

// VM: 0=none, 1=vmcnt(6), 2=vmcnt(3), 3=vmcnt(0)
#define NPHASE(BUF,KH,STMT,VM) do{ \
    const char* pa_ = smem + (BUF)*49152 + (KH)*16384; \
    const char* pb_ = smem + (BUF)*49152 + 32768 + (KH)*8192; \
    STMT; \
    bf16x8 a_[8], b_[2]; \
    _Pragma("unroll") \
    for (int j_=0;j_<2;j_++) b_[j_] = *(const bf16x8*)(pb_ + (wn*2+j_)*1024 + lo); \
    _Pragma("unroll") \
    for (int m_=0;m_<8;m_++) a_[m_] = *(const bf16x8*)(pa_ + (wm*8+m_)*1024 + lo); \
    __builtin_amdgcn_s_setprio(1); \
    _Pragma("unroll") \
    for (int m_=0;m_<8;m_++) \
      _Pragma("unroll") \
      for (int j_=0;j_<2;j_++) \
        acc[m_][j_] = __builtin_amdgcn_mfma_f32_16x16x32_bf16(a_[m_], b_[j_], acc[m_][j_], 0,0,0); \
    __builtin_amdgcn_s_setprio(0); \
    if ((VM)==1) asm volatile("s_waitcnt vmcnt(6)":::"memory"); \
    if ((VM)==2) asm volatile("s_waitcnt vmcnt(3)":::"memory"); \
    if ((VM)==3) asm volatile("s_waitcnt vmcnt(0)":::"memory"); \
    asm volatile("s_barrier":::"memory"); \
  }while(0)

  // prologue: tile0 (both halves) + tile1 kh0 -> 9 loads/wave
  SAN(0,0,0); SBN(0,0,0); SAN(0,1,0); SBN(0,1,0); SAN(1,0,1); SBN(1,0,1);
  asm volatile("s_waitcnt vmcnt(6)":::"memory");
  asm volatile("s_barrier":::"memory");

  for (int it = 0; it < NIT-1; ++it) {
    int t1 = 2*it+1, t2 = 2*it+2, t3 = 2*it+3;
    NPHASE(0,0, { SAN(1,1,t1); SBN(1,1,t1); }, 1);
    NPHASE(0,1, { SAN(0,0,t2); SBN(0,0,t2); }, 1);
    NPHASE(1,0, { SAN(0,1,t2); SBN(0,1,t2); }, 1);
    NPHASE(1,1, { SAN(1,0,t3); SBN(1,0,t3); }, 1);
  }
  { // final iteration (tiles NT-2, NT-1)
    int tl = NT-1;
    NPHASE(0,0, { SAN(1,1,tl); SBN(1,1,tl); }, 1);
    NPHASE(0,1, ((void)0), 2);
    NPHASE(1,0, ((void)0), 3);
    NPHASE(1,1, ((void)0), 0);
  }
#undef SAN
#undef SBN
#undef NPHASE

#pragma unroll
  for (int i=0;i<8;i++)
#pragma unroll
    for (int j=0;j<2;j++)
#pragma unroll
      for (int r=0;r<4;r++){
        int gm = mt*256 + wm*128 + i*16 + (lane>>4)*4 + r;
        int gn = nt*128 + wn*32 + j*16 + (lane&15);
        C0[(long)gm*ldc + gn] = acc[i][j][r];
      }
}

// ---------------- fused: depthwise causal conv (K=4) + silu  |  dt/a/cumsum ----------------
__global__ __launch_bounds__(256) void k_convdt(
    const u16* __restrict__ Pb, const float* __restrict__ cw, const float* __restrict__ cb,
    u16* __restrict__ XBC,
    const float* __restrict__ DTraw, const float* __restrict__ dt_bias,
    const float* __restrict__ A_log,
    float* __restrict__ dtb, float* __restrict__ csb, float* __restrict__ cdec)
{
  __shared__ float sc[256];
  if (blockIdx.x < 8704){
    // ---- conv + silu ----
    long tg = (long)blockIdx.x*256 + threadIdx.x;
    int row = (int)(tg/544);
    int ch0 = (int)(tg%544)*8;
    int s = row & 2047;
    float acc[8];
#pragma unroll
    for (int j=0;j<8;j++) acc[j] = cb[ch0+j];
#pragma unroll
    for (int k=0;k<4;k++){
      int sk = s - 3 + k;
      if (sk >= 0){
        u16x8 v = *(const u16x8*)&Pb[(long)(row-3+k)*NPAD + INTER + ch0];
#pragma unroll
        for (int j=0;j<8;j++) acc[j] += b2f(v[j]) * cw[(ch0+j)*4 + k];
      }
    }
    u16x8 o;
#pragma unroll
    for (int j=0;j<8;j++){ float x = acc[j]; o[j] = f2b(x/(1.f+__expf(-x))); }
    *(u16x8*)&XBC[(long)row*CONVD + ch0] = o;
  } else {
    // ---- dt = softplus(dtraw + bias), a = dt*A, cumsum per (b,h,chunk) ----
    int bid = blockIdx.x - 8704;   // ((b*64+h)*8 + c)
    int bh = bid>>3, c = bid&7;
    int h = bh & 63, b = bh>>6;
    int l = threadIdx.x;
    int row = (b*8+c)*256 + l;
    float x = DTraw[(long)row*64 + h] + dt_bias[h];
    float dt = (x > 20.f) ? x : log1pf(__expf(x));
    float a = dt * (-__expf(A_log[h]));
    dtb[(long)row*64 + h] = dt;
    sc[l] = a; __syncthreads();
    for (int off=1; off<256; off<<=1){
      float v = (l>=off) ? sc[l-off] : 0.f;
      __syncthreads();
      sc[l] += v;
      __syncthreads();
    }
    float cs = sc[l];
    csb[(long)bid*256 + l] = cs;
    if (l==255) cdec[bid] = __expf(cs);
  }
}

// ---------------- fused: G = C@B^T (blocks 0..63) | chunk states via MFMA (64..1087) ----------------
// Independent dataflows: G <- (C,B); states <- (x,B,dt,cs).  Shared 53KB LDS region.
__global__ __launch_bounds__(256) void k_gstates(
    const u16* __restrict__ XBC, const float* __restrict__ dtb, const float* __restrict__ csb,
    float* __restrict__ G, float* __restrict__ states)
{
  __shared__ __align__(16) char smem[53248];
  const int t = threadIdx.x, w = t>>6, lane = t&63;

  if (blockIdx.x < 64){
    // ===== G[bc] = C @ B^T, 128x128 tile, K=128 =====
    int bid = blockIdx.x;
    int z = bid>>2, mt = (bid>>1)&1, nt = bid&1;
    u16* As = (u16*)smem;                 // 128x64
    u16* Bs = (u16*)(smem + 16384);       // 128x64
    const u16* Ab = XBC + INTER + DSTATE + (long)z*256*CONVD + (long)mt*128*CONVD;
    const u16* Bb = XBC + INTER          + (long)z*256*CONVD + (long)nt*128*CONVD;
    const int wm = w>>1, wn = w&1;
    f32x4 acc[4][4];
#pragma unroll
    for (int i=0;i<4;i++)
#pragma unroll
      for (int j=0;j<4;j++) acc[i][j] = (f32x4){0.f,0.f,0.f,0.f};
    const int srow = (lane>>3), scol = (lane&7)*8;
    for (int k0=0; k0<128; k0+=64){
#pragma unroll
      for (int i=0;i<4;i++){
        int ch = w*4+i;
        int row = ch*8 + srow;
        gl_lds16(Ab + (long)row*CONVD + k0 + scol, As + ch*512);
        gl_lds16(Bb + (long)row*CONVD + k0 + scol, Bs + ch*512);
      }
      __syncthreads();
#pragma unroll
      for (int kk=0;kk<2;kk++){
        bf16x8 af[4], bfr[4];
#pragma unroll
        for (int i=0;i<4;i++) af[i]  = *(const bf16x8*)&As[(wm*64+i*16+(lane&15))*64 + kk*32 + (lane>>4)*8];
#pragma unroll
        for (int j=0;j<4;j++) bfr[j] = *(const bf16x8*)&Bs[(wn*64+j*16+(lane&15))*64 + kk*32 + (lane>>4)*8];
#pragma unroll
        for (int i=0;i<4;i++)
#pragma unroll
          for (int j=0;j<4;j++)
            acc[i][j] = __builtin_amdgcn_mfma_f32_16x16x32_bf16(af[i], bfr[j], acc[i][j], 0,0,0);
      }
      __syncthreads();
    }
#pragma unroll
    for (int i=0;i<4;i++)
#pragma unroll
      for (int j=0;j<4;j++)
#pragma unroll
        for (int r=0;r<4;r++){
          int gm = mt*128 + wm*64 + i*16 + (lane>>4)*4 + r;
          int gn = nt*128 + wn*64 + j*16 + (lane&15);
          G[(long)z*65536 + (long)gm*256 + gn] = acc[i][j][r];
        }
    return;
  }

  // ===== chunk states: states[p][n] = sum_l xdt[l][p]*decay[l]*B[l][n], XOR-swizzled =====
  int bid = blockIdx.x - 64;       // (b*8+c)*64 + h
  u16* xsT = (u16*)smem;                       // 64x136
  u16* bsT = (u16*)(smem + 17408);             // 128x136
  float* dtl = (float*)(smem + 52224);         // 128
  float* del = (float*)(smem + 52736);         // 128
  int h = bid & 63, bc = bid >> 6;
  int b = bc>>3, c = bc&7;
  int rowb = bc*256;
  int csbase = ((b*64+h)*8 + c)*256;
  float clast = csb[csbase + 255];
  f32x4 acc[8];
#pragma unroll
  for (int j=0;j<8;j++) acc[j] = (f32x4){0.f,0.f,0.f,0.f};
  for (int half=0; half<2; half++){
    int lbase = half*128;
    if (t < 128){
      dtl[t] = dtb[(long)(rowb+lbase+t)*64 + h];
      del[t] = __expf(clast - csb[csbase + lbase + t]);
    }
    __syncthreads();
#pragma unroll
    for (int it=0; it<2; it++){
      int id = it*256+t;
      int p8 = id&7, l = (id>>3)*2;
      u16x8 v0 = *(const u16x8*)&XBC[(long)(rowb+lbase+l  )*CONVD + h*64 + p8*8];
      u16x8 v1 = *(const u16x8*)&XBC[(long)(rowb+lbase+l+1)*CONVD + h*64 + p8*8];
      float d0 = dtl[l], d1 = dtl[l+1];
#pragma unroll
      for (int j=0;j<8;j++){
        int row = p8*8+j;
        u32 dv = (u32)f2b(b2f(v0[j])*d0) | ((u32)f2b(b2f(v1[j])*d1)<<16);
        u32 byte = (u32)(2*(row*136 + l)) ^ (((u32)(row>>3)&7u)<<4);
        *(u32*)((char*)xsT + byte) = dv;
      }
    }
#pragma unroll
    for (int it=0; it<4; it++){
      int id = it*256+t;
      int n8 = id&15, l = (id>>4)*2;
      u16x8 v0 = *(const u16x8*)&XBC[(long)(rowb+lbase+l  )*CONVD + INTER + n8*8];
      u16x8 v1 = *(const u16x8*)&XBC[(long)(rowb+lbase+l+1)*CONVD + INTER + n8*8];
      float d0 = del[l], d1 = del[l+1];
#pragma unroll
      for (int j=0;j<8;j++){
        int row = n8*8+j;
        u32 dv = (u32)f2b(b2f(v0[j])*d0) | ((u32)f2b(b2f(v1[j])*d1)<<16);
        u32 byte = (u32)(2*(row*136 + l)) ^ (((u32)(row>>3)&7u)<<4);
        *(u32*)((char*)bsT + byte) = dv;
      }
    }
    __syncthreads();
#pragma unroll
    for (int ks=0; ks<4; ks++){
      int rowA = w*16 + (lane&15);
      u32 abyte = (u32)(2*(rowA*136 + ks*32 + (lane>>4)*8)) ^ (((u32)(rowA>>3)&7u)<<4);
      bf16x8 af = *(const bf16x8*)((char*)xsT + abyte);
#pragma unroll
      for (int j=0;j<8;j++){
        int rowB = j*16 + (lane&15);
        u32 bbyte = (u32)(2*(rowB*136 + ks*32 + (lane>>4)*8)) ^ (((u32)(rowB>>3)&7u)<<4);
        bf16x8 bf = *(const bf16x8*)((char*)bsT + bbyte);
        acc[j] = __builtin_amdgcn_mfma_f32_16x16x32_bf16(af, bf, acc[j], 0,0,0);
      }
    }
    __syncthreads();
  }
  float* outp = states + (long)bid*8192;
#pragma unroll
  for (int j=0;j<8;j++)
#pragma unroll
    for (int r=0;r<4;r++){
      int gm = w*16 + (lane>>4)*4 + r;
      int gn = j*16 + (lane&15);
      outp[gm*128 + gn] = acc[j][r];
    }
}

// ---------------- inter-chunk scan (vectorized x4) ----------------
__global__ __launch_bounds__(256) void k_scan(
    const float* __restrict__ states, const float* __restrict__ cdec,
    u16* __restrict__ prevb)
{
  int bid = blockIdx.x;            // (b*64+h)*8 + sub
  int bh = bid>>3, sub = bid&7;
  int b = bh>>6, h = bh&63;
  int e = (sub*256 + threadIdx.x)*4;
  f32x4 carry = (f32x4){0.f,0.f,0.f,0.f};
#pragma unroll
  for (int c=0;c<8;c++){
    long idx = ((long)((b*8+c)*64 + h))*8192 + e;
    u16x4 o;
    o[0]=f2b(carry[0]); o[1]=f2b(carry[1]); o[2]=f2b(carry[2]); o[3]=f2b(carry[3]);
    *(u16x4*)&prevb[idx] = o;
    f32x4 s = *(const f32x4*)&states[idx];
    float d = cdec[bh*8 + c];
    carry = carry*d + s;
  }
}

// ---------------- fused Y_diag + Y_off + D*x per (b,c,h), triangular-skip ----------------
__global__ __launch_bounds__(256) void k_ydiag(
    const u16* __restrict__ XBC, const float* __restrict__ G,
    const u16* __restrict__ prevb, const float* __restrict__ dtb,
    const float* __restrict__ csb, const float* __restrict__ Dp,
    float* __restrict__ Y)
{
  __shared__ u16 PA[256*72];
  __shared__ u16 PB[64*72];
  __shared__ float csl[256];
  int bid = blockIdx.x;
  int h = bid&63, bc = bid>>6;
  int b = bc>>3, c = bc&7;
  int rowb = bc*256;
  int t = threadIdx.x, w = t>>6, lane = t&63;
  int csbase = ((b*64+h)*8 + c)*256;
  csl[t] = csb[csbase + t];
  const float* Gz = G + (long)bc*65536;
  f32x4 ad[4][4], ao[4][4];
#pragma unroll
  for (int i=0;i<4;i++)
#pragma unroll
    for (int j=0;j<4;j++){ ad[i][j]=(f32x4){0.f,0.f,0.f,0.f}; ao[i][j]=(f32x4){0.f,0.f,0.f,0.f}; }
  __syncthreads();
  for (int sl6=0; sl6<6; sl6++){
    if (sl6 < 4){
      int s0 = sl6*64;
#pragma unroll
      for (int r=0;r<8;r++){
        if ((r+1)*32 > s0){          // rows r*32..r*32+31 contain some l >= s0
          int id = r*256+t;
          int l = id>>3, sc8 = (id&7)*8;
          f32x4 g0 = *(const f32x4*)&Gz[l*256 + s0+sc8];
          f32x4 g1 = *(const f32x4*)&Gz[l*256 + s0+sc8+4];
          float cl = csl[l];
          u16x8 o;
#pragma unroll
          for (int jj=0;jj<4;jj++){
            int s = s0+sc8+jj;
            o[jj] = (s<=l) ? f2b(g0[jj]*__expf(cl - csl[s])) : (u16)0;
          }
#pragma unroll
          for (int jj=4;jj<8;jj++){
            int s = s0+sc8+jj;
            o[jj] = (s<=l) ? f2b(g1[jj-4]*__expf(cl - csl[s])) : (u16)0;
          }
          *(u16x8*)&PA[l*72 + sc8] = o;
        }
      }
#pragma unroll
      for (int r=0;r<16;r++){
        int id = r*256+t;
        int p = id&63, ks = id>>6;
        float xv = b2f(XBC[(long)(rowb+s0+ks)*CONVD + h*64 + p]);
        float d = dtb[(long)(rowb+s0+ks)*64 + h];
        PB[p*72 + ks] = f2b(xv*d);
      }
    } else {
      int n0 = (sl6-4)*64;
#pragma unroll
      for (int r=0;r<8;r++){
        int id = r*256+t;
        int l = id>>3, kc = (id&7)*8;
        u16x8 v = *(const u16x8*)&XBC[(long)(rowb+l)*CONVD + INTER + DSTATE + n0 + kc];
        *(u16x8*)&PA[l*72 + kc] = v;
      }
#pragma unroll
      for (int r=0;r<2;r++){
        int id = r*256+t;
        int p = id>>3, kc = (id&7)*8;
        u16x8 v = *(const u16x8*)&prevb[((long)bid*64 + p)*128 + n0 + kc];
        *(u16x8*)&PB[p*72 + kc] = v;
      }
    }
    __syncthreads();
    if (sl6 < 4){
      if (w >= sl6){
#pragma unroll
        for (int kk=0;kk<2;kk++){
          bf16x8 af[4], bfr[4];
#pragma unroll
          for (int i=0;i<4;i++) af[i]  = *(const bf16x8*)&PA[(w*64+i*16+(lane&15))*72 + kk*32 + (lane>>4)*8];
#pragma unroll
          for (int j=0;j<4;j++) bfr[j] = *(const bf16x8*)&PB[(j*16+(lane&15))*72 + kk*32 + (lane>>4)*8];
#pragma unroll
          for (int i=0;i<4;i++)
#pragma unroll
            for (int j=0;j<4;j++)
              ad[i][j] = __builtin_amdgcn_mfma_f32_16x16x32_bf16(af[i], bfr[j], ad[i][j], 0,0,0);
        }
      }
    } else {
#pragma unroll
      for (int kk=0;kk<2;kk++){
        bf16x8 af[4], bfr[4];
#pragma unroll
        for (int i=0;i<4;i++) af[i]  = *(const bf16x8*)&PA[(w*64+i*16+(lane&15))*72 + kk*32 + (lane>>4)*8];
#pragma unroll
        for (int j=0;j<4;j++) bfr[j] = *(const bf16x8*)&PB[(j*16+(lane&15))*72 + kk*32 + (lane>>4)*8];
#pragma unroll
        for (int i=0;i<4;i++)
#pragma unroll
          for (int j=0;j<4;j++)
            ao[i][j] = __builtin_amdgcn_mfma_f32_16x16x32_bf16(af[i], bfr[j], ao[i][j], 0,0,0);
      }
    }
    __syncthreads();
  }
  float Dh = Dp[h];
#pragma unroll
  for (int i=0;i<4;i++)
#pragma unroll
    for (int r=0;r<4;r++){
      int l = w*64 + i*16 + (lane>>4)*4 + r;
      float e = __expf(csl[l]);          // hoisted: one exp per (i,r), not per (i,j,r)
#pragma unroll
      for (int j=0;j<4;j++){
        int p = j*16 + (lane&15);
        float xv = b2f(XBC[(long)(rowb+l)*CONVD + h*64 + p]);
        float v = ad[i][j][r] + e*ao[i][j][r] + Dh*xv;
        Y[(long)(rowb+l)*INTER + h*64 + p] = v;
      }
    }
}

// ---------------- gated RMSNorm -> bf16 ----------------
__global__ __launch_bounds__(256) void k_norm(
    const float* __restrict__ Y, const u16* __restrict__ Pb,
    const float* __restrict__ nw, u16* __restrict__ hb)
{
  int row = blockIdx.x, t = threadIdx.x;
  int w = t>>6, lane = t&63;
  float hv[16];
  float ss = 0.f;
#pragma unroll
  for (int r=0;r<4;r++){
    int idx = (r*256+t)*4;
    f32x4 yv = *(const f32x4*)&Y[(long)row*INTER + idx];
    u16x4 gv = *(const u16x4*)&Pb[(long)row*NPAD + idx];
#pragma unroll
    for (int jj=0;jj<4;jj++){
      float g = b2f(gv[jj]);
      float hh = yv[jj] * g / (1.f+__expf(-g));
      hv[r*4+jj] = hh;
      ss += hh*hh;
    }
  }
  for (int off=32; off; off>>=1) ss += __shfl_down(ss, off);
  __shared__ float sm[4];
  if (lane==0) sm[w]=ss;
  __syncthreads();
  float tot = sm[0]+sm[1]+sm[2]+sm[3];
  float sc = rsqrtf(tot/4096.f + 1e-6f);
#pragma unroll
  for (int r=0;r<4;r++){
    int idx = (r*256+t)*4;
    f32x4 nv = *(const f32x4*)&nw[idx];
    u16x4 o;
#pragma unroll
    for (int jj=0;jj<4;jj++) o[jj] = f2b(hv[r*4+jj]*nv[jj]*sc);
    *(u16x4*)&hb[(long)row*INTER + idx] = o;
  }
}

// ---------------- launch ----------------
extern "C" void kernel_launch(void* const* d_in, const int* in_sizes, int n_in,
                              void* d_out, int out_size, void* d_ws, size_t ws_size,
                              hipStream_t stream)
{
  (void)in_sizes; (void)n_in;
  const float* X    = (const float*)d_in[0];
  const float* W1   = (const float*)d_in[1];
  const float* CW   = (const float*)d_in[2];
  const float* CB   = (const float*)d_in[3];
  const float* DTB  = (const float*)d_in[4];
  const float* ALOG = (const float*)d_in[5];
  const float* DD   = (const float*)d_in[6];
  const float* NW   = (const float*)d_in[7];
  const float* W2   = (const float*)d_in[8];
  float* out = (float*)d_out;
  char* ws = (char*)d_ws;

  constexpr long OFF_XB    = 0L;
  constexpr long OFF_WB    = 16777216L;
  constexpr long OFF_Y     = 0L;
  constexpr long OFF_ST    = 67108864L;
  constexpr long OFF_HB    = 67108864L;
  constexpr long OFF_W2B   = 100663296L;
  constexpr long OFF_PB    = 117440512L;   // 4096 x 8704 bf16 = 71,303,168
  constexpr long OFF_DTRAW = 188743680L;   // 4096 x 64 fp32 = 1,048,576
  constexpr long OFF_XBC   = 189792256L;
  constexpr long OFF_DT    = 225443840L;
  constexpr long OFF_CS    = 226492416L;
  constexpr long OFF_CDEC  = 227540992L;
  constexpr long OFF_G     = 227545088L;
  constexpr long OFF_PREV  = 231739392L;
  constexpr long WS_NEEDED = 248516608L;

  if ((long)ws_size < WS_NEEDED){
    hipMemsetAsync(d_out, 0, (size_t)out_size*4, stream);
    return;
  }

  u16*   Xb    = (u16*)(ws + OFF_XB);
  u16*   Wb    = (u16*)(ws + OFF_WB);
  u16*   W2b   = (u16*)(ws + OFF_W2B);
  u16*   Pb    = (u16*)(ws + OFF_PB);
  float* DTraw = (float*)(ws + OFF_DTRAW);
  u16*   XBCb  = (u16*)(ws + OFF_XBC);
  float* dtb   = (float*)(ws + OFF_DT);
  float* csb   = (float*)(ws + OFF_CS);
  float* cdec  = (float*)(ws + OFF_CDEC);
  float* G     = (float*)(ws + OFF_G);
  float* st    = (float*)(ws + OFF_ST);
  u16*   prevb = (u16*)(ws + OFF_PREV);
  float* Y     = (float*)(ws + OFF_Y);
  u16*   hb    = (u16*)(ws + OFF_HB);

  // fused converts (x8): X (4096 blocks) | W1 + pad (8704) | W2 (4096)
  k_cvt3<<<16896, 256, 0, stream>>>(X, W1, W2, Xb, Wb, W2b);

  // in_proj: (4096x2048) @ (8704x2048)^T -> Pb bf16 (ld 8704) + DTraw fp32 side-store
  k_gemm8<0><<<dim3(544,1), 512, 0, stream>>>(Xb, Wb, Pb, DTraw, 2048, 2048, NPAD, 2048, 16, 0L);

  // fused conv+silu (blocks 0..8703) | dt/a/cumsum (8704..9727)
  k_convdt<<<9728, 256, 0, stream>>>(Pb, CW, CB, XBCb, DTraw, DTB, ALOG, dtb, csb, cdec);

  // fused G = C@B^T (blocks 0..63) | chunk states (64..1087)
  k_gstates<<<1088, 256, 0, stream>>>(XBCb, dtb, csb, G, st);

  // inter-chunk scan (x4 vectorized)
  k_scan<<<1024, 256, 0, stream>>>(st, cdec, prevb);

  // Y = Y_diag + Y_off + D*x  (triangular skip)
  k_ydiag<<<1024, 256, 0, stream>>>(XBCb, G, prevb, dtb, csb, DD, Y);

  // gated RMSNorm -> bf16
  k_norm<<<4096, 256, 0, stream>>>(Y, Pb, NW, hb);

  // out_proj: (4096x4096) @ (2048x4096)^T -> d_out fp32, 256x128 tiles, 256 blocks, no split-K
  k_gemmN<<<256, 512, 0, stream>>>(hb, W2b, out, 4096, 4096, 2048, 4096, 16);
}

// Round 15
// 511.548 us; speedup vs baseline: 1.1946x; 1.0754x over previous
//
#include <hip/hip_runtime.h>

#define DEV __device__ __forceinline__

typedef unsigned short u16;
typedef unsigned int u32;
typedef __attribute__((ext_vector_type(4))) float f32x4;
typedef __attribute__((ext_vector_type(8))) u16 u16x8;
typedef __attribute__((ext_vector_type(4))) u16 u16x4;
typedef __attribute__((ext_vector_type(8))) __bf16 bf16x8;

#define INTER 4096
#define DSTATE 128
#define CONVD 4352
#define NPAD 8704
#define NROWS 4096

DEV float b2f(u16 u){ union{u32 i; float f;} v; v.i = ((u32)u)<<16; return v.f; }
DEV u16 f2b(float f){ union{u32 i; float f;} v; v.f = f; u32 r = v.i + 0x7fffu + ((v.i>>16)&1u); return (u16)(r>>16); }

typedef const __attribute__((address_space(1))) u32 gas_u32;
typedef __attribute__((address_space(3))) u32 las_u32;
DEV void gl_lds16(const u16* g, u16* l){
  __builtin_amdgcn_global_load_lds((gas_u32*)g, (las_u32*)l, 16, 0, 0);
}

// ---------------- fused f32 -> bf16 converts, x8 vectorized (X, W1 with zero-pad, W2) ----------------
__global__ __launch_bounds__(256) void k_cvt3(
    const float* __restrict__ X, const float* __restrict__ W1, const float* __restrict__ W2,
    u16* __restrict__ Xb, u16* __restrict__ Wb, u16* __restrict__ W2b)
{
  long b = blockIdx.x;
  const float* src; u16* dst; long n, base;
  if (b < 4096)       { src = X;  dst = Xb;  n = 8388608L;  base = b*2048L; }
  else if (b < 12800) { src = W1; dst = Wb;  n = 17432576L; base = (b-4096)*2048L; }
  else                { src = W2; dst = W2b; n = 8388608L;  base = (b-12800)*2048L; }
  long i = base + (long)threadIdx.x*8;
  u16x8 o;
  if (i < n){
    f32x4 v0 = *(const f32x4*)&src[i];
    f32x4 v1 = *(const f32x4*)&src[i+4];
    o[0]=f2b(v0[0]); o[1]=f2b(v0[1]); o[2]=f2b(v0[2]); o[3]=f2b(v0[3]);
    o[4]=f2b(v1[0]); o[5]=f2b(v1[1]); o[6]=f2b(v1[2]); o[7]=f2b(v1[3]);
  } else {
    o[0]=0;o[1]=0;o[2]=0;o[3]=0;o[4]=0;o[5]=0;o[6]=0;o[7]=0;
  }
  *(u16x8*)&dst[i] = o;
}

// ================= 256x256 BT GEMM, 128KB, SGB-interleaved (R7 proven) — in_proj =================
// NOTE (R8 lesson): acc[8][4]=128 regs requires <=2 waves/SIMD; do NOT raise occupancy arg.
template<int EPI>
__global__ __launch_bounds__(512, 2) void k_gemm8(
    const u16* __restrict__ A, const u16* __restrict__ B,
    void* __restrict__ C0, float* __restrict__ C1,
    int lda, int ldb, int ldc, int K, int NTM, long sCz)
{
  __shared__ __align__(16) char smem[131072];
  const int t = threadIdx.x, lane = t & 63, w = t >> 6;
  const int wm = w >> 2, wn = w & 3, w64 = w * 64;
  const int NT = K >> 6, NIT = NT >> 1;
  const int z = blockIdx.y;

  const int nwg = gridDim.x;
  const int orig = blockIdx.x;
  const int wg = (orig & 7) * (nwg >> 3) + (orig >> 3);
  const int mt = wg % NTM, nt = wg / NTM;     // nt-major: A streams, B panels L2-resident

  const u16* Ab = A + (long)mt * 256 * lda + (long)z * K;
  const u16* Bb = B + (long)nt * 256 * ldb + (long)z * K;

  const int laneoff = (lane & 15) * 64 + (lane >> 4) * 16;
  const int lo = laneoff ^ (((laneoff >> 9) & 1) << 5);

  long aoff[2], boff[2];
#pragma unroll
  for (int q = 0; q < 2; q++) {
    int u = t + q * 512;
    int up = u ^ (((u >> 5) & 1) << 1);          // inverse st_16x32 swizzle on 16B chunks
    int row = (up >> 6) * 16 + ((up & 63) >> 2);
    int c8 = (up & 3) * 8;
    aoff[q] = (long)row * lda + c8;
    boff[q] = (long)row * ldb + c8;
  }

  f32x4 acc[8][4];
#pragma unroll
  for (int i=0;i<8;i++)
#pragma unroll
    for (int j=0;j<4;j++) acc[i][j] = (f32x4){0.f,0.f,0.f,0.f};

#define SA(BUF,KH,KT) do{ long kb_ = (long)(KT)*64 + (KH)*32; \
    gl_lds16(Ab + aoff[0] + kb_, (u16*)(smem + (BUF)*65536 + (KH)*16384 + w64*16)); \
    gl_lds16(Ab + aoff[1] + kb_, (u16*)(smem + (BUF)*65536 + (KH)*16384 + 8192 + w64*16)); }while(0)
#define SB(BUF,KH,KT) do{ long kb_ = (long)(KT)*64 + (KH)*32; \
    gl_lds16(Bb + boff[0] + kb_, (u16*)(smem + (BUF)*65536 + 32768 + (KH)*16384 + w64*16)); \
    gl_lds16(Bb + boff[1] + kb_, (u16*)(smem + (BUF)*65536 + 32768 + (KH)*16384 + 8192 + w64*16)); }while(0)

// VM: 0=none, 1=vmcnt(8), 2=vmcnt(4), 3=vmcnt(0).  HASV: stage present (pin VMEM group).
#define SPHASE(BUF,KH,STMT,VM,HASV) do{ \
    const char* pa_ = smem + (BUF)*65536 + (KH)*16384; \
    const char* pb_ = smem + (BUF)*65536 + 32768 + (KH)*16384; \
    STMT; \
    bf16x8 a_[8], b_[4]; \
    _Pragma("unroll") \
    for (int j_=0;j_<4;j_++) b_[j_] = *(const bf16x8*)(pb_ + (wn*4+j_)*1024 + lo); \
    _Pragma("unroll") \
    for (int m_=0;m_<8;m_++) a_[m_] = *(const bf16x8*)(pa_ + (wm*8+m_)*1024 + lo); \
    __builtin_amdgcn_s_setprio(1); \
    _Pragma("unroll") \
    for (int m_=0;m_<8;m_++) \
      _Pragma("unroll") \
      for (int j_=0;j_<4;j_++) \
        acc[m_][j_] = __builtin_amdgcn_mfma_f32_16x16x32_bf16(a_[m_], b_[j_], acc[m_][j_], 0,0,0); \
    __builtin_amdgcn_s_setprio(0); \
    /* pinned schedule: DSx6 (B0-3,A0,A1) | VMEMx4 stage | 6x{MFMAx4, DSx1} | MFMAx8 */ \
    __builtin_amdgcn_sched_group_barrier(0x100, 6, 0); \
    if (HASV) __builtin_amdgcn_sched_group_barrier(0x010, 4, 0); \
    _Pragma("unroll") \
    for (int g_=0; g_<6; ++g_){ \
      __builtin_amdgcn_sched_group_barrier(0x008, 4, 0); \
      __builtin_amdgcn_sched_group_barrier(0x100, 1, 0); \
    } \
    __builtin_amdgcn_sched_group_barrier(0x008, 8, 0); \
    if ((VM)==1) asm volatile("s_waitcnt vmcnt(8)":::"memory"); \
    if ((VM)==2) asm volatile("s_waitcnt vmcnt(4)":::"memory"); \
    if ((VM)==3) asm volatile("s_waitcnt vmcnt(0)":::"memory"); \
    asm volatile("s_barrier":::"memory"); \
  }while(0)

  // prologue: tile0 (both halves) + tile1 kh0  -> 12 loads/wave
  SA(0,0,0); SB(0,0,0); SA(0,1,0); SB(0,1,0); SA(1,0,1); SB(1,0,1);
  asm volatile("s_waitcnt vmcnt(8)":::"memory");
  asm volatile("s_barrier":::"memory");

  for (int it = 0; it < NIT-1; ++it) {
    int t1 = 2*it+1, t2 = 2*it+2, t3 = 2*it+3;
    SPHASE(0,0, { SA(1,1,t1); SB(1,1,t1); }, 1, 1);
    SPHASE(0,1, { SA(0,0,t2); SB(0,0,t2); }, 1, 1);
    SPHASE(1,0, { SA(0,1,t2); SB(0,1,t2); }, 1, 1);
    SPHASE(1,1, { SA(1,0,t3); SB(1,0,t3); }, 1, 1);
  }
  { // final iteration (tiles NT-2, NT-1)
    int tl = NT-1;
    SPHASE(0,0, { SA(1,1,tl); SB(1,1,tl); }, 1, 1);
    SPHASE(0,1, ((void)0), 2, 0);
    SPHASE(1,0, ((void)0), 3, 0);
    SPHASE(1,1, ((void)0), 0, 0);
  }
#undef SA
#undef SB
#undef SPHASE

#pragma unroll
  for (int i=0;i<8;i++)
#pragma unroll
    for (int j=0;j<4;j++)
#pragma unroll
      for (int r=0;r<4;r++){
        int gm = mt*256 + wm*128 + i*16 + (lane>>4)*4 + r;
        int gn = nt*256 + wn*64 + j*16 + (lane&15);
        float v = acc[i][j][r];
        if (EPI==0){
          ((u16*)C0)[(long)gm*ldc + gn] = f2b(v);
          if (gn >= 8448 && gn < 8512) C1[(long)gm*64 + (gn-8448)] = v;
        } else {
          ((float*)C0)[(long)z*sCz + (long)gm*ldc + gn] = v;
        }
      }
}

// ================= 256x128 BT GEMM — out_proj (no split-K, fp32 direct store) =================
__global__ __launch_bounds__(512, 2) void k_gemmN(
    const u16* __restrict__ A, const u16* __restrict__ B, float* __restrict__ C0,
    int lda, int ldb, int ldc, int K, int NTM)
{
  __shared__ __align__(16) char smem[98304];
  const int t = threadIdx.x, lane = t & 63, w = t >> 6;
  const int wm = w >> 2, wn = w & 3, w64 = w * 64;
  const int NT = K >> 6, NIT = NT >> 1;

  const int nwg = gridDim.x;
  const int orig = blockIdx.x;
  const int wg = (orig & 7) * (nwg >> 3) + (orig >> 3);
  const int mt = wg % NTM, nt = wg / NTM;

  const u16* Ab = A + (long)mt * 256 * lda;
  const u16* Bb = B + (long)nt * 128 * ldb;

  const int laneoff = (lane & 15) * 64 + (lane >> 4) * 16;
  const int lo = laneoff ^ (((laneoff >> 9) & 1) << 5);

  long aoff[2];
#pragma unroll
  for (int q = 0; q < 2; q++) {
    int u = t + q * 512;
    int up = u ^ (((u >> 5) & 1) << 1);
    int row = (up >> 6) * 16 + ((up & 63) >> 2);
    int c8 = (up & 3) * 8;
    aoff[q] = (long)row * lda + c8;
  }
  long boff;
  {
    int up = t ^ (((t >> 5) & 1) << 1);
    int row = (up >> 6) * 16 + ((up & 63) >> 2);   // 0..127
    int c8 = (up & 3) * 8;
    boff = (long)row * ldb + c8;
  }

  f32x4 acc[8][2];
#pragma unroll
  for (int i=0;i<8;i++)
#pragma unroll
    for (int j=0;j<2;j++) acc[i][j] = (f32x4){0.f,0.f,0.f,0.f};

#define SAN(BUF,KH,KT) do{ long kb_ = (long)(KT)*64 + (KH)*32; \
    gl_lds16(Ab + aoff[0] + kb_, (u16*)(smem + (BUF)*49152 + (KH)*16384 + w64*16)); \
    gl_lds16(Ab + aoff[1] + kb_, (u16*)(smem + (BUF)*49152 + (KH)*16384 + 8192 + w64*16)); }while(0)
#define SBN(BUF,KH,KT) do{ long kb_ = (long)(KT)*64 + (KH)*32; \
    gl_lds16(Bb + boff + kb_, (u16*)(smem + (BUF)*49152 + 32768 + (KH)*8192 + w64*16)); }while(0)

// VM: 0=none, 1=vmcnt(6), 2=vmcnt(3), 3=vmcnt(0)
#define NPHASE(BUF,KH,STMT,VM) do{ \
    const char* pa_ = smem + (BUF)*49152 + (KH)*16384; \
    const char* pb_ = smem + (BUF)*49152 + 32768 + (KH)*8192; \
    STMT; \
    bf16x8 a_[8], b_[2]; \
    _Pragma("unroll") \
    for (int j_=0;j_<2;j_++) b_[j_] = *(const bf16x8*)(pb_ + (wn*2+j_)*1024 + lo); \
    _Pragma("unroll") \
    for (int m_=0;m_<8;m_++) a_[m_] = *(const bf16x8*)(pa_ + (wm*8+m_)*1024 + lo); \
    __builtin_amdgcn_s_setprio(1); \
    _Pragma("unroll") \
    for (int m_=0;m_<8;m_++) \
      _Pragma("unroll") \
      for (int j_=0;j_<2;j_++) \
        acc[m_][j_] = __builtin_amdgcn_mfma_f32_16x16x32_bf16(a_[m_], b_[j_], acc[m_][j_], 0,0,0); \
    __builtin_amdgcn_s_setprio(0); \
    if ((VM)==1) asm volatile("s_waitcnt vmcnt(6)":::"memory"); \
    if ((VM)==2) asm volatile("s_waitcnt vmcnt(3)":::"memory"); \
    if ((VM)==3) asm volatile("s_waitcnt vmcnt(0)":::"memory"); \
    asm volatile("s_barrier":::"memory"); \
  }while(0)

  // prologue: tile0 (both halves) + tile1 kh0 -> 9 loads/wave
  SAN(0,0,0); SBN(0,0,0); SAN(0,1,0); SBN(0,1,0); SAN(1,0,1); SBN(1,0,1);
  asm volatile("s_waitcnt vmcnt(6)":::"memory");
  asm volatile("s_barrier":::"memory");

  for (int it = 0; it < NIT-1; ++it) {
    int t1 = 2*it+1, t2 = 2*it+2, t3 = 2*it+3;
    NPHASE(0,0, { SAN(1,1,t1); SBN(1,1,t1); }, 1);
    NPHASE(0,1, { SAN(0,0,t2); SBN(0,0,t2); }, 1);
    NPHASE(1,0, { SAN(0,1,t2); SBN(0,1,t2); }, 1);
    NPHASE(1,1, { SAN(1,0,t3); SBN(1,0,t3); }, 1);
  }
  { // final iteration (tiles NT-2, NT-1)
    int tl = NT-1;
    NPHASE(0,0, { SAN(1,1,tl); SBN(1,1,tl); }, 1);
    NPHASE(0,1, ((void)0), 2);
    NPHASE(1,0, ((void)0), 3);
    NPHASE(1,1, ((void)0), 0);
  }
#undef SAN
#undef SBN
#undef NPHASE

#pragma unroll
  for (int i=0;i<8;i++)
#pragma unroll
    for (int j=0;j<2;j++)
#pragma unroll
      for (int r=0;r<4;r++){
        int gm = mt*256 + wm*128 + i*16 + (lane>>4)*4 + r;
        int gn = nt*128 + wn*32 + j*16 + (lane&15);
        C0[(long)gm*ldc + gn] = acc[i][j][r];
      }
}

// ---------------- fused: depthwise causal conv (K=4) + silu (4-row batched) | dt/a/cumsum ----------------
// Conv: each thread produces 4 consecutive rows for one 8-channel group, loading 7 input
// rows once (was 16 loads per 4 rows -> 1.75x read cut).  4-aligned row groups never span
// the batch boundary (2048%4==0); causal masking per-output via sk>=0 as before.
__global__ __launch_bounds__(256) void k_convdt(
    const u16* __restrict__ Pb, const float* __restrict__ cw, const float* __restrict__ cb,
    u16* __restrict__ XBC,
    const float* __restrict__ DTraw, const float* __restrict__ dt_bias,
    const float* __restrict__ A_log,
    float* __restrict__ dtb, float* __restrict__ csb, float* __restrict__ cdec)
{
  __shared__ float sc[256];
  if (blockIdx.x < 2176){
    // ---- conv + silu, 4 rows per thread ----
    long tg = (long)blockIdx.x*256 + threadIdx.x;
    int rg  = (int)(tg/544);          // row group 0..1023
    int ch0 = (int)(tg%544)*8;
    int row0 = rg*4;
    float wgt[4];
#pragma unroll
    for (int k=0;k<4;k++) wgt[k]=0.f;  // placeholder to keep cw loads simple below
    // per-channel weights: cw[(ch0+j)*4 + k]
    u16x8 rbuf[7];
#pragma unroll
    for (int i=0;i<7;i++){
      int gr = row0 - 3 + i;
      if (gr >= 0){
        rbuf[i] = *(const u16x8*)&Pb[(long)gr*NPAD + INTER + ch0];
      } else {
        u16x8 z; 
#pragma unroll
        for (int j=0;j<8;j++) z[j]=0;
        rbuf[i] = z;
      }
    }
#pragma unroll
    for (int so=0; so<4; so++){
      int row = row0 + so;
      int s = row & 2047;
      float acc[8];
#pragma unroll
      for (int j=0;j<8;j++) acc[j] = cb[ch0+j];
#pragma unroll
      for (int k=0;k<4;k++){
        int sk = s - 3 + k;
        if (sk >= 0){
          u16x8 v = rbuf[so+k];
#pragma unroll
          for (int j=0;j<8;j++) acc[j] += b2f(v[j]) * cw[(ch0+j)*4 + k];
        }
      }
      u16x8 o;
#pragma unroll
      for (int j=0;j<8;j++){ float x = acc[j]; o[j] = f2b(x/(1.f+__expf(-x))); }
      *(u16x8*)&XBC[(long)row*CONVD + ch0] = o;
    }
    (void)wgt;
  } else {
    // ---- dt = softplus(dtraw + bias), a = dt*A, cumsum per (b,h,chunk) ----
    int bid = blockIdx.x - 2176;   // ((b*64+h)*8 + c)
    int bh = bid>>3, c = bid&7;
    int h = bh & 63, b = bh>>6;
    int l = threadIdx.x;
    int row = (b*8+c)*256 + l;
    float x = DTraw[(long)row*64 + h] + dt_bias[h];
    float dt = (x > 20.f) ? x : log1pf(__expf(x));
    float a = dt * (-__expf(A_log[h]));
    dtb[(long)row*64 + h] = dt;
    sc[l] = a; __syncthreads();
    for (int off=1; off<256; off<<=1){
      float v = (l>=off) ? sc[l-off] : 0.f;
      __syncthreads();
      sc[l] += v;
      __syncthreads();
    }
    float cs = sc[l];
    csb[(long)bid*256 + l] = cs;
    if (l==255) cdec[bid] = __expf(cs);
  }
}

// ---------------- fused: G = C@B^T (blocks 0..63) | chunk states via MFMA (64..1087) ----------------
__global__ __launch_bounds__(256) void k_gstates(
    const u16* __restrict__ XBC, const float* __restrict__ dtb, const float* __restrict__ csb,
    float* __restrict__ G, float* __restrict__ states)
{
  __shared__ __align__(16) char smem[53248];
  const int t = threadIdx.x, w = t>>6, lane = t&63;

  if (blockIdx.x < 64){
    // ===== G[bc] = C @ B^T, 128x128 tile, K=128 =====
    int bid = blockIdx.x;
    int z = bid>>2, mt = (bid>>1)&1, nt = bid&1;
    u16* As = (u16*)smem;                 // 128x64
    u16* Bs = (u16*)(smem + 16384);       // 128x64
    const u16* Ab = XBC + INTER + DSTATE + (long)z*256*CONVD + (long)mt*128*CONVD;
    const u16* Bb = XBC + INTER          + (long)z*256*CONVD + (long)nt*128*CONVD;
    const int wm = w>>1, wn = w&1;
    f32x4 acc[4][4];
#pragma unroll
    for (int i=0;i<4;i++)
#pragma unroll
      for (int j=0;j<4;j++) acc[i][j] = (f32x4){0.f,0.f,0.f,0.f};
    const int srow = (lane>>3), scol = (lane&7)*8;
    for (int k0=0; k0<128; k0+=64){
#pragma unroll
      for (int i=0;i<4;i++){
        int ch = w*4+i;
        int row = ch*8 + srow;
        gl_lds16(Ab + (long)row*CONVD + k0 + scol, As + ch*512);
        gl_lds16(Bb + (long)row*CONVD + k0 + scol, Bs + ch*512);
      }
      __syncthreads();
#pragma unroll
      for (int kk=0;kk<2;kk++){
        bf16x8 af[4], bfr[4];
#pragma unroll
        for (int i=0;i<4;i++) af[i]  = *(const bf16x8*)&As[(wm*64+i*16+(lane&15))*64 + kk*32 + (lane>>4)*8];
#pragma unroll
        for (int j=0;j<4;j++) bfr[j] = *(const bf16x8*)&Bs[(wn*64+j*16+(lane&15))*64 + kk*32 + (lane>>4)*8];
#pragma unroll
        for (int i=0;i<4;i++)
#pragma unroll
          for (int j=0;j<4;j++)
            acc[i][j] = __builtin_amdgcn_mfma_f32_16x16x32_bf16(af[i], bfr[j], acc[i][j], 0,0,0);
      }
      __syncthreads();
    }
#pragma unroll
    for (int i=0;i<4;i++)
#pragma unroll
      for (int j=0;j<4;j++)
#pragma unroll
        for (int r=0;r<4;r++){
          int gm = mt*128 + wm*64 + i*16 + (lane>>4)*4 + r;
          int gn = nt*128 + wn*64 + j*16 + (lane&15);
          G[(long)z*65536 + (long)gm*256 + gn] = acc[i][j][r];
        }
    return;
  }

  // ===== chunk states: states[p][n] = sum_l xdt[l][p]*decay[l]*B[l][n], XOR-swizzled =====
  int bid = blockIdx.x - 64;       // (b*8+c)*64 + h
  u16* xsT = (u16*)smem;                       // 64x136
  u16* bsT = (u16*)(smem + 17408);             // 128x136
  float* dtl = (float*)(smem + 52224);         // 128
  float* del = (float*)(smem + 52736);         // 128
  int h = bid & 63, bc = bid >> 6;
  int b = bc>>3, c = bc&7;
  int rowb = bc*256;
  int csbase = ((b*64+h)*8 + c)*256;
  float clast = csb[csbase + 255];
  f32x4 acc[8];
#pragma unroll
  for (int j=0;j<8;j++) acc[j] = (f32x4){0.f,0.f,0.f,0.f};
  for (int half=0; half<2; half++){
    int lbase = half*128;
    if (t < 128){
      dtl[t] = dtb[(long)(rowb+lbase+t)*64 + h];
      del[t] = __expf(clast - csb[csbase + lbase + t]);
    }
    __syncthreads();
#pragma unroll
    for (int it=0; it<2; it++){
      int id = it*256+t;
      int p8 = id&7, l = (id>>3)*2;
      u16x8 v0 = *(const u16x8*)&XBC[(long)(rowb+lbase+l  )*CONVD + h*64 + p8*8];
      u16x8 v1 = *(const u16x8*)&XBC[(long)(rowb+lbase+l+1)*CONVD + h*64 + p8*8];
      float d0 = dtl[l], d1 = dtl[l+1];
#pragma unroll
      for (int j=0;j<8;j++){
        int row = p8*8+j;
        u32 dv = (u32)f2b(b2f(v0[j])*d0) | ((u32)f2b(b2f(v1[j])*d1)<<16);
        u32 byte = (u32)(2*(row*136 + l)) ^ (((u32)(row>>3)&7u)<<4);
        *(u32*)((char*)xsT + byte) = dv;
      }
    }
#pragma unroll
    for (int it=0; it<4; it++){
      int id = it*256+t;
      int n8 = id&15, l = (id>>4)*2;
      u16x8 v0 = *(const u16x8*)&XBC[(long)(rowb+lbase+l  )*CONVD + INTER + n8*8];
      u16x8 v1 = *(const u16x8*)&XBC[(long)(rowb+lbase+l+1)*CONVD + INTER + n8*8];
      float d0 = del[l], d1 = del[l+1];
#pragma unroll
      for (int j=0;j<8;j++){
        int row = n8*8+j;
        u32 dv = (u32)f2b(b2f(v0[j])*d0) | ((u32)f2b(b2f(v1[j])*d1)<<16);
        u32 byte = (u32)(2*(row*136 + l)) ^ (((u32)(row>>3)&7u)<<4);
        *(u32*)((char*)bsT + byte) = dv;
      }
    }
    __syncthreads();
#pragma unroll
    for (int ks=0; ks<4; ks++){
      int rowA = w*16 + (lane&15);
      u32 abyte = (u32)(2*(rowA*136 + ks*32 + (lane>>4)*8)) ^ (((u32)(rowA>>3)&7u)<<4);
      bf16x8 af = *(const bf16x8*)((char*)xsT + abyte);
#pragma unroll
      for (int j=0;j<8;j++){
        int rowB = j*16 + (lane&15);
        u32 bbyte = (u32)(2*(rowB*136 + ks*32 + (lane>>4)*8)) ^ (((u32)(rowB>>3)&7u)<<4);
        bf16x8 bf = *(const bf16x8*)((char*)bsT + bbyte);
        acc[j] = __builtin_amdgcn_mfma_f32_16x16x32_bf16(af, bf, acc[j], 0,0,0);
      }
    }
    __syncthreads();
  }
  float* outp = states + (long)bid*8192;
#pragma unroll
  for (int j=0;j<8;j++)
#pragma unroll
    for (int r=0;r<4;r++){
      int gm = w*16 + (lane>>4)*4 + r;
      int gn = j*16 + (lane&15);
      outp[gm*128 + gn] = acc[j][r];
    }
}

// ---------------- inter-chunk scan (vectorized x4) ----------------
__global__ __launch_bounds__(256) void k_scan(
    const float* __restrict__ states, const float* __restrict__ cdec,
    u16* __restrict__ prevb)
{
  int bid = blockIdx.x;            // (b*64+h)*8 + sub
  int bh = bid>>3, sub = bid&7;
  int b = bh>>6, h = bh&63;
  int e = (sub*256 + threadIdx.x)*4;
  f32x4 carry = (f32x4){0.f,0.f,0.f,0.f};
#pragma unroll
  for (int c=0;c<8;c++){
    long idx = ((long)((b*8+c)*64 + h))*8192 + e;
    u16x4 o;
    o[0]=f2b(carry[0]); o[1]=f2b(carry[1]); o[2]=f2b(carry[2]); o[3]=f2b(carry[3]);
    *(u16x4*)&prevb[idx] = o;
    f32x4 s = *(const f32x4*)&states[idx];
    float d = cdec[bh*8 + c];
    carry = carry*d + s;
  }
}

// ---------------- fused Y_diag + Y_off + D*x per (b,c,h), triangular-skip ----------------
__global__ __launch_bounds__(256) void k_ydiag(
    const u16* __restrict__ XBC, const float* __restrict__ G,
    const u16* __restrict__ prevb, const float* __restrict__ dtb,
    const float* __restrict__ csb, const float* __restrict__ Dp,
    float* __restrict__ Y)
{
  __shared__ u16 PA[256*72];
  __shared__ u16 PB[64*72];
  __shared__ float csl[256];
  int bid = blockIdx.x;
  int h = bid&63, bc = bid>>6;
  int b = bc>>3, c = bc&7;
  int rowb = bc*256;
  int t = threadIdx.x, w = t>>6, lane = t&63;
  int csbase = ((b*64+h)*8 + c)*256;
  csl[t] = csb[csbase + t];
  const float* Gz = G + (long)bc*65536;
  f32x4 ad[4][4], ao[4][4];
#pragma unroll
  for (int i=0;i<4;i++)
#pragma unroll
    for (int j=0;j<4;j++){ ad[i][j]=(f32x4){0.f,0.f,0.f,0.f}; ao[i][j]=(f32x4){0.f,0.f,0.f,0.f}; }
  __syncthreads();
  for (int sl6=0; sl6<6; sl6++){
    if (sl6 < 4){
      int s0 = sl6*64;
#pragma unroll
      for (int r=0;r<8;r++){
        if ((r+1)*32 > s0){          // rows r*32..r*32+31 contain some l >= s0
          int id = r*256+t;
          int l = id>>3, sc8 = (id&7)*8;
          f32x4 g0 = *(const f32x4*)&Gz[l*256 + s0+sc8];
          f32x4 g1 = *(const f32x4*)&Gz[l*256 + s0+sc8+4];
          float cl = csl[l];
          u16x8 o;
#pragma unroll
          for (int jj=0;jj<4;jj++){
            int s = s0+sc8+jj;
            o[jj] = (s<=l) ? f2b(g0[jj]*__expf(cl - csl[s])) : (u16)0;
          }
#pragma unroll
          for (int jj=4;jj<8;jj++){
            int s = s0+sc8+jj;
            o[jj] = (s<=l) ? f2b(g1[jj-4]*__expf(cl - csl[s])) : (u16)0;
          }
          *(u16x8*)&PA[l*72 + sc8] = o;
        }
      }
#pragma unroll
      for (int r=0;r<16;r++){
        int id = r*256+t;
        int p = id&63, ks = id>>6;
        float xv = b2f(XBC[(long)(rowb+s0+ks)*CONVD + h*64 + p]);
        float d = dtb[(long)(rowb+s0+ks)*64 + h];
        PB[p*72 + ks] = f2b(xv*d);
      }
    } else {
      int n0 = (sl6-4)*64;
#pragma unroll
      for (int r=0;r<8;r++){
        int id = r*256+t;
        int l = id>>3, kc = (id&7)*8;
        u16x8 v = *(const u16x8*)&XBC[(long)(rowb+l)*CONVD + INTER + DSTATE + n0 + kc];
        *(u16x8*)&PA[l*72 + kc] = v;
      }
#pragma unroll
      for (int r=0;r<2;r++){
        int id = r*256+t;
        int p = id>>3, kc = (id&7)*8;
        u16x8 v = *(const u16x8*)&prevb[((long)bid*64 + p)*128 + n0 + kc];
        *(u16x8*)&PB[p*72 + kc] = v;
      }
    }
    __syncthreads();
    if (sl6 < 4){
      if (w >= sl6){
#pragma unroll
        for (int kk=0;kk<2;kk++){
          bf16x8 af[4], bfr[4];
#pragma unroll
          for (int i=0;i<4;i++) af[i]  = *(const bf16x8*)&PA[(w*64+i*16+(lane&15))*72 + kk*32 + (lane>>4)*8];
#pragma unroll
          for (int j=0;j<4;j++) bfr[j] = *(const bf16x8*)&PB[(j*16+(lane&15))*72 + kk*32 + (lane>>4)*8];
#pragma unroll
          for (int i=0;i<4;i++)
#pragma unroll
            for (int j=0;j<4;j++)
              ad[i][j] = __builtin_amdgcn_mfma_f32_16x16x32_bf16(af[i], bfr[j], ad[i][j], 0,0,0);
        }
      }
    } else {
#pragma unroll
      for (int kk=0;kk<2;kk++){
        bf16x8 af[4], bfr[4];
#pragma unroll
        for (int i=0;i<4;i++) af[i]  = *(const bf16x8*)&PA[(w*64+i*16+(lane&15))*72 + kk*32 + (lane>>4)*8];
#pragma unroll
        for (int j=0;j<4;j++) bfr[j] = *(const bf16x8*)&PB[(j*16+(lane&15))*72 + kk*32 + (lane>>4)*8];
#pragma unroll
        for (int i=0;i<4;i++)
#pragma unroll
          for (int j=0;j<4;j++)
            ao[i][j] = __builtin_amdgcn_mfma_f32_16x16x32_bf16(af[i], bfr[j], ao[i][j], 0,0,0);
      }
    }
    __syncthreads();
  }
  float Dh = Dp[h];
#pragma unroll
  for (int i=0;i<4;i++)
#pragma unroll
    for (int r=0;r<4;r++){
      int l = w*64 + i*16 + (lane>>4)*4 + r;
      float e = __expf(csl[l]);          // hoisted: one exp per (i,r), not per (i,j,r)
#pragma unroll
      for (int j=0;j<4;j++){
        int p = j*16 + (lane&15);
        float xv = b2f(XBC[(long)(rowb+l)*CONVD + h*64 + p]);
        float v = ad[i][j][r] + e*ao[i][j][r] + Dh*xv;
        Y[(long)(rowb+l)*INTER + h*64 + p] = v;
      }
    }
}

// ---------------- gated RMSNorm -> bf16 ----------------
__global__ __launch_bounds__(256) void k_norm(
    const float* __restrict__ Y, const u16* __restrict__ Pb,
    const float* __restrict__ nw, u16* __restrict__ hb)
{
  int row = blockIdx.x, t = threadIdx.x;
  int w = t>>6, lane = t&63;
  float hv[16];
  float ss = 0.f;
#pragma unroll
  for (int r=0;r<4;r++){
    int idx = (r*256+t)*4;
    f32x4 yv = *(const f32x4*)&Y[(long)row*INTER + idx];
    u16x4 gv = *(const u16x4*)&Pb[(long)row*NPAD + idx];
#pragma unroll
    for (int jj=0;jj<4;jj++){
      float g = b2f(gv[jj]);
      float hh = yv[jj] * g / (1.f+__expf(-g));
      hv[r*4+jj] = hh;
      ss += hh*hh;
    }
  }
  for (int off=32; off; off>>=1) ss += __shfl_down(ss, off);
  __shared__ float sm[4];
  if (lane==0) sm[w]=ss;
  __syncthreads();
  float tot = sm[0]+sm[1]+sm[2]+sm[3];
  float sc = rsqrtf(tot/4096.f + 1e-6f);
#pragma unroll
  for (int r=0;r<4;r++){
    int idx = (r*256+t)*4;
    f32x4 nv = *(const f32x4*)&nw[idx];
    u16x4 o;
#pragma unroll
    for (int jj=0;jj<4;jj++) o[jj] = f2b(hv[r*4+jj]*nv[jj]*sc);
    *(u16x4*)&hb[(long)row*INTER + idx] = o;
  }
}

// ---------------- launch ----------------
extern "C" void kernel_launch(void* const* d_in, const int* in_sizes, int n_in,
                              void* d_out, int out_size, void* d_ws, size_t ws_size,
                              hipStream_t stream)
{
  (void)in_sizes; (void)n_in;
  const float* X    = (const float*)d_in[0];
  const float* W1   = (const float*)d_in[1];
  const float* CW   = (const float*)d_in[2];
  const float* CB   = (const float*)d_in[3];
  const float* DTB  = (const float*)d_in[4];
  const float* ALOG = (const float*)d_in[5];
  const float* DD   = (const float*)d_in[6];
  const float* NW   = (const float*)d_in[7];
  const float* W2   = (const float*)d_in[8];
  float* out = (float*)d_out;
  char* ws = (char*)d_ws;

  constexpr long OFF_XB    = 0L;
  constexpr long OFF_WB    = 16777216L;
  constexpr long OFF_Y     = 0L;
  constexpr long OFF_ST    = 67108864L;
  constexpr long OFF_HB    = 67108864L;
  constexpr long OFF_W2B   = 100663296L;
  constexpr long OFF_PB    = 117440512L;   // 4096 x 8704 bf16 = 71,303,168
  constexpr long OFF_DTRAW = 188743680L;   // 4096 x 64 fp32 = 1,048,576
  constexpr long OFF_XBC   = 189792256L;
  constexpr long OFF_DT    = 225443840L;
  constexpr long OFF_CS    = 226492416L;
  constexpr long OFF_CDEC  = 227540992L;
  constexpr long OFF_G     = 227545088L;
  constexpr long OFF_PREV  = 231739392L;
  constexpr long WS_NEEDED = 248516608L;

  if ((long)ws_size < WS_NEEDED){
    hipMemsetAsync(d_out, 0, (size_t)out_size*4, stream);
    return;
  }

  u16*   Xb    = (u16*)(ws + OFF_XB);
  u16*   Wb    = (u16*)(ws + OFF_WB);
  u16*   W2b   = (u16*)(ws + OFF_W2B);
  u16*   Pb    = (u16*)(ws + OFF_PB);
  float* DTraw = (float*)(ws + OFF_DTRAW);
  u16*   XBCb  = (u16*)(ws + OFF_XBC);
  float* dtb   = (float*)(ws + OFF_DT);
  float* csb   = (float*)(ws + OFF_CS);
  float* cdec  = (float*)(ws + OFF_CDEC);
  float* G     = (float*)(ws + OFF_G);
  float* st    = (float*)(ws + OFF_ST);
  u16*   prevb = (u16*)(ws + OFF_PREV);
  float* Y     = (float*)(ws + OFF_Y);
  u16*   hb    = (u16*)(ws + OFF_HB);

  // fused converts (x8): X (4096 blocks) | W1 + pad (8704) | W2 (4096)
  k_cvt3<<<16896, 256, 0, stream>>>(X, W1, W2, Xb, Wb, W2b);

  // in_proj: (4096x2048) @ (8704x2048)^T -> Pb bf16 (ld 8704) + DTraw fp32 side-store
  k_gemm8<0><<<dim3(544,1), 512, 0, stream>>>(Xb, Wb, Pb, DTraw, 2048, 2048, NPAD, 2048, 16, 0L);

  // fused conv+silu 4-row batched (blocks 0..2175) | dt/a/cumsum (2176..3199)
  k_convdt<<<3200, 256, 0, stream>>>(Pb, CW, CB, XBCb, DTraw, DTB, ALOG, dtb, csb, cdec);

  // fused G = C@B^T (blocks 0..63) | chunk states (64..1087)
  k_gstates<<<1088, 256, 0, stream>>>(XBCb, dtb, csb, G, st);

  // inter-chunk scan (x4 vectorized)
  k_scan<<<1024, 256, 0, stream>>>(st, cdec, prevb);

  // Y = Y_diag + Y_off + D*x  (triangular skip)
  k_ydiag<<<1024, 256, 0, stream>>>(XBCb, G, prevb, dtb, csb, DD, Y);

  // gated RMSNorm -> bf16
  k_norm<<<4096, 256, 0, stream>>>(Y, Pb, NW, hb);

  // out_proj: (4096x4096) @ (2048x4096)^T -> d_out fp32, 256x128 tiles, 256 blocks, no split-K
  k_gemmN<<<256, 512, 0, stream>>>(hb, W2b, out, 4096, 4096, 2048, 4096, 16);
}